// Round 6
// baseline (256.554 us; speedup 1.0000x reference)
//
#include <hip/hip_runtime.h>
#include <math.h>

#define NN   4096
#define DD   256
#define NHD  768
#define NH   4
#define NE   131072
#define KVSPLIT 4
#define PAD  128
#define QSCALE 0.18033688011112042f   // 0.125 * log2(e)

using bfx8   = __attribute__((ext_vector_type(8))) short;
using f32x4  = __attribute__((ext_vector_type(4))) float;
using f32x16 = __attribute__((ext_vector_type(16))) float;
#define MFMA16(a,b,c) __builtin_amdgcn_mfma_f32_16x16x32_bf16(a, b, c, 0, 0, 0)
#define MFMA32(a,b,c) __builtin_amdgcn_mfma_f32_32x32x16_bf16(a, b, c, 0, 0, 0)

__device__ __forceinline__ ushort bf16_rne(float f) {
  uint u = __float_as_uint(f);
  u += 0x7fffu + ((u >> 16) & 1u);
  return (ushort)(u >> 16);
}
__device__ __forceinline__ float bf16_tof(ushort h) {
  return __uint_as_float(((uint)h) << 16);
}
__device__ __forceinline__ float fexp2(float x) { return __builtin_amdgcn_exp2f(x); }
__device__ __forceinline__ int swzf(int row) {   // u32-index XOR mask, bits 2..4
  return ((row & 7) << 2) ^ ((row & 8) << 1);
}
__device__ __forceinline__ void split8(const float* f, uint4& uh, uint4& ul) {
  ushort hs[8], ls[8];
#pragma unroll
  for (int j = 0; j < 8; ++j) {
    hs[j] = bf16_rne(f[j]);
    ls[j] = bf16_rne(f[j] - bf16_tof(hs[j]));
  }
  uh = make_uint4((uint)hs[0] | ((uint)hs[1] << 16), (uint)hs[2] | ((uint)hs[3] << 16),
                  (uint)hs[4] | ((uint)hs[5] << 16), (uint)hs[6] | ((uint)hs[7] << 16));
  ul = make_uint4((uint)ls[0] | ((uint)ls[1] << 16), (uint)ls[2] | ((uint)ls[3] << 16),
                  (uint)ls[4] | ((uint)ls[5] << 16), (uint)ls[6] | ((uint)ls[7] << 16));
}

// ---------------- split-bf16 MFMA GEMM, async-staged ------------------------
__global__ __launch_bounds__(256, 4) void gemmm(
    const ushort* __restrict__ Ahi, const ushort* __restrict__ Alo,
    const ushort* __restrict__ Whi, const ushort* __restrict__ Wlo,
    const float* __restrict__ bias, float* __restrict__ Cf,
    ushort* __restrict__ Chi, ushort* __restrict__ Clo,
    int M, int Nc, int K, float preScale, int preScaleCols) {
  __shared__ uint sAh[2048], sAl[2048], sBh[2048], sBl[2048];
  const int tid = threadIdx.x;
  const int wid = tid >> 6, lane = tid & 63;
  const int m15 = lane & 15, g2 = lane >> 4;
  const int wr = wid >> 1, wc = wid & 1;
  const int mb = blockIdx.x << 6, nb = blockIdx.y << 6;
  const int sw = swzf(m15);
  const int pr0 = tid >> 3, pc0 = (tid & 7) << 2;
  const int pr1 = (tid + 256) >> 3, pc1 = pc0;
  const int wi0 = (pr0 << 5) + (pc0 ^ swzf(pr0));
  const int wi1 = (pr1 << 5) + (pc1 ^ swzf(pr1));
  uint4 rah0, ral0, rbh0, rbl0, rah1, ral1, rbh1, rbl1;
  auto issue = [&](int k0) {
    size_t a0 = (size_t)(mb + pr0) * K + k0 + (pc0 << 1);
    size_t a1 = (size_t)(mb + pr1) * K + k0 + (pc1 << 1);
    size_t b0 = (size_t)(nb + pr0) * K + k0 + (pc0 << 1);
    size_t b1 = (size_t)(nb + pr1) * K + k0 + (pc1 << 1);
    rah0 = *(const uint4*)(Ahi + a0); ral0 = *(const uint4*)(Alo + a0);
    rah1 = *(const uint4*)(Ahi + a1); ral1 = *(const uint4*)(Alo + a1);
    rbh0 = *(const uint4*)(Whi + b0); rbl0 = *(const uint4*)(Wlo + b0);
    rbh1 = *(const uint4*)(Whi + b1); rbl1 = *(const uint4*)(Wlo + b1);
  };
  f32x4 acc[2][2];
#pragma unroll
  for (int r = 0; r < 2; ++r)
#pragma unroll
    for (int c = 0; c < 2; ++c) acc[r][c] = (f32x4){0.f, 0.f, 0.f, 0.f};

  issue(0);
  for (int k0 = 0; k0 < K; k0 += 64) {
    __syncthreads();
    *(uint4*)&sAh[wi0] = rah0; *(uint4*)&sAl[wi0] = ral0;
    *(uint4*)&sBh[wi0] = rbh0; *(uint4*)&sBl[wi0] = rbl0;
    *(uint4*)&sAh[wi1] = rah1; *(uint4*)&sAl[wi1] = ral1;
    *(uint4*)&sBh[wi1] = rbh1; *(uint4*)&sBl[wi1] = rbl1;
    __syncthreads();
    if (k0 + 64 < K) issue(k0 + 64);
#pragma unroll
    for (int c = 0; c < 2; ++c) {
      bfx8 ah[2], alo[2], bh[2], blo[2];
#pragma unroll
      for (int r = 0; r < 2; ++r) {
        int rowA = (wr << 5) + (r << 4) + m15;
        int idxA = (rowA << 5) + (((c << 4) + (g2 << 2)) ^ sw);
        ah[r]  = __builtin_bit_cast(bfx8, *(const uint4*)&sAh[idxA]);
        alo[r] = __builtin_bit_cast(bfx8, *(const uint4*)&sAl[idxA]);
        int rowB = (wc << 5) + (r << 4) + m15;
        int idxB = (rowB << 5) + (((c << 4) + (g2 << 2)) ^ sw);
        bh[r]  = __builtin_bit_cast(bfx8, *(const uint4*)&sBh[idxB]);
        blo[r] = __builtin_bit_cast(bfx8, *(const uint4*)&sBl[idxB]);
      }
#pragma unroll
      for (int r = 0; r < 2; ++r)
#pragma unroll
        for (int cc = 0; cc < 2; ++cc) {
          acc[r][cc] = MFMA16(ah[r], bh[cc], acc[r][cc]);
          acc[r][cc] = MFMA16(ah[r], blo[cc], acc[r][cc]);
          acc[r][cc] = MFMA16(alo[r], bh[cc], acc[r][cc]);
        }
    }
  }
#pragma unroll
  for (int r = 0; r < 2; ++r)
#pragma unroll
    for (int cc = 0; cc < 2; ++cc) {
      int col = nb + (wc << 5) + (cc << 4) + m15;
      float bv = bias ? bias[col] : 0.f;
      float sc = (col < preScaleCols) ? preScale : 1.f;
#pragma unroll
      for (int j = 0; j < 4; ++j) {
        int row = mb + (wr << 5) + (r << 4) + (g2 << 2) + j;
        float v = (acc[r][cc][j] + bv) * sc;
        if (Cf) Cf[(size_t)row * Nc + col] = v;
        if (Chi) {
          ushort hi = bf16_rne(v);
          Chi[(size_t)row * Nc + col] = hi;
          if (Clo) Clo[(size_t)row * Nc + col] = bf16_rne(v - bf16_tof(hi));
        }
      }
    }
}

// ------- convert x/ipw/W1/W2 to hi/lo; zero cnt/cursor; opw^T; bfv ----------
__global__ __launch_bounds__(256) void k_cvt5(
    const float* __restrict__ x, const float* __restrict__ ipw,
    const float* __restrict__ opw, const float* __restrict__ W1,
    const float* __restrict__ W2, const float* __restrict__ opb,
    ushort* xh, ushort* xl, ushort* iph, ushort* ipl,
    ushort* w1h, ushort* w1l, ushort* w2h, ushort* w2l,
    ushort* opth, ushort* optl, float* bfv,
    int* cnt, int* cursor) {
  __shared__ float sT[64 * 65];
  int b = blockIdx.x;
  if (b >= 672) {
    if (b < 676) {                       // zero cnt+cursor
      int i = ((b - 672) * 256 + threadIdx.x) * 4;
      *(int4*)(cnt + i) = make_int4(0, 0, 0, 0);
      *(int4*)(cursor + i) = make_int4(0, 0, 0, 0);
    } else if (b < 692) {                // transpose-convert opw -> opth/optl
      int tx = b - 676, by = tx >> 2, bx = tx & 3;
      int r = threadIdx.x >> 2, cb = (threadIdx.x & 3) << 4;
      const float* src = opw + (size_t)(by * 64 + r) * 256 + bx * 64 + cb;
#pragma unroll
      for (int i = 0; i < 4; ++i) {
        float4 v = *(const float4*)(src + i * 4);
        sT[r * 65 + cb + i * 4 + 0] = v.x; sT[r * 65 + cb + i * 4 + 1] = v.y;
        sT[r * 65 + cb + i * 4 + 2] = v.z; sT[r * 65 + cb + i * 4 + 3] = v.w;
      }
      __syncthreads();
      int d = threadIdx.x >> 2, nb2 = (threadIdx.x & 3) << 4;
      float f[16];
#pragma unroll
      for (int i = 0; i < 16; ++i) f[i] = sT[(nb2 + i) * 65 + d];
      uint4 uh0, ul0, uh1, ul1;
      split8(&f[0], uh0, ul0); split8(&f[8], uh1, ul1);
      size_t o = (size_t)(bx * 64 + d) * 256 + by * 64 + nb2;
      *(uint4*)(opth + o) = uh0; *(uint4*)(opth + o + 8) = uh1;
      *(uint4*)(optl + o) = ul0; *(uint4*)(optl + o + 8) = ul1;
    } else {                             // bfv = W1 * opb
      int t = threadIdx.x;
      sT[t] = opb[t];
      __syncthreads();
      float acc = 0.f;
      const float* wr = W1 + (size_t)t * 256;
      for (int k = 0; k < 256; ++k) acc += wr[k] * sT[k];
      bfv[t] = acc;
    }
    return;
  }
  const float* src; ushort* hi; ushort* lo; int base;
  if (b < 512)      { src = x;   hi = xh;  lo = xl;  base = b; }
  else if (b < 608) { src = ipw; hi = iph; lo = ipl; base = b - 512; }
  else if (b < 640) { src = W1;  hi = w1h; lo = w1l; base = b - 608; }
  else              { src = W2;  hi = w2h; lo = w2l; base = b - 640; }
  size_t i = (size_t)base * 256 + threadIdx.x;
  float f[8];
  *(float4*)&f[0] = *(const float4*)(src + i * 8);
  *(float4*)&f[4] = *(const float4*)(src + i * 8 + 4);
  uint4 uh, ul; split8(f, uh, ul);
  *(uint4*)(hi + i * 8) = uh;
  *(uint4*)(lo + i * 8) = ul;
}

// ---------------- repack V (hi only) to transposed [h][d][n] ----------------
__global__ __launch_bounds__(256) void k_cvtV(const ushort* __restrict__ qh,
    ushort* __restrict__ vhg) {
  __shared__ ushort sh[64 * 72];
  int n0 = blockIdx.x << 6, h = blockIdx.y, t = threadIdx.x;
  {
    int nn = t >> 2, cb = (t & 3) << 4;
    size_t off = (size_t)(n0 + nn) * NHD + 2 * DD + h * 64 + cb;
    *(uint4*)&sh[nn * 72 + cb]     = *(const uint4*)(qh + off);
    *(uint4*)&sh[nn * 72 + cb + 8] = *(const uint4*)(qh + off + 8);
  }
  __syncthreads();
  {
    int d = t >> 2, nb = (t & 3) << 4;
    ushort oh[16];
#pragma unroll
    for (int i = 0; i < 16; ++i) oh[i] = sh[(nb + i) * 72 + d];
    size_t o = ((size_t)(h * 64 + d) << 12) + n0 + nb;
    *(uint4*)(vhg + o)     = *(uint4*)&oh[0];
    *(uint4*)(vhg + o + 8) = *(uint4*)&oh[8];
  }
}

// ------- MFMA 32x32 swapped-operand flash, 2-term QK / 2-term PV ------------
// K,V bf16-hi only in LDS (16 KB); Q and P keep hi/lo. 128-thr blocks, 64 q.
__global__ __launch_bounds__(128, 4) void flashm(
    const ushort* __restrict__ qkvh, const ushort* __restrict__ qkvl,
    const ushort* __restrict__ vhg,
    float* __restrict__ opT, float* __restrict__ ml) {
  __shared__ uint sKh[2048], sVh[2048];   // 16 KB

  const int b = blockIdx.x;
  const int id = b & 15;                 // (h,split): XCD-local KV slice
  const int h = id >> 2, split = id & 3;
  const int qb = (b >> 4) << 6;          // 64 q rows per block
  const int kv0 = split << 10;           // 1024 keys per split
  const int NT = 16;

  const int tid = threadIdx.x;           // 0..127
  const int wid = tid >> 6, lane = tid & 63;
  const int m31 = lane & 31, g = lane >> 5;

  bfx8 qh[4], ql[4];
  {
    const size_t qoff = (size_t)(qb + (wid << 5) + m31) * NHD + h * 64 + (g << 3);
#pragma unroll
    for (int c = 0; c < 4; ++c) {
      qh[c] = __builtin_bit_cast(bfx8, *(const uint4*)(qkvh + qoff + (c << 4)));
      ql[c] = __builtin_bit_cast(bfx8, *(const uint4*)(qkvl + qoff + (c << 4)));
    }
  }

  f32x16 o[2];
#pragma unroll
  for (int dt = 0; dt < 2; ++dt)
#pragma unroll
    for (int j = 0; j < 16; ++j) o[dt][j] = 0.f;
  float mreg = -1e30f, lreg = 0.f;

  // staging: 4 K-chunks + 4 V-chunks, 128 threads x 16B each
  uint4 rk[4], rv[4];
  int prs[4], wis[4];
#pragma unroll
  for (int ch = 0; ch < 4; ++ch) {
    int idx = tid + (ch << 7);
    int row = idx >> 3, c32 = (idx & 7) << 2;
    prs[ch] = row;
    wis[ch] = (row << 5) + (c32 ^ swzf(row));
  }
  auto issue = [&](int kv) {
#pragma unroll
    for (int ch = 0; ch < 4; ++ch) {
      int idx = tid + (ch << 7);
      int row = idx >> 3, c32 = (idx & 7) << 2;
      rk[ch] = *(const uint4*)(qkvh + (size_t)(kv + row) * NHD + DD + h * 64 + (c32 << 1));
      rv[ch] = *(const uint4*)(vhg + ((size_t)(h * 64 + row) << 12) + kv + (c32 << 1));
    }
  };

  issue(kv0);
  for (int it = 0; it < NT; ++it) {
    __syncthreads();
#pragma unroll
    for (int ch = 0; ch < 4; ++ch) {
      *(uint4*)&sKh[wis[ch]] = rk[ch];
      *(uint4*)&sVh[wis[ch]] = rv[ch];
    }
    __syncthreads();
    if (it + 1 < NT) issue(kv0 + ((it + 1) << 6));

    // ---- S^T = K_bf16 * Q_split (2-term), log2-domain ----
    f32x16 s[2];
#pragma unroll
    for (int kt = 0; kt < 2; ++kt) {
#pragma unroll
      for (int j = 0; j < 16; ++j) s[kt][j] = 0.f;
      const int row = (kt << 5) + m31;
      const int rb = row << 5;
      const int sw2 = swzf(row);
      __builtin_amdgcn_s_setprio(1);
#pragma unroll
      for (int c = 0; c < 4; ++c) {
        int col = ((c << 3) + (g << 2)) ^ sw2;
        bfx8 kh = __builtin_bit_cast(bfx8, *(const uint4*)&sKh[rb + col]);
        s[kt] = MFMA32(kh, qh[c], s[kt]);
        s[kt] = MFMA32(kh, ql[c], s[kt]);
      }
      __builtin_amdgcn_s_setprio(0);
    }

    // ---- online softmax, lane-local for q = m31 ----
    float v16[16];
#pragma unroll
    for (int j = 0; j < 16; ++j) v16[j] = fmaxf(s[0][j], s[1][j]);
#pragma unroll
    for (int st = 8; st; st >>= 1)
#pragma unroll
      for (int j = 0; j < 8; ++j)
        if (j < st) v16[j] = fmaxf(v16[j], v16[j + st]);
    float mt = fmaxf(v16[0], __shfl_xor(v16[0], 32));
    int need = (mt > mreg + 8.f) ? 1 : 0;
    if (__any(need)) {
      float mn = fmaxf(mreg, mt);
      float al = fexp2(mreg - mn);
      mreg = mn; lreg *= al;
#pragma unroll
      for (int dt = 0; dt < 2; ++dt)
#pragma unroll
        for (int j = 0; j < 16; ++j) o[dt][j] *= al;
    }
    float p0[16], p1[16];
#pragma unroll
    for (int j = 0; j < 16; ++j) {
      p0[j] = fexp2(s[0][j] - mreg);
      p1[j] = fexp2(s[1][j] - mreg);
    }
    {
      float t16[16];
#pragma unroll
      for (int j = 0; j < 16; ++j) t16[j] = p0[j] + p1[j];
#pragma unroll
      for (int st = 8; st; st >>= 1)
#pragma unroll
        for (int j = 0; j < 8; ++j)
          if (j < st) t16[j] += t16[j + st];
      lreg += t16[0] + __shfl_xor(t16[0], 32);
    }

    // ---- pack P hi/lo in-register ----
    uint puh[2][8], pul[2][8];
#pragma unroll
    for (int kt = 0; kt < 2; ++kt)
#pragma unroll
      for (int jj = 0; jj < 8; ++jj) {
        float a = kt ? p1[2 * jj] : p0[2 * jj];
        float bq = kt ? p1[2 * jj + 1] : p0[2 * jj + 1];
        uint ua = __float_as_uint(a), ub = __float_as_uint(bq);
        puh[kt][jj] = (ua >> 16) | (ub & 0xffff0000u);
        float ra = a - __uint_as_float(ua & 0xffff0000u);
        float rb = bq - __uint_as_float(ub & 0xffff0000u);
        pul[kt][jj] = (__float_as_uint(ra) >> 16) | (__float_as_uint(rb) & 0xffff0000u);
      }

    // ---- O^T += V^T_bf16 * P_split (2-term), permuted K-order ----
#pragma unroll
    for (int dt = 0; dt < 2; ++dt) {
      const int row = (dt << 5) + m31;
      const int rb = row << 5;
      const int sw2 = swzf(row);
      __builtin_amdgcn_s_setprio(1);
#pragma unroll
      for (int kt = 0; kt < 2; ++kt)
#pragma unroll
        for (int cc = 0; cc < 2; ++cc) {
          int cA = ((kt << 4) + (cc << 3) + (g << 1)) ^ sw2;
          int cB = ((kt << 4) + (cc << 3) + (g << 1) + 4) ^ sw2;
          uint2 vh0 = *(const uint2*)&sVh[rb + cA];
          uint2 vh1 = *(const uint2*)&sVh[rb + cB];
          bfx8 ah = __builtin_bit_cast(bfx8, make_uint4(vh0.x, vh0.y, vh1.x, vh1.y));
          bfx8 bh = __builtin_bit_cast(bfx8, make_uint4(puh[kt][4 * cc], puh[kt][4 * cc + 1],
                                                        puh[kt][4 * cc + 2], puh[kt][4 * cc + 3]));
          bfx8 bl = __builtin_bit_cast(bfx8, make_uint4(pul[kt][4 * cc], pul[kt][4 * cc + 1],
                                                        pul[kt][4 * cc + 2], pul[kt][4 * cc + 3]));
          o[dt] = MFMA32(ah, bh, o[dt]);
          o[dt] = MFMA32(ah, bl, o[dt]);
        }
      __builtin_amdgcn_s_setprio(0);
    }
  }

  const int region = (split * NH + h) * (NN >> 5) + (qb >> 5) + wid;
  float* ob = opT + (size_t)region * 2048;
#pragma unroll
  for (int dt = 0; dt < 2; ++dt)
#pragma unroll
    for (int r = 0; r < 16; ++r) {
      int d = (dt << 5) + (r & 3) + ((r >> 2) << 3) + (g << 2);
      ob[(d << 5) + m31] = o[dt][r];
    }
  if (!g) {
    size_t qi = (size_t)(split * NH + h) * NN + qb + (wid << 5) + m31;
    ml[qi * 2]     = mreg;
    ml[qi * 2 + 1] = lreg;
  }
}

// ---------------- combine KV-split partials -> attn hi/lo -------------------
__global__ __launch_bounds__(256) void k_comb(const float* __restrict__ opT,
    const float* __restrict__ ml, ushort* __restrict__ attnh, ushort* __restrict__ attnl) {
  int qt = blockIdx.x, h = blockIdx.y, t = threadIdx.x;
  int qq = t & 31, dg = t >> 5;
  int q = (qt << 5) + qq;
  float ms[KVSPLIT], ls[KVSPLIT];
#pragma unroll
  for (int s = 0; s < KVSPLIT; ++s) {
    const float* e = ml + ((size_t)(s * NH + h) * NN + q) * 2;
    ms[s] = e[0]; ls[s] = e[1];
  }
  float Mx = ms[0];
#pragma unroll
  for (int s = 1; s < KVSPLIT; ++s) Mx = fmaxf(Mx, ms[s]);
  float cs[KVSPLIT], L = 0.f;
#pragma unroll
  for (int s = 0; s < KVSPLIT; ++s) { cs[s] = fexp2(ms[s] - Mx); L += ls[s] * cs[s]; }
  float invL = 1.f / L;
  float vals[8];
#pragma unroll
  for (int j = 0; j < 8; ++j) {
    int d = (dg << 3) + j;
    float acc = 0.f;
#pragma unroll
    for (int s = 0; s < KVSPLIT; ++s)
      acc += opT[((size_t)((s * NH + h) * (NN >> 5) + qt)) * 2048 + (d << 5) + qq] * cs[s];
    vals[j] = acc * invL;
  }
  ushort hs[8], lo[8];
#pragma unroll
  for (int j = 0; j < 8; ++j) {
    hs[j] = bf16_rne(vals[j]);
    lo[j] = bf16_rne(vals[j] - bf16_tof(hs[j]));
  }
  size_t oo = (size_t)q * DD + h * 64 + (dg << 3);
  *(uint4*)(attnh + oo) = make_uint4((uint)hs[0] | ((uint)hs[1] << 16), (uint)hs[2] | ((uint)hs[3] << 16),
                                     (uint)hs[4] | ((uint)hs[5] << 16), (uint)hs[6] | ((uint)hs[7] << 16));
  *(uint4*)(attnl + oo) = make_uint4((uint)lo[0] | ((uint)lo[1] << 16), (uint)lo[2] | ((uint)lo[3] << 16),
                                     (uint)lo[4] | ((uint)lo[5] << 16), (uint)lo[6] | ((uint)lo[7] << 16));
}

// ---------------- CSR (fixed-stride) + gather (bf16-hi input) ---------------
__global__ void k_hist(const int* __restrict__ dst, int* __restrict__ cnt) {
  int e = blockIdx.x * 256 + threadIdx.x;
  if (e < NE) atomicAdd(&cnt[dst[e]], 1);
}
__global__ void k_fill(const int* __restrict__ src, const int* __restrict__ dst,
    const int* __restrict__ cnt, int* cursor, int* __restrict__ lst,
    float* __restrict__ dinv) {
  int e = blockIdx.x * 256 + threadIdx.x;
  if (e < NN) dinv[e] = (float)(1.0 / sqrt((double)(cnt[e] + 1)));
  if (e < NE) {
    int d = dst[e];
    int pos = atomicAdd(&cursor[d], 1);
    if (pos < PAD) lst[(d << 7) + pos] = src[e];
  }
}
__device__ __forceinline__ float4 bf4_tof(ushort4 u) {
  return make_float4(bf16_tof(u.x), bf16_tof(u.y), bf16_tof(u.z), bf16_tof(u.w));
}
__global__ __launch_bounds__(256) void k_gather(const ushort* __restrict__ hin,
    const int* __restrict__ cnt, const int* __restrict__ lst,
    const float* __restrict__ dinv, const float* __restrict__ bias,
    float* __restrict__ outF, ushort* __restrict__ oh, ushort* __restrict__ ol,
    int relu) {
  int g = (blockIdx.x << 2) + (threadIdx.x >> 6);
  int lane = threadIdx.x & 63;
  float di = dinv[g];
  int c4 = lane << 2;
  float4 hv = bf4_tof(*(const ushort4*)(hin + (size_t)g * DD + c4));
  float w = di * di;
  float a0x = hv.x * w, a0y = hv.y * w, a0z = hv.z * w, a0w = hv.w * w;
  float a1x = 0, a1y = 0, a1z = 0, a1w = 0;
  float a2x = 0, a2y = 0, a2z = 0, a2w = 0;
  float a3x = 0, a3y = 0, a3z = 0, a3w = 0;
  int num = min(cnt[g], PAD);
  const int* lrow = lst + (g << 7);
  int i = 0;
  for (; i + 4 <= num; i += 4) {
    int4 s4 = *(const int4*)(lrow + i);
    float w0 = dinv[s4.x] * di, w1 = dinv[s4.y] * di;
    float w2 = dinv[s4.z] * di, w3 = dinv[s4.w] * di;
    float4 h0 = bf4_tof(*(const ushort4*)(hin + (size_t)s4.x * DD + c4));
    float4 h1 = bf4_tof(*(const ushort4*)(hin + (size_t)s4.y * DD + c4));
    float4 h2 = bf4_tof(*(const ushort4*)(hin + (size_t)s4.z * DD + c4));
    float4 h3 = bf4_tof(*(const ushort4*)(hin + (size_t)s4.w * DD + c4));
    a0x += h0.x * w0; a0y += h0.y * w0; a0z += h0.z * w0; a0w += h0.w * w0;
    a1x += h1.x * w1; a1y += h1.y * w1; a1z += h1.z * w1; a1w += h1.w * w1;
    a2x += h2.x * w2; a2y += h2.y * w2; a2z += h2.z * w2; a2w += h2.w * w2;
    a3x += h3.x * w3; a3y += h3.y * w3; a3z += h3.z * w3; a3w += h3.w * w3;
  }
  for (; i < num; ++i) {
    int sI = lrow[i];
    float ww = dinv[sI] * di;
    float4 hs = bf4_tof(*(const ushort4*)(hin + (size_t)sI * DD + c4));
    a0x += hs.x * ww; a0y += hs.y * ww; a0z += hs.z * ww; a0w += hs.w * ww;
  }
  float4 bv = *(const float4*)(bias + c4);
  float4 acc = make_float4((a0x + a1x) + (a2x + a3x) + bv.x,
                           (a0y + a1y) + (a2y + a3y) + bv.y,
                           (a0z + a1z) + (a2z + a3z) + bv.z,
                           (a0w + a1w) + (a2w + a3w) + bv.w);
  if (relu) {
    acc.x = fmaxf(acc.x, 0.f); acc.y = fmaxf(acc.y, 0.f);
    acc.z = fmaxf(acc.z, 0.f); acc.w = fmaxf(acc.w, 0.f);
  }
  if (outF) *(float4*)(outF + (size_t)g * DD + c4) = acc;
  if (oh) {
    ushort h0 = bf16_rne(acc.x), h1 = bf16_rne(acc.y);
    ushort h2 = bf16_rne(acc.z), h3 = bf16_rne(acc.w);
    size_t oo = (size_t)g * DD + c4;
    *(ushort4*)(oh + oo) = make_ushort4(h0, h1, h2, h3);
    *(ushort4*)(ol + oo) = make_ushort4(
        bf16_rne(acc.x - bf16_tof(h0)), bf16_rne(acc.y - bf16_tof(h1)),
        bf16_rne(acc.z - bf16_tof(h2)), bf16_rne(acc.w - bf16_tof(h3)));
  }
}

// ---------------- launch ---------------------------------------------------
extern "C" void kernel_launch(void* const* d_in, const int* in_sizes, int n_in,
                              void* d_out, int out_size, void* d_ws, size_t ws_size,
                              hipStream_t stream) {
  const float* x   = (const float*)d_in[0];
  const int*   ei  = (const int*)d_in[1];
  const float* ipw = (const float*)d_in[2];
  const float* ipb = (const float*)d_in[3];
  const float* opw = (const float*)d_in[4];
  const float* opb = (const float*)d_in[5];
  const float* W1  = (const float*)d_in[6];
  const float* b1  = (const float*)d_in[7];
  const float* W2  = (const float*)d_in[8];
  const float* b2  = (const float*)d_in[9];
  const int* srcI = ei;
  const int* dstI = ei + NE;

  char* w = (char*)d_ws;
  ushort* qkvh  = (ushort*)w; w += (size_t)NN * NHD * 2;
  ushort* qkvl  = (ushort*)w; w += (size_t)NN * NHD * 2;
  ushort* xh    = (ushort*)w; w += (size_t)NN * DD * 2;   // reused as attnh
  ushort* xl    = (ushort*)w; w += (size_t)NN * DD * 2;   // reused as attnl
  ushort* iph   = (ushort*)w; w += (size_t)NHD * DD * 2;
  ushort* ipl   = (ushort*)w; w += (size_t)NHD * DD * 2;
  ushort* w1h   = (ushort*)w; w += (size_t)DD * DD * 2;
  ushort* w1l   = (ushort*)w; w += (size_t)DD * DD * 2;
  ushort* w2h   = (ushort*)w; w += (size_t)DD * DD * 2;
  ushort* w2l   = (ushort*)w; w += (size_t)DD * DD * 2;
  ushort* opth  = (ushort*)w; w += (size_t)DD * DD * 2;
  ushort* optl  = (ushort*)w; w += (size_t)DD * DD * 2;
  ushort* wfh   = (ushort*)w; w += (size_t)DD * DD * 2;
  ushort* wfl   = (ushort*)w; w += (size_t)DD * DD * 2;
  float*  bfv   = (float*)w;  w += (size_t)DD * 4;
  ushort* vhg   = (ushort*)w; w += (size_t)NH * NN * 64 * 2;
  ushort* hlin1 = (ushort*)w; w += (size_t)NN * DD * 2;
  ushort* hlin2 = (ushort*)w; w += (size_t)NN * DD * 2;
  ushort* g1h   = (ushort*)w; w += (size_t)NN * DD * 2;
  ushort* g1l   = (ushort*)w; w += (size_t)NN * DD * 2;
  float*  opT   = (float*)w;  w += (size_t)KVSPLIT * NH * NN * 64 * 4;
  float*  ml    = (float*)w;  w += (size_t)KVSPLIT * NH * NN * 2 * 4;
  int*    cnt    = (int*)w;   w += NN * 4;
  int*    cursor = (int*)w;   w += NN * 4;
  float*  dinv   = (float*)w; w += NN * 4;
  int*    lst    = (int*)w;   w += (size_t)NN * PAD * 4;
  ushort* attnh = xh;
  ushort* attnl = xl;

  // conversions + opw^T + bfv + zero cnt/cursor
  hipLaunchKernelGGL(k_cvt5, dim3(693), dim3(256), 0, stream, x, ipw, opw, W1, W2, opb,
                     xh, xl, iph, ipl, w1h, w1l, w2h, w2l, opth, optl, bfv, cnt, cursor);
  hipLaunchKernelGGL(k_hist, dim3(NE / 256), dim3(256), 0, stream, dstI, cnt);
  hipLaunchKernelGGL(k_fill, dim3(NE / 256), dim3(256), 0, stream, srcI, dstI, cnt,
                     cursor, lst, dinv);

  // Wf = W1 * Wop  (via gemmm with W = opw^T)
  hipLaunchKernelGGL(gemmm, dim3(4, 4), dim3(256), 0, stream,
                     w1h, w1l, opth, optl, (const float*)nullptr, (float*)nullptr,
                     wfh, wfl, DD, DD, DD, 1.f, 0);

  // QKV projection (Q cols pre-scaled by 0.125*log2e)
  hipLaunchKernelGGL(gemmm, dim3(64, 12), dim3(256), 0, stream,
                     xh, xl, iph, ipl, ipb, (float*)nullptr, qkvh, qkvl,
                     NN, NHD, DD, QSCALE, DD);
  hipLaunchKernelGGL(k_cvtV, dim3(64, NH), dim3(256), 0, stream, qkvh, vhg);
  hipLaunchKernelGGL(flashm, dim3((NN / 64) * 16), dim3(128), 0, stream,
                     qkvh, qkvl, vhg, opT, ml);
  hipLaunchKernelGGL(k_comb, dim3(NN / 32, NH), dim3(256), 0, stream, opT, ml, attnh, attnl);

  // fused out-proj + GCN1 linear: hlin1 = attn * Wf^T + W1*bop  (bf16-hi out)
  hipLaunchKernelGGL(gemmm, dim3(64, 4), dim3(256), 0, stream,
                     attnh, attnl, wfh, wfl, bfv, (float*)nullptr,
                     hlin1, (ushort*)nullptr, NN, DD, DD, 1.f, 0);
  hipLaunchKernelGGL(k_gather, dim3(NN / 4), dim3(256), 0, stream, hlin1, cnt, lst,
                     dinv, b1, (float*)nullptr, g1h, g1l, 1);
  // GCN2
  hipLaunchKernelGGL(gemmm, dim3(64, 4), dim3(256), 0, stream,
                     g1h, g1l, w2h, w2l, (const float*)nullptr, (float*)nullptr,
                     hlin2, (ushort*)nullptr, NN, DD, DD, 1.f, 0);
  hipLaunchKernelGGL(k_gather, dim3(NN / 4), dim3(256), 0, stream, hlin2, cnt, lst,
                     dinv, b2, (float*)d_out, (ushort*)nullptr, (ushort*)nullptr, 0);
}

// Round 7
// 137.505 us; speedup vs baseline: 1.8658x; 1.8658x over previous
//
#include <hip/hip_runtime.h>
#include <math.h>

#define NN   4096
#define DD   256
#define NHD  768
#define NH   4
#define NE   131072
#define KVSPLIT 4
#define PAD  128
#define QSCALE 0.18033688011112042f   // 0.125 * log2(e)

using bfx8   = __attribute__((ext_vector_type(8))) short;
using f32x4  = __attribute__((ext_vector_type(4))) float;
using f32x16 = __attribute__((ext_vector_type(16))) float;
#define MFMA16(a,b,c) __builtin_amdgcn_mfma_f32_16x16x32_bf16(a, b, c, 0, 0, 0)
#define MFMA32(a,b,c) __builtin_amdgcn_mfma_f32_32x32x16_bf16(a, b, c, 0, 0, 0)

__device__ __forceinline__ ushort bf16_rne(float f) {
  uint u = __float_as_uint(f);
  u += 0x7fffu + ((u >> 16) & 1u);
  return (ushort)(u >> 16);
}
__device__ __forceinline__ float bf16_tof(ushort h) {
  return __uint_as_float(((uint)h) << 16);
}
__device__ __forceinline__ float fexp2(float x) { return __builtin_amdgcn_exp2f(x); }
__device__ __forceinline__ int swzf(int row) {   // u32-index XOR mask, bits 2..4
  return ((row & 7) << 2) ^ ((row & 8) << 1);
}
__device__ __forceinline__ void split8(const float* f, uint4& uh, uint4& ul) {
  ushort hs[8], ls[8];
#pragma unroll
  for (int j = 0; j < 8; ++j) {
    hs[j] = bf16_rne(f[j]);
    ls[j] = bf16_rne(f[j] - bf16_tof(hs[j]));
  }
  uh = make_uint4((uint)hs[0] | ((uint)hs[1] << 16), (uint)hs[2] | ((uint)hs[3] << 16),
                  (uint)hs[4] | ((uint)hs[5] << 16), (uint)hs[6] | ((uint)hs[7] << 16));
  ul = make_uint4((uint)ls[0] | ((uint)ls[1] << 16), (uint)ls[2] | ((uint)ls[3] << 16),
                  (uint)ls[4] | ((uint)ls[5] << 16), (uint)ls[6] | ((uint)ls[7] << 16));
}

// ---------------- split-bf16 MFMA GEMM, async-staged ------------------------
__global__ __launch_bounds__(256, 4) void gemmm(
    const ushort* __restrict__ Ahi, const ushort* __restrict__ Alo,
    const ushort* __restrict__ Whi, const ushort* __restrict__ Wlo,
    const float* __restrict__ bias, float* __restrict__ Cf,
    ushort* __restrict__ Chi, ushort* __restrict__ Clo,
    int M, int Nc, int K, float preScale, int preScaleCols) {
  __shared__ uint sAh[2048], sAl[2048], sBh[2048], sBl[2048];
  const int tid = threadIdx.x;
  const int wid = tid >> 6, lane = tid & 63;
  const int m15 = lane & 15, g2 = lane >> 4;
  const int wr = wid >> 1, wc = wid & 1;
  const int mb = blockIdx.x << 6, nb = blockIdx.y << 6;
  const int sw = swzf(m15);
  const int pr0 = tid >> 3, pc0 = (tid & 7) << 2;
  const int pr1 = (tid + 256) >> 3, pc1 = pc0;
  const int wi0 = (pr0 << 5) + (pc0 ^ swzf(pr0));
  const int wi1 = (pr1 << 5) + (pc1 ^ swzf(pr1));
  uint4 rah0, ral0, rbh0, rbl0, rah1, ral1, rbh1, rbl1;
  auto issue = [&](int k0) {
    size_t a0 = (size_t)(mb + pr0) * K + k0 + (pc0 << 1);
    size_t a1 = (size_t)(mb + pr1) * K + k0 + (pc1 << 1);
    size_t b0 = (size_t)(nb + pr0) * K + k0 + (pc0 << 1);
    size_t b1 = (size_t)(nb + pr1) * K + k0 + (pc1 << 1);
    rah0 = *(const uint4*)(Ahi + a0); ral0 = *(const uint4*)(Alo + a0);
    rah1 = *(const uint4*)(Ahi + a1); ral1 = *(const uint4*)(Alo + a1);
    rbh0 = *(const uint4*)(Whi + b0); rbl0 = *(const uint4*)(Wlo + b0);
    rbh1 = *(const uint4*)(Whi + b1); rbl1 = *(const uint4*)(Wlo + b1);
  };
  f32x4 acc[2][2];
#pragma unroll
  for (int r = 0; r < 2; ++r)
#pragma unroll
    for (int c = 0; c < 2; ++c) acc[r][c] = (f32x4){0.f, 0.f, 0.f, 0.f};

  issue(0);
  for (int k0 = 0; k0 < K; k0 += 64) {
    __syncthreads();
    *(uint4*)&sAh[wi0] = rah0; *(uint4*)&sAl[wi0] = ral0;
    *(uint4*)&sBh[wi0] = rbh0; *(uint4*)&sBl[wi0] = rbl0;
    *(uint4*)&sAh[wi1] = rah1; *(uint4*)&sAl[wi1] = ral1;
    *(uint4*)&sBh[wi1] = rbh1; *(uint4*)&sBl[wi1] = rbl1;
    __syncthreads();
    if (k0 + 64 < K) issue(k0 + 64);
#pragma unroll
    for (int c = 0; c < 2; ++c) {
      bfx8 ah[2], alo[2], bh[2], blo[2];
#pragma unroll
      for (int r = 0; r < 2; ++r) {
        int rowA = (wr << 5) + (r << 4) + m15;
        int idxA = (rowA << 5) + (((c << 4) + (g2 << 2)) ^ sw);
        ah[r]  = __builtin_bit_cast(bfx8, *(const uint4*)&sAh[idxA]);
        alo[r] = __builtin_bit_cast(bfx8, *(const uint4*)&sAl[idxA]);
        int rowB = (wc << 5) + (r << 4) + m15;
        int idxB = (rowB << 5) + (((c << 4) + (g2 << 2)) ^ sw);
        bh[r]  = __builtin_bit_cast(bfx8, *(const uint4*)&sBh[idxB]);
        blo[r] = __builtin_bit_cast(bfx8, *(const uint4*)&sBl[idxB]);
      }
#pragma unroll
      for (int r = 0; r < 2; ++r)
#pragma unroll
        for (int cc = 0; cc < 2; ++cc) {
          acc[r][cc] = MFMA16(ah[r], bh[cc], acc[r][cc]);
          acc[r][cc] = MFMA16(ah[r], blo[cc], acc[r][cc]);
          acc[r][cc] = MFMA16(alo[r], bh[cc], acc[r][cc]);
        }
    }
  }
#pragma unroll
  for (int r = 0; r < 2; ++r)
#pragma unroll
    for (int cc = 0; cc < 2; ++cc) {
      int col = nb + (wc << 5) + (cc << 4) + m15;
      float bv = bias ? bias[col] : 0.f;
      float sc = (col < preScaleCols) ? preScale : 1.f;
#pragma unroll
      for (int j = 0; j < 4; ++j) {
        int row = mb + (wr << 5) + (r << 4) + (g2 << 2) + j;
        float v = (acc[r][cc][j] + bv) * sc;
        if (Cf) Cf[(size_t)row * Nc + col] = v;
        if (Chi) {
          ushort hi = bf16_rne(v);
          Chi[(size_t)row * Nc + col] = hi;
          if (Clo) Clo[(size_t)row * Nc + col] = bf16_rne(v - bf16_tof(hi));
        }
      }
    }
}

// ------- convert x/ipw/W1/W2 to hi/lo; zero cnt/cursor; opw^T; bfv ----------
__global__ __launch_bounds__(256) void k_cvt5(
    const float* __restrict__ x, const float* __restrict__ ipw,
    const float* __restrict__ opw, const float* __restrict__ W1,
    const float* __restrict__ W2, const float* __restrict__ opb,
    ushort* xh, ushort* xl, ushort* iph, ushort* ipl,
    ushort* w1h, ushort* w1l, ushort* w2h, ushort* w2l,
    ushort* opth, ushort* optl, float* bfv,
    int* cnt, int* cursor) {
  __shared__ float sT[64 * 65];
  int b = blockIdx.x;
  if (b >= 672) {
    if (b < 676) {                       // zero cnt+cursor
      int i = ((b - 672) * 256 + threadIdx.x) * 4;
      *(int4*)(cnt + i) = make_int4(0, 0, 0, 0);
      *(int4*)(cursor + i) = make_int4(0, 0, 0, 0);
    } else if (b < 692) {                // transpose-convert opw -> opth/optl
      int tx = b - 676, by = tx >> 2, bx = tx & 3;
      int r = threadIdx.x >> 2, cb = (threadIdx.x & 3) << 4;
      const float* src = opw + (size_t)(by * 64 + r) * 256 + bx * 64 + cb;
#pragma unroll
      for (int i = 0; i < 4; ++i) {
        float4 v = *(const float4*)(src + i * 4);
        sT[r * 65 + cb + i * 4 + 0] = v.x; sT[r * 65 + cb + i * 4 + 1] = v.y;
        sT[r * 65 + cb + i * 4 + 2] = v.z; sT[r * 65 + cb + i * 4 + 3] = v.w;
      }
      __syncthreads();
      int d = threadIdx.x >> 2, nb2 = (threadIdx.x & 3) << 4;
      float f[16];
#pragma unroll
      for (int i = 0; i < 16; ++i) f[i] = sT[(nb2 + i) * 65 + d];
      uint4 uh0, ul0, uh1, ul1;
      split8(&f[0], uh0, ul0); split8(&f[8], uh1, ul1);
      size_t o = (size_t)(bx * 64 + d) * 256 + by * 64 + nb2;
      *(uint4*)(opth + o) = uh0; *(uint4*)(opth + o + 8) = uh1;
      *(uint4*)(optl + o) = ul0; *(uint4*)(optl + o + 8) = ul1;
    } else {                             // bfv = W1 * opb
      int t = threadIdx.x;
      sT[t] = opb[t];
      __syncthreads();
      float acc = 0.f;
      const float* wr = W1 + (size_t)t * 256;
      for (int k = 0; k < 256; ++k) acc += wr[k] * sT[k];
      bfv[t] = acc;
    }
    return;
  }
  const float* src; ushort* hi; ushort* lo; int base;
  if (b < 512)      { src = x;   hi = xh;  lo = xl;  base = b; }
  else if (b < 608) { src = ipw; hi = iph; lo = ipl; base = b - 512; }
  else if (b < 640) { src = W1;  hi = w1h; lo = w1l; base = b - 608; }
  else              { src = W2;  hi = w2h; lo = w2l; base = b - 640; }
  size_t i = (size_t)base * 256 + threadIdx.x;
  float f[8];
  *(float4*)&f[0] = *(const float4*)(src + i * 8);
  *(float4*)&f[4] = *(const float4*)(src + i * 8 + 4);
  uint4 uh, ul; split8(f, uh, ul);
  *(uint4*)(hi + i * 8) = uh;
  *(uint4*)(lo + i * 8) = ul;
}

// ---------------- repack V (hi only) to transposed [h][d][n] ----------------
__global__ __launch_bounds__(256) void k_cvtV(const ushort* __restrict__ qh,
    ushort* __restrict__ vhg) {
  __shared__ ushort sh[64 * 72];
  int n0 = blockIdx.x << 6, h = blockIdx.y, t = threadIdx.x;
  {
    int nn = t >> 2, cb = (t & 3) << 4;
    size_t off = (size_t)(n0 + nn) * NHD + 2 * DD + h * 64 + cb;
    *(uint4*)&sh[nn * 72 + cb]     = *(const uint4*)(qh + off);
    *(uint4*)&sh[nn * 72 + cb + 8] = *(const uint4*)(qh + off + 8);
  }
  __syncthreads();
  {
    int d = t >> 2, nb = (t & 3) << 4;
    ushort oh[16];
#pragma unroll
    for (int i = 0; i < 16; ++i) oh[i] = sh[(nb + i) * 72 + d];
    size_t o = ((size_t)(h * 64 + d) << 12) + n0 + nb;
    *(uint4*)(vhg + o)     = *(uint4*)&oh[0];
    *(uint4*)(vhg + o + 8) = *(uint4*)&oh[8];
  }
}

// ------- MFMA 32x32 swapped-operand flash, 2-term QK / 2-term PV ------------
// Round-5 proven shape: 256 threads, 128 q rows, grid 512 (L2-friendly).
// K,V bf16-hi only in LDS (16 KB); Q and P keep hi/lo.
__global__ __launch_bounds__(256, 2) void flashm(
    const ushort* __restrict__ qkvh, const ushort* __restrict__ qkvl,
    const ushort* __restrict__ vhg,
    float* __restrict__ opT, float* __restrict__ ml) {
  __shared__ uint sKh[2048], sVh[2048];   // 16 KB

  const int b = blockIdx.x;
  const int id = b & 15;                 // (h,split): co-located per XCD
  const int h = id >> 2, split = id & 3;
  const int qb = (b >> 4) << 7;          // 128 q rows per block
  const int kv0 = split << 10;           // 1024 keys per split
  const int NT = 16;

  const int tid = threadIdx.x;
  const int wid = tid >> 6, lane = tid & 63;
  const int m31 = lane & 31, g = lane >> 5;

  bfx8 qh[4], ql[4];
  {
    const size_t qoff = (size_t)(qb + (wid << 5) + m31) * NHD + h * 64 + (g << 3);
#pragma unroll
    for (int c = 0; c < 4; ++c) {
      qh[c] = __builtin_bit_cast(bfx8, *(const uint4*)(qkvh + qoff + (c << 4)));
      ql[c] = __builtin_bit_cast(bfx8, *(const uint4*)(qkvl + qoff + (c << 4)));
    }
  }

  f32x16 o[2];
#pragma unroll
  for (int dt = 0; dt < 2; ++dt)
#pragma unroll
    for (int j = 0; j < 16; ++j) o[dt][j] = 0.f;
  float mreg = -1e30f, lreg = 0.f;

  // staging: 2 chunks of 256 threads x 16B (K tile 8 KB + V tile 8 KB)
  const int pr0 = tid >> 3, pc0 = (tid & 7) << 2;
  const int pr1 = (tid + 256) >> 3;
  const int wi0 = (pr0 << 5) + (pc0 ^ swzf(pr0));
  const int wi1 = (pr1 << 5) + (pc0 ^ swzf(pr1));
  uint4 rk0, rk1, rv0, rv1;
  auto issue = [&](int kv) {
    rk0 = *(const uint4*)(qkvh + (size_t)(kv + pr0) * NHD + DD + h * 64 + (pc0 << 1));
    rk1 = *(const uint4*)(qkvh + (size_t)(kv + pr1) * NHD + DD + h * 64 + (pc0 << 1));
    rv0 = *(const uint4*)(vhg + ((size_t)(h * 64 + pr0) << 12) + kv + (pc0 << 1));
    rv1 = *(const uint4*)(vhg + ((size_t)(h * 64 + pr1) << 12) + kv + (pc0 << 1));
  };

  issue(kv0);
  for (int it = 0; it < NT; ++it) {
    __syncthreads();
    *(uint4*)&sKh[wi0] = rk0; *(uint4*)&sVh[wi0] = rv0;
    *(uint4*)&sKh[wi1] = rk1; *(uint4*)&sVh[wi1] = rv1;
    __syncthreads();
    if (it + 1 < NT) issue(kv0 + ((it + 1) << 6));

    // ---- S^T = K_bf16 * Q_split (2-term), log2-domain ----
    f32x16 s[2];
#pragma unroll
    for (int kt = 0; kt < 2; ++kt) {
#pragma unroll
      for (int j = 0; j < 16; ++j) s[kt][j] = 0.f;
      const int row = (kt << 5) + m31;
      const int rb = row << 5;
      const int sw2 = swzf(row);
      __builtin_amdgcn_s_setprio(1);
#pragma unroll
      for (int c = 0; c < 4; ++c) {
        int col = ((c << 3) + (g << 2)) ^ sw2;
        bfx8 kh = __builtin_bit_cast(bfx8, *(const uint4*)&sKh[rb + col]);
        s[kt] = MFMA32(kh, qh[c], s[kt]);
        s[kt] = MFMA32(kh, ql[c], s[kt]);
      }
      __builtin_amdgcn_s_setprio(0);
    }

    // ---- online softmax, lane-local for q = m31 ----
    float v16[16];
#pragma unroll
    for (int j = 0; j < 16; ++j) v16[j] = fmaxf(s[0][j], s[1][j]);
#pragma unroll
    for (int st = 8; st; st >>= 1)
#pragma unroll
      for (int j = 0; j < 8; ++j)
        if (j < st) v16[j] = fmaxf(v16[j], v16[j + st]);
    float mt = fmaxf(v16[0], __shfl_xor(v16[0], 32));
    int need = (mt > mreg + 8.f) ? 1 : 0;
    if (__any(need)) {
      float mn = fmaxf(mreg, mt);
      float al = fexp2(mreg - mn);
      mreg = mn; lreg *= al;
#pragma unroll
      for (int dt = 0; dt < 2; ++dt)
#pragma unroll
        for (int j = 0; j < 16; ++j) o[dt][j] *= al;
    }
    float p0[16], p1[16];
#pragma unroll
    for (int j = 0; j < 16; ++j) {
      p0[j] = fexp2(s[0][j] - mreg);
      p1[j] = fexp2(s[1][j] - mreg);
    }
    {
      float t16[16];
#pragma unroll
      for (int j = 0; j < 16; ++j) t16[j] = p0[j] + p1[j];
#pragma unroll
      for (int st = 8; st; st >>= 1)
#pragma unroll
        for (int j = 0; j < 8; ++j)
          if (j < st) t16[j] += t16[j + st];
      lreg += t16[0] + __shfl_xor(t16[0], 32);
    }

    // ---- pack P hi/lo in-register ----
    uint puh[2][8], pul[2][8];
#pragma unroll
    for (int kt = 0; kt < 2; ++kt)
#pragma unroll
      for (int jj = 0; jj < 8; ++jj) {
        float a = kt ? p1[2 * jj] : p0[2 * jj];
        float bq = kt ? p1[2 * jj + 1] : p0[2 * jj + 1];
        uint ua = __float_as_uint(a), ub = __float_as_uint(bq);
        puh[kt][jj] = (ua >> 16) | (ub & 0xffff0000u);
        float ra = a - __uint_as_float(ua & 0xffff0000u);
        float rb = bq - __uint_as_float(ub & 0xffff0000u);
        pul[kt][jj] = (__float_as_uint(ra) >> 16) | (__float_as_uint(rb) & 0xffff0000u);
      }

    // ---- O^T += V^T_bf16 * P_split (2-term), permuted K-order ----
#pragma unroll
    for (int dt = 0; dt < 2; ++dt) {
      const int row = (dt << 5) + m31;
      const int rb = row << 5;
      const int sw2 = swzf(row);
      __builtin_amdgcn_s_setprio(1);
#pragma unroll
      for (int kt = 0; kt < 2; ++kt)
#pragma unroll
        for (int cc = 0; cc < 2; ++cc) {
          int cA = ((kt << 4) + (cc << 3) + (g << 1)) ^ sw2;
          int cB = ((kt << 4) + (cc << 3) + (g << 1) + 4) ^ sw2;
          uint2 vh0 = *(const uint2*)&sVh[rb + cA];
          uint2 vh1 = *(const uint2*)&sVh[rb + cB];
          bfx8 ah = __builtin_bit_cast(bfx8, make_uint4(vh0.x, vh0.y, vh1.x, vh1.y));
          bfx8 bh = __builtin_bit_cast(bfx8, make_uint4(puh[kt][4 * cc], puh[kt][4 * cc + 1],
                                                        puh[kt][4 * cc + 2], puh[kt][4 * cc + 3]));
          bfx8 bl = __builtin_bit_cast(bfx8, make_uint4(pul[kt][4 * cc], pul[kt][4 * cc + 1],
                                                        pul[kt][4 * cc + 2], pul[kt][4 * cc + 3]));
          o[dt] = MFMA32(ah, bh, o[dt]);
          o[dt] = MFMA32(ah, bl, o[dt]);
        }
      __builtin_amdgcn_s_setprio(0);
    }
  }

  const int region = (split * NH + h) * (NN >> 5) + (qb >> 5) + wid;
  float* ob = opT + (size_t)region * 2048;
#pragma unroll
  for (int dt = 0; dt < 2; ++dt)
#pragma unroll
    for (int r = 0; r < 16; ++r) {
      int d = (dt << 5) + (r & 3) + ((r >> 2) << 3) + (g << 2);
      ob[(d << 5) + m31] = o[dt][r];
    }
  if (!g) {
    size_t qi = (size_t)(split * NH + h) * NN + qb + (wid << 5) + m31;
    ml[qi * 2]     = mreg;
    ml[qi * 2 + 1] = lreg;
  }
}

// ---------------- combine KV-split partials -> attn hi/lo -------------------
__global__ __launch_bounds__(256) void k_comb(const float* __restrict__ opT,
    const float* __restrict__ ml, ushort* __restrict__ attnh, ushort* __restrict__ attnl) {
  int qt = blockIdx.x, h = blockIdx.y, t = threadIdx.x;
  int qq = t & 31, dg = t >> 5;
  int q = (qt << 5) + qq;
  float ms[KVSPLIT], ls[KVSPLIT];
#pragma unroll
  for (int s = 0; s < KVSPLIT; ++s) {
    const float* e = ml + ((size_t)(s * NH + h) * NN + q) * 2;
    ms[s] = e[0]; ls[s] = e[1];
  }
  float Mx = ms[0];
#pragma unroll
  for (int s = 1; s < KVSPLIT; ++s) Mx = fmaxf(Mx, ms[s]);
  float cs[KVSPLIT], L = 0.f;
#pragma unroll
  for (int s = 0; s < KVSPLIT; ++s) { cs[s] = fexp2(ms[s] - Mx); L += ls[s] * cs[s]; }
  float invL = 1.f / L;
  float vals[8];
#pragma unroll
  for (int j = 0; j < 8; ++j) {
    int d = (dg << 3) + j;
    float acc = 0.f;
#pragma unroll
    for (int s = 0; s < KVSPLIT; ++s)
      acc += opT[((size_t)((s * NH + h) * (NN >> 5) + qt)) * 2048 + (d << 5) + qq] * cs[s];
    vals[j] = acc * invL;
  }
  ushort hs[8], lo[8];
#pragma unroll
  for (int j = 0; j < 8; ++j) {
    hs[j] = bf16_rne(vals[j]);
    lo[j] = bf16_rne(vals[j] - bf16_tof(hs[j]));
  }
  size_t oo = (size_t)q * DD + h * 64 + (dg << 3);
  *(uint4*)(attnh + oo) = make_uint4((uint)hs[0] | ((uint)hs[1] << 16), (uint)hs[2] | ((uint)hs[3] << 16),
                                     (uint)hs[4] | ((uint)hs[5] << 16), (uint)hs[6] | ((uint)hs[7] << 16));
  *(uint4*)(attnl + oo) = make_uint4((uint)lo[0] | ((uint)lo[1] << 16), (uint)lo[2] | ((uint)lo[3] << 16),
                                     (uint)lo[4] | ((uint)lo[5] << 16), (uint)lo[6] | ((uint)lo[7] << 16));
}

// ---------------- CSR (fixed-stride) + gather (bf16-hi input) ---------------
__global__ void k_hist(const int* __restrict__ dst, int* __restrict__ cnt) {
  int e = blockIdx.x * 256 + threadIdx.x;
  if (e < NE) atomicAdd(&cnt[dst[e]], 1);
}
__global__ void k_fill(const int* __restrict__ src, const int* __restrict__ dst,
    const int* __restrict__ cnt, int* cursor, int* __restrict__ lst,
    float* __restrict__ dinv) {
  int e = blockIdx.x * 256 + threadIdx.x;
  if (e < NN) dinv[e] = (float)(1.0 / sqrt((double)(cnt[e] + 1)));
  if (e < NE) {
    int d = dst[e];
    int pos = atomicAdd(&cursor[d], 1);
    if (pos < PAD) lst[(d << 7) + pos] = src[e];
  }
}
__device__ __forceinline__ float4 bf4_tof(ushort4 u) {
  return make_float4(bf16_tof(u.x), bf16_tof(u.y), bf16_tof(u.z), bf16_tof(u.w));
}
__global__ __launch_bounds__(256) void k_gather(const ushort* __restrict__ hin,
    const int* __restrict__ cnt, const int* __restrict__ lst,
    const float* __restrict__ dinv, const float* __restrict__ bias,
    float* __restrict__ outF, ushort* __restrict__ oh, ushort* __restrict__ ol,
    int relu) {
  int g = (blockIdx.x << 2) + (threadIdx.x >> 6);
  int lane = threadIdx.x & 63;
  float di = dinv[g];
  int c4 = lane << 2;
  float4 hv = bf4_tof(*(const ushort4*)(hin + (size_t)g * DD + c4));
  float w = di * di;
  float a0x = hv.x * w, a0y = hv.y * w, a0z = hv.z * w, a0w = hv.w * w;
  float a1x = 0, a1y = 0, a1z = 0, a1w = 0;
  float a2x = 0, a2y = 0, a2z = 0, a2w = 0;
  float a3x = 0, a3y = 0, a3z = 0, a3w = 0;
  int num = min(cnt[g], PAD);
  const int* lrow = lst + (g << 7);
  int i = 0;
  for (; i + 4 <= num; i += 4) {
    int4 s4 = *(const int4*)(lrow + i);
    float w0 = dinv[s4.x] * di, w1 = dinv[s4.y] * di;
    float w2 = dinv[s4.z] * di, w3 = dinv[s4.w] * di;
    float4 h0 = bf4_tof(*(const ushort4*)(hin + (size_t)s4.x * DD + c4));
    float4 h1 = bf4_tof(*(const ushort4*)(hin + (size_t)s4.y * DD + c4));
    float4 h2 = bf4_tof(*(const ushort4*)(hin + (size_t)s4.z * DD + c4));
    float4 h3 = bf4_tof(*(const ushort4*)(hin + (size_t)s4.w * DD + c4));
    a0x += h0.x * w0; a0y += h0.y * w0; a0z += h0.z * w0; a0w += h0.w * w0;
    a1x += h1.x * w1; a1y += h1.y * w1; a1z += h1.z * w1; a1w += h1.w * w1;
    a2x += h2.x * w2; a2y += h2.y * w2; a2z += h2.z * w2; a2w += h2.w * w2;
    a3x += h3.x * w3; a3y += h3.y * w3; a3z += h3.z * w3; a3w += h3.w * w3;
  }
  for (; i < num; ++i) {
    int sI = lrow[i];
    float ww = dinv[sI] * di;
    float4 hs = bf4_tof(*(const ushort4*)(hin + (size_t)sI * DD + c4));
    a0x += hs.x * ww; a0y += hs.y * ww; a0z += hs.z * ww; a0w += hs.w * ww;
  }
  float4 bv = *(const float4*)(bias + c4);
  float4 acc = make_float4((a0x + a1x) + (a2x + a3x) + bv.x,
                           (a0y + a1y) + (a2y + a3y) + bv.y,
                           (a0z + a1z) + (a2z + a3z) + bv.z,
                           (a0w + a1w) + (a2w + a3w) + bv.w);
  if (relu) {
    acc.x = fmaxf(acc.x, 0.f); acc.y = fmaxf(acc.y, 0.f);
    acc.z = fmaxf(acc.z, 0.f); acc.w = fmaxf(acc.w, 0.f);
  }
  if (outF) *(float4*)(outF + (size_t)g * DD + c4) = acc;
  if (oh) {
    ushort h0 = bf16_rne(acc.x), h1 = bf16_rne(acc.y);
    ushort h2 = bf16_rne(acc.z), h3 = bf16_rne(acc.w);
    size_t oo = (size_t)g * DD + c4;
    *(ushort4*)(oh + oo) = make_ushort4(h0, h1, h2, h3);
    *(ushort4*)(ol + oo) = make_ushort4(
        bf16_rne(acc.x - bf16_tof(h0)), bf16_rne(acc.y - bf16_tof(h1)),
        bf16_rne(acc.z - bf16_tof(h2)), bf16_rne(acc.w - bf16_tof(h3)));
  }
}

// ---------------- launch ---------------------------------------------------
extern "C" void kernel_launch(void* const* d_in, const int* in_sizes, int n_in,
                              void* d_out, int out_size, void* d_ws, size_t ws_size,
                              hipStream_t stream) {
  const float* x   = (const float*)d_in[0];
  const int*   ei  = (const int*)d_in[1];
  const float* ipw = (const float*)d_in[2];
  const float* ipb = (const float*)d_in[3];
  const float* opw = (const float*)d_in[4];
  const float* opb = (const float*)d_in[5];
  const float* W1  = (const float*)d_in[6];
  const float* b1  = (const float*)d_in[7];
  const float* W2  = (const float*)d_in[8];
  const float* b2  = (const float*)d_in[9];
  const int* srcI = ei;
  const int* dstI = ei + NE;

  char* w = (char*)d_ws;
  ushort* qkvh  = (ushort*)w; w += (size_t)NN * NHD * 2;
  ushort* qkvl  = (ushort*)w; w += (size_t)NN * NHD * 2;
  ushort* xh    = (ushort*)w; w += (size_t)NN * DD * 2;   // reused as attnh
  ushort* xl    = (ushort*)w; w += (size_t)NN * DD * 2;   // reused as attnl
  ushort* iph   = (ushort*)w; w += (size_t)NHD * DD * 2;
  ushort* ipl   = (ushort*)w; w += (size_t)NHD * DD * 2;
  ushort* w1h   = (ushort*)w; w += (size_t)DD * DD * 2;
  ushort* w1l   = (ushort*)w; w += (size_t)DD * DD * 2;
  ushort* w2h   = (ushort*)w; w += (size_t)DD * DD * 2;
  ushort* w2l   = (ushort*)w; w += (size_t)DD * DD * 2;
  ushort* opth  = (ushort*)w; w += (size_t)DD * DD * 2;
  ushort* optl  = (ushort*)w; w += (size_t)DD * DD * 2;
  ushort* wfh   = (ushort*)w; w += (size_t)DD * DD * 2;
  ushort* wfl   = (ushort*)w; w += (size_t)DD * DD * 2;
  float*  bfv   = (float*)w;  w += (size_t)DD * 4;
  ushort* vhg   = (ushort*)w; w += (size_t)NH * NN * 64 * 2;
  ushort* hlin1 = (ushort*)w; w += (size_t)NN * DD * 2;
  ushort* hlin2 = (ushort*)w; w += (size_t)NN * DD * 2;
  ushort* g1h   = (ushort*)w; w += (size_t)NN * DD * 2;
  ushort* g1l   = (ushort*)w; w += (size_t)NN * DD * 2;
  float*  opT   = (float*)w;  w += (size_t)KVSPLIT * NH * NN * 64 * 4;
  float*  ml    = (float*)w;  w += (size_t)KVSPLIT * NH * NN * 2 * 4;
  int*    cnt    = (int*)w;   w += NN * 4;
  int*    cursor = (int*)w;   w += NN * 4;
  float*  dinv   = (float*)w; w += NN * 4;
  int*    lst    = (int*)w;   w += (size_t)NN * PAD * 4;
  ushort* attnh = xh;
  ushort* attnl = xl;

  // conversions + opw^T + bfv + zero cnt/cursor
  hipLaunchKernelGGL(k_cvt5, dim3(693), dim3(256), 0, stream, x, ipw, opw, W1, W2, opb,
                     xh, xl, iph, ipl, w1h, w1l, w2h, w2l, opth, optl, bfv, cnt, cursor);
  hipLaunchKernelGGL(k_hist, dim3(NE / 256), dim3(256), 0, stream, dstI, cnt);
  hipLaunchKernelGGL(k_fill, dim3(NE / 256), dim3(256), 0, stream, srcI, dstI, cnt,
                     cursor, lst, dinv);

  // Wf = W1 * Wop  (via gemmm with W = opw^T)
  hipLaunchKernelGGL(gemmm, dim3(4, 4), dim3(256), 0, stream,
                     w1h, w1l, opth, optl, (const float*)nullptr, (float*)nullptr,
                     wfh, wfl, DD, DD, DD, 1.f, 0);

  // QKV projection (Q cols pre-scaled by 0.125*log2e)
  hipLaunchKernelGGL(gemmm, dim3(64, 12), dim3(256), 0, stream,
                     xh, xl, iph, ipl, ipb, (float*)nullptr, qkvh, qkvl,
                     NN, NHD, DD, QSCALE, DD);
  hipLaunchKernelGGL(k_cvtV, dim3(64, NH), dim3(256), 0, stream, qkvh, vhg);
  hipLaunchKernelGGL(flashm, dim3((NN / 128) * 16), dim3(256), 0, stream,
                     qkvh, qkvl, vhg, opT, ml);
  hipLaunchKernelGGL(k_comb, dim3(NN / 32, NH), dim3(256), 0, stream, opT, ml, attnh, attnl);

  // fused out-proj + GCN1 linear: hlin1 = attn * Wf^T + W1*bop  (bf16-hi out)
  hipLaunchKernelGGL(gemmm, dim3(64, 4), dim3(256), 0, stream,
                     attnh, attnl, wfh, wfl, bfv, (float*)nullptr,
                     hlin1, (ushort*)nullptr, NN, DD, DD, 1.f, 0);
  hipLaunchKernelGGL(k_gather, dim3(NN / 4), dim3(256), 0, stream, hlin1, cnt, lst,
                     dinv, b1, (float*)nullptr, g1h, g1l, 1);
  // GCN2
  hipLaunchKernelGGL(gemmm, dim3(64, 4), dim3(256), 0, stream,
                     g1h, g1l, w2h, w2l, (const float*)nullptr, (float*)nullptr,
                     hlin2, (ushort*)nullptr, NN, DD, DD, 1.f, 0);
  hipLaunchKernelGGL(k_gather, dim3(NN / 4), dim3(256), 0, stream, hlin2, cnt, lst,
                     dinv, b2, (float*)d_out, (ushort*)nullptr, (ushort*)nullptr, 0);
}

// Round 8
// 137.173 us; speedup vs baseline: 1.8703x; 1.0024x over previous
//
#include <hip/hip_runtime.h>
#include <math.h>

#define NN   4096
#define DD   256
#define NHD  768
#define NH   4
#define NE   131072
#define KVSPLIT 4
#define PAD  128
#define QSCALE 0.18033688011112042f   // 0.125 * log2(e)

using bfx8   = __attribute__((ext_vector_type(8))) short;
using f32x4  = __attribute__((ext_vector_type(4))) float;
using f32x16 = __attribute__((ext_vector_type(16))) float;
#define MFMA16(a,b,c) __builtin_amdgcn_mfma_f32_16x16x32_bf16(a, b, c, 0, 0, 0)
#define MFMA32(a,b,c) __builtin_amdgcn_mfma_f32_32x32x16_bf16(a, b, c, 0, 0, 0)

__device__ __forceinline__ ushort bf16_rne(float f) {
  uint u = __float_as_uint(f);
  u += 0x7fffu + ((u >> 16) & 1u);
  return (ushort)(u >> 16);
}
__device__ __forceinline__ float bf16_tof(ushort h) {
  return __uint_as_float(((uint)h) << 16);
}
__device__ __forceinline__ float fexp2(float x) { return __builtin_amdgcn_exp2f(x); }
__device__ __forceinline__ int swzf(int row) {   // u32-index XOR mask, bits 2..4
  return ((row & 7) << 2) ^ ((row & 8) << 1);
}
__device__ __forceinline__ void split8(const float* f, uint4& uh, uint4& ul) {
  ushort hs[8], ls[8];
#pragma unroll
  for (int j = 0; j < 8; ++j) {
    hs[j] = bf16_rne(f[j]);
    ls[j] = bf16_rne(f[j] - bf16_tof(hs[j]));
  }
  uh = make_uint4((uint)hs[0] | ((uint)hs[1] << 16), (uint)hs[2] | ((uint)hs[3] << 16),
                  (uint)hs[4] | ((uint)hs[5] << 16), (uint)hs[6] | ((uint)hs[7] << 16));
  ul = make_uint4((uint)ls[0] | ((uint)ls[1] << 16), (uint)ls[2] | ((uint)ls[3] << 16),
                  (uint)ls[4] | ((uint)ls[5] << 16), (uint)ls[6] | ((uint)ls[7] << 16));
}

// ---------------- split-bf16 MFMA GEMM, async-staged ------------------------
// mode 0: normal (Cf fp32 and/or Chi/Clo hi/lo).  mode 1: QKV epilogue —
// cols<256 -> Q hi/lo (Chi/Clo compact [row*256]), 256..511 -> K hi (kout),
// >=512 -> V hi transposed [h*64+d][n] (vout).
__global__ __launch_bounds__(256, 4) void gemmm(
    const ushort* __restrict__ Ahi, const ushort* __restrict__ Alo,
    const ushort* __restrict__ Whi, const ushort* __restrict__ Wlo,
    const float* __restrict__ bias, float* __restrict__ Cf,
    ushort* __restrict__ Chi, ushort* __restrict__ Clo,
    int M, int Nc, int K, float preScale, int preScaleCols,
    int mode, ushort* __restrict__ kout, ushort* __restrict__ vout) {
  __shared__ uint sAh[2048], sAl[2048], sBh[2048], sBl[2048];
  const int tid = threadIdx.x;
  const int wid = tid >> 6, lane = tid & 63;
  const int m15 = lane & 15, g2 = lane >> 4;
  const int wr = wid >> 1, wc = wid & 1;
  const int mb = blockIdx.x << 6, nb = blockIdx.y << 6;
  const int sw = swzf(m15);
  const int pr0 = tid >> 3, pc0 = (tid & 7) << 2;
  const int pr1 = (tid + 256) >> 3, pc1 = pc0;
  const int wi0 = (pr0 << 5) + (pc0 ^ swzf(pr0));
  const int wi1 = (pr1 << 5) + (pc1 ^ swzf(pr1));
  uint4 rah0, ral0, rbh0, rbl0, rah1, ral1, rbh1, rbl1;
  auto issue = [&](int k0) {
    size_t a0 = (size_t)(mb + pr0) * K + k0 + (pc0 << 1);
    size_t a1 = (size_t)(mb + pr1) * K + k0 + (pc1 << 1);
    size_t b0 = (size_t)(nb + pr0) * K + k0 + (pc0 << 1);
    size_t b1 = (size_t)(nb + pr1) * K + k0 + (pc1 << 1);
    rah0 = *(const uint4*)(Ahi + a0); ral0 = *(const uint4*)(Alo + a0);
    rah1 = *(const uint4*)(Ahi + a1); ral1 = *(const uint4*)(Alo + a1);
    rbh0 = *(const uint4*)(Whi + b0); rbl0 = *(const uint4*)(Wlo + b0);
    rbh1 = *(const uint4*)(Whi + b1); rbl1 = *(const uint4*)(Wlo + b1);
  };
  f32x4 acc[2][2];
#pragma unroll
  for (int r = 0; r < 2; ++r)
#pragma unroll
    for (int c = 0; c < 2; ++c) acc[r][c] = (f32x4){0.f, 0.f, 0.f, 0.f};

  issue(0);
  for (int k0 = 0; k0 < K; k0 += 64) {
    __syncthreads();
    *(uint4*)&sAh[wi0] = rah0; *(uint4*)&sAl[wi0] = ral0;
    *(uint4*)&sBh[wi0] = rbh0; *(uint4*)&sBl[wi0] = rbl0;
    *(uint4*)&sAh[wi1] = rah1; *(uint4*)&sAl[wi1] = ral1;
    *(uint4*)&sBh[wi1] = rbh1; *(uint4*)&sBl[wi1] = rbl1;
    __syncthreads();
    if (k0 + 64 < K) issue(k0 + 64);
#pragma unroll
    for (int c = 0; c < 2; ++c) {
      bfx8 ah[2], alo[2], bh[2], blo[2];
#pragma unroll
      for (int r = 0; r < 2; ++r) {
        int rowA = (wr << 5) + (r << 4) + m15;
        int idxA = (rowA << 5) + (((c << 4) + (g2 << 2)) ^ sw);
        ah[r]  = __builtin_bit_cast(bfx8, *(const uint4*)&sAh[idxA]);
        alo[r] = __builtin_bit_cast(bfx8, *(const uint4*)&sAl[idxA]);
        int rowB = (wc << 5) + (r << 4) + m15;
        int idxB = (rowB << 5) + (((c << 4) + (g2 << 2)) ^ sw);
        bh[r]  = __builtin_bit_cast(bfx8, *(const uint4*)&sBh[idxB]);
        blo[r] = __builtin_bit_cast(bfx8, *(const uint4*)&sBl[idxB]);
      }
#pragma unroll
      for (int r = 0; r < 2; ++r)
#pragma unroll
        for (int cc = 0; cc < 2; ++cc) {
          acc[r][cc] = MFMA16(ah[r], bh[cc], acc[r][cc]);
          acc[r][cc] = MFMA16(ah[r], blo[cc], acc[r][cc]);
          acc[r][cc] = MFMA16(alo[r], bh[cc], acc[r][cc]);
        }
    }
  }
#pragma unroll
  for (int r = 0; r < 2; ++r)
#pragma unroll
    for (int cc = 0; cc < 2; ++cc) {
      int col = nb + (wc << 5) + (cc << 4) + m15;
      float bv = bias ? bias[col] : 0.f;
      float sc = (col < preScaleCols) ? preScale : 1.f;
      int row0 = mb + (wr << 5) + (r << 4) + (g2 << 2);
      float v4[4];
#pragma unroll
      for (int j = 0; j < 4; ++j) v4[j] = (acc[r][cc][j] + bv) * sc;
      if (mode == 1) {
        if (col < 256) {
#pragma unroll
          for (int j = 0; j < 4; ++j) {
            ushort hi = bf16_rne(v4[j]);
            Chi[(size_t)(row0 + j) * 256 + col] = hi;
            Clo[(size_t)(row0 + j) * 256 + col] = bf16_rne(v4[j] - bf16_tof(hi));
          }
        } else if (col < 512) {
#pragma unroll
          for (int j = 0; j < 4; ++j)
            kout[(size_t)(row0 + j) * 256 + (col - 256)] = bf16_rne(v4[j]);
        } else {
          ushort4 vs = make_ushort4(bf16_rne(v4[0]), bf16_rne(v4[1]),
                                    bf16_rne(v4[2]), bf16_rne(v4[3]));
          *(ushort4*)(vout + ((size_t)(col - 512) << 12) + row0) = vs;
        }
      } else {
#pragma unroll
        for (int j = 0; j < 4; ++j) {
          int row = row0 + j;
          float v = v4[j];
          if (Cf) Cf[(size_t)row * Nc + col] = v;
          if (Chi) {
            ushort hi = bf16_rne(v);
            Chi[(size_t)row * Nc + col] = hi;
            if (Clo) Clo[(size_t)row * Nc + col] = bf16_rne(v - bf16_tof(hi));
          }
        }
      }
    }
}

// ------- convert x/ipw/W1/W2 to hi/lo; opw^T; bfv; edge histogram -----------
__global__ __launch_bounds__(256) void k_cvt5(
    const float* __restrict__ x, const float* __restrict__ ipw,
    const float* __restrict__ opw, const float* __restrict__ W1,
    const float* __restrict__ W2, const float* __restrict__ opb,
    const int* __restrict__ dst,
    ushort* xh, ushort* xl, ushort* iph, ushort* ipl,
    ushort* w1h, ushort* w1l, ushort* w2h, ushort* w2l,
    ushort* opth, ushort* optl, float* bfv, int* cnt) {
  __shared__ float sT[64 * 65];
  int b = blockIdx.x;
  if (b >= 672) {
    if (b < 688) {                       // transpose-convert opw -> opth/optl
      int tx = b - 672, by = tx >> 2, bx = tx & 3;
      int r = threadIdx.x >> 2, cb = (threadIdx.x & 3) << 4;
      const float* src = opw + (size_t)(by * 64 + r) * 256 + bx * 64 + cb;
#pragma unroll
      for (int i = 0; i < 4; ++i) {
        float4 v = *(const float4*)(src + i * 4);
        sT[r * 65 + cb + i * 4 + 0] = v.x; sT[r * 65 + cb + i * 4 + 1] = v.y;
        sT[r * 65 + cb + i * 4 + 2] = v.z; sT[r * 65 + cb + i * 4 + 3] = v.w;
      }
      __syncthreads();
      int d = threadIdx.x >> 2, nb2 = (threadIdx.x & 3) << 4;
      float f[16];
#pragma unroll
      for (int i = 0; i < 16; ++i) f[i] = sT[(nb2 + i) * 65 + d];
      uint4 uh0, ul0, uh1, ul1;
      split8(&f[0], uh0, ul0); split8(&f[8], uh1, ul1);
      size_t o = (size_t)(bx * 64 + d) * 256 + by * 64 + nb2;
      *(uint4*)(opth + o) = uh0; *(uint4*)(opth + o + 8) = uh1;
      *(uint4*)(optl + o) = ul0; *(uint4*)(optl + o + 8) = ul1;
    } else if (b == 688) {               // bfv = W1 * opb
      int t = threadIdx.x;
      sT[t] = opb[t];
      __syncthreads();
      float acc = 0.f;
      const float* wr = W1 + (size_t)t * 256;
      for (int k = 0; k < 256; ++k) acc += wr[k] * sT[k];
      bfv[t] = acc;
    } else {                             // edge histogram (cnt pre-zeroed)
      int e = (b - 689) * 256 + threadIdx.x;
      if (e < NE) atomicAdd(&cnt[dst[e]], 1);
    }
    return;
  }
  const float* src; ushort* hi; ushort* lo; int base;
  if (b < 512)      { src = x;   hi = xh;  lo = xl;  base = b; }
  else if (b < 608) { src = ipw; hi = iph; lo = ipl; base = b - 512; }
  else if (b < 640) { src = W1;  hi = w1h; lo = w1l; base = b - 608; }
  else              { src = W2;  hi = w2h; lo = w2l; base = b - 640; }
  size_t i = (size_t)base * 256 + threadIdx.x;
  float f[8];
  *(float4*)&f[0] = *(const float4*)(src + i * 8);
  *(float4*)&f[4] = *(const float4*)(src + i * 8 + 4);
  uint4 uh, ul; split8(f, uh, ul);
  *(uint4*)(hi + i * 8) = uh;
  *(uint4*)(lo + i * 8) = ul;
}

// ------- MFMA 32x32 swapped-operand flash, 2-term QK / 2-term PV ------------
// 256 threads, 128 q rows, grid 512 (L2-friendly id co-location).
// K,V bf16-hi only in LDS (16 KB); Q and P keep hi/lo. Deferred l-reduction.
__global__ __launch_bounds__(256, 2) void flashm(
    const ushort* __restrict__ qhg, const ushort* __restrict__ qlg,
    const ushort* __restrict__ khg, const ushort* __restrict__ vhg,
    float* __restrict__ opT, float* __restrict__ ml) {
  __shared__ uint sKh[2048], sVh[2048];   // 16 KB

  const int b = blockIdx.x;
  const int id = b & 15;                 // (h,split): co-located per XCD
  const int h = id >> 2, split = id & 3;
  const int qb = (b >> 4) << 7;          // 128 q rows per block
  const int kv0 = split << 10;           // 1024 keys per split
  const int NT = 16;

  const int tid = threadIdx.x;
  const int wid = tid >> 6, lane = tid & 63;
  const int m31 = lane & 31, g = lane >> 5;

  bfx8 qh[4], ql[4];
  {
    const size_t qoff = (size_t)(qb + (wid << 5) + m31) * 256 + h * 64 + (g << 3);
#pragma unroll
    for (int c = 0; c < 4; ++c) {
      qh[c] = __builtin_bit_cast(bfx8, *(const uint4*)(qhg + qoff + (c << 4)));
      ql[c] = __builtin_bit_cast(bfx8, *(const uint4*)(qlg + qoff + (c << 4)));
    }
  }

  f32x16 o[2];
#pragma unroll
  for (int dt = 0; dt < 2; ++dt)
#pragma unroll
    for (int j = 0; j < 16; ++j) o[dt][j] = 0.f;
  float mreg = -1e30f;
  float lacc[16];
#pragma unroll
  for (int j = 0; j < 16; ++j) lacc[j] = 0.f;

  // staging: 2 chunks of 256 threads x 16B (K tile 8 KB + V tile 8 KB)
  const int pr0 = tid >> 3, pc0 = (tid & 7) << 2;
  const int pr1 = (tid + 256) >> 3;
  const int wi0 = (pr0 << 5) + (pc0 ^ swzf(pr0));
  const int wi1 = (pr1 << 5) + (pc0 ^ swzf(pr1));
  uint4 rk0, rk1, rv0, rv1;
  auto issue = [&](int kv) {
    rk0 = *(const uint4*)(khg + (size_t)(kv + pr0) * 256 + h * 64 + (pc0 << 1));
    rk1 = *(const uint4*)(khg + (size_t)(kv + pr1) * 256 + h * 64 + (pc0 << 1));
    rv0 = *(const uint4*)(vhg + ((size_t)(h * 64 + pr0) << 12) + kv + (pc0 << 1));
    rv1 = *(const uint4*)(vhg + ((size_t)(h * 64 + pr1) << 12) + kv + (pc0 << 1));
  };

  issue(kv0);
  for (int it = 0; it < NT; ++it) {
    __syncthreads();
    *(uint4*)&sKh[wi0] = rk0; *(uint4*)&sVh[wi0] = rv0;
    *(uint4*)&sKh[wi1] = rk1; *(uint4*)&sVh[wi1] = rv1;
    __syncthreads();
    if (it + 1 < NT) issue(kv0 + ((it + 1) << 6));

    // ---- S^T = K_bf16 * Q_split (2-term), log2-domain ----
    f32x16 s[2];
#pragma unroll
    for (int kt = 0; kt < 2; ++kt) {
#pragma unroll
      for (int j = 0; j < 16; ++j) s[kt][j] = 0.f;
      const int row = (kt << 5) + m31;
      const int rb = row << 5;
      const int sw2 = swzf(row);
      __builtin_amdgcn_s_setprio(1);
#pragma unroll
      for (int c = 0; c < 4; ++c) {
        int col = ((c << 3) + (g << 2)) ^ sw2;
        bfx8 kh = __builtin_bit_cast(bfx8, *(const uint4*)&sKh[rb + col]);
        s[kt] = MFMA32(kh, qh[c], s[kt]);
        s[kt] = MFMA32(kh, ql[c], s[kt]);
      }
      __builtin_amdgcn_s_setprio(0);
    }

    // ---- online softmax, lane-local for q = m31; deferred l ----
    float v16[16];
#pragma unroll
    for (int j = 0; j < 16; ++j) v16[j] = fmaxf(s[0][j], s[1][j]);
#pragma unroll
    for (int st = 8; st; st >>= 1)
#pragma unroll
      for (int j = 0; j < 8; ++j)
        if (j < st) v16[j] = fmaxf(v16[j], v16[j + st]);
    float mt = fmaxf(v16[0], __shfl_xor(v16[0], 32));
    int need = (mt > mreg + 8.f) ? 1 : 0;
    if (__any(need)) {
      float mn = fmaxf(mreg, mt);
      float al = fexp2(mreg - mn);
      mreg = mn;
#pragma unroll
      for (int j = 0; j < 16; ++j) lacc[j] *= al;
#pragma unroll
      for (int dt = 0; dt < 2; ++dt)
#pragma unroll
        for (int j = 0; j < 16; ++j) o[dt][j] *= al;
    }
    float p0[16], p1[16];
#pragma unroll
    for (int j = 0; j < 16; ++j) {
      p0[j] = fexp2(s[0][j] - mreg);
      p1[j] = fexp2(s[1][j] - mreg);
      lacc[j] += p0[j] + p1[j];
    }

    // ---- pack P hi/lo in-register ----
    uint puh[2][8], pul[2][8];
#pragma unroll
    for (int kt = 0; kt < 2; ++kt)
#pragma unroll
      for (int jj = 0; jj < 8; ++jj) {
        float a = kt ? p1[2 * jj] : p0[2 * jj];
        float bq = kt ? p1[2 * jj + 1] : p0[2 * jj + 1];
        uint ua = __float_as_uint(a), ub = __float_as_uint(bq);
        puh[kt][jj] = (ua >> 16) | (ub & 0xffff0000u);
        float ra = a - __uint_as_float(ua & 0xffff0000u);
        float rb = bq - __uint_as_float(ub & 0xffff0000u);
        pul[kt][jj] = (__float_as_uint(ra) >> 16) | (__float_as_uint(rb) & 0xffff0000u);
      }

    // ---- O^T += V^T_bf16 * P_split (2-term), permuted K-order ----
#pragma unroll
    for (int dt = 0; dt < 2; ++dt) {
      const int row = (dt << 5) + m31;
      const int rb = row << 5;
      const int sw2 = swzf(row);
      __builtin_amdgcn_s_setprio(1);
#pragma unroll
      for (int kt = 0; kt < 2; ++kt)
#pragma unroll
        for (int cc = 0; cc < 2; ++cc) {
          int cA = ((kt << 4) + (cc << 3) + (g << 1)) ^ sw2;
          int cB = ((kt << 4) + (cc << 3) + (g << 1) + 4) ^ sw2;
          uint2 vh0 = *(const uint2*)&sVh[rb + cA];
          uint2 vh1 = *(const uint2*)&sVh[rb + cB];
          bfx8 ah = __builtin_bit_cast(bfx8, make_uint4(vh0.x, vh0.y, vh1.x, vh1.y));
          bfx8 bh = __builtin_bit_cast(bfx8, make_uint4(puh[kt][4 * cc], puh[kt][4 * cc + 1],
                                                        puh[kt][4 * cc + 2], puh[kt][4 * cc + 3]));
          bfx8 bl = __builtin_bit_cast(bfx8, make_uint4(pul[kt][4 * cc], pul[kt][4 * cc + 1],
                                                        pul[kt][4 * cc + 2], pul[kt][4 * cc + 3]));
          o[dt] = MFMA32(ah, bh, o[dt]);
          o[dt] = MFMA32(ah, bl, o[dt]);
        }
      __builtin_amdgcn_s_setprio(0);
    }
  }

  // final l reduction (deferred)
  float lreg;
  {
#pragma unroll
    for (int st = 8; st; st >>= 1)
#pragma unroll
      for (int j = 0; j < 8; ++j)
        if (j < st) lacc[j] += lacc[j + st];
    lreg = lacc[0] + __shfl_xor(lacc[0], 32);
  }

  const int region = (split * NH + h) * (NN >> 5) + (qb >> 5) + wid;
  float* ob = opT + (size_t)region * 2048;
#pragma unroll
  for (int dt = 0; dt < 2; ++dt)
#pragma unroll
    for (int r = 0; r < 16; ++r) {
      int d = (dt << 5) + (r & 3) + ((r >> 2) << 3) + (g << 2);
      ob[(d << 5) + m31] = o[dt][r];
    }
  if (!g) {
    size_t qi = (size_t)(split * NH + h) * NN + qb + (wid << 5) + m31;
    ml[qi * 2]     = mreg;
    ml[qi * 2 + 1] = lreg;
  }
}

// ---------------- combine KV-split partials -> attn hi/lo -------------------
__global__ __launch_bounds__(256) void k_comb(const float* __restrict__ opT,
    const float* __restrict__ ml, ushort* __restrict__ attnh, ushort* __restrict__ attnl) {
  int qt = blockIdx.x, h = blockIdx.y, t = threadIdx.x;
  int qq = t & 31, dg = t >> 5;
  int q = (qt << 5) + qq;
  float ms[KVSPLIT], ls[KVSPLIT];
#pragma unroll
  for (int s = 0; s < KVSPLIT; ++s) {
    const float* e = ml + ((size_t)(s * NH + h) * NN + q) * 2;
    ms[s] = e[0]; ls[s] = e[1];
  }
  float Mx = ms[0];
#pragma unroll
  for (int s = 1; s < KVSPLIT; ++s) Mx = fmaxf(Mx, ms[s]);
  float cs[KVSPLIT], L = 0.f;
#pragma unroll
  for (int s = 0; s < KVSPLIT; ++s) { cs[s] = fexp2(ms[s] - Mx); L += ls[s] * cs[s]; }
  float invL = 1.f / L;
  float vals[8];
#pragma unroll
  for (int j = 0; j < 8; ++j) {
    int d = (dg << 3) + j;
    float acc = 0.f;
#pragma unroll
    for (int s = 0; s < KVSPLIT; ++s)
      acc += opT[((size_t)((s * NH + h) * (NN >> 5) + qt)) * 2048 + (d << 5) + qq] * cs[s];
    vals[j] = acc * invL;
  }
  ushort hs[8], lo[8];
#pragma unroll
  for (int j = 0; j < 8; ++j) {
    hs[j] = bf16_rne(vals[j]);
    lo[j] = bf16_rne(vals[j] - bf16_tof(hs[j]));
  }
  size_t oo = (size_t)q * DD + h * 64 + (dg << 3);
  *(uint4*)(attnh + oo) = make_uint4((uint)hs[0] | ((uint)hs[1] << 16), (uint)hs[2] | ((uint)hs[3] << 16),
                                     (uint)hs[4] | ((uint)hs[5] << 16), (uint)hs[6] | ((uint)hs[7] << 16));
  *(uint4*)(attnl + oo) = make_uint4((uint)lo[0] | ((uint)lo[1] << 16), (uint)lo[2] | ((uint)lo[3] << 16),
                                     (uint)lo[4] | ((uint)lo[5] << 16), (uint)lo[6] | ((uint)lo[7] << 16));
}

// ---------------- CSR (fixed-stride) + gather (bf16-hi input) ---------------
__global__ void k_fill(const int* __restrict__ src, const int* __restrict__ dst,
    const int* __restrict__ cnt, int* cursor, int* __restrict__ lst,
    float* __restrict__ dinv) {
  int e = blockIdx.x * 256 + threadIdx.x;
  if (e < NN) dinv[e] = (float)(1.0 / sqrt((double)(cnt[e] + 1)));
  if (e < NE) {
    int d = dst[e];
    int pos = atomicAdd(&cursor[d], 1);
    if (pos < PAD) lst[(d << 7) + pos] = src[e];
  }
}
__device__ __forceinline__ float4 bf4_tof(ushort4 u) {
  return make_float4(bf16_tof(u.x), bf16_tof(u.y), bf16_tof(u.z), bf16_tof(u.w));
}
__global__ __launch_bounds__(256) void k_gather(const ushort* __restrict__ hin,
    const int* __restrict__ cnt, const int* __restrict__ lst,
    const float* __restrict__ dinv, const float* __restrict__ bias,
    float* __restrict__ outF, ushort* __restrict__ oh, ushort* __restrict__ ol,
    int relu) {
  int g = (blockIdx.x << 2) + (threadIdx.x >> 6);
  int lane = threadIdx.x & 63;
  float di = dinv[g];
  int c4 = lane << 2;
  float4 hv = bf4_tof(*(const ushort4*)(hin + (size_t)g * DD + c4));
  float w = di * di;
  float a0x = hv.x * w, a0y = hv.y * w, a0z = hv.z * w, a0w = hv.w * w;
  float a1x = 0, a1y = 0, a1z = 0, a1w = 0;
  float a2x = 0, a2y = 0, a2z = 0, a2w = 0;
  float a3x = 0, a3y = 0, a3z = 0, a3w = 0;
  int num = min(cnt[g], PAD);
  const int* lrow = lst + (g << 7);
  int i = 0;
  for (; i + 4 <= num; i += 4) {
    int4 s4 = *(const int4*)(lrow + i);
    float w0 = dinv[s4.x] * di, w1 = dinv[s4.y] * di;
    float w2 = dinv[s4.z] * di, w3 = dinv[s4.w] * di;
    float4 h0 = bf4_tof(*(const ushort4*)(hin + (size_t)s4.x * DD + c4));
    float4 h1 = bf4_tof(*(const ushort4*)(hin + (size_t)s4.y * DD + c4));
    float4 h2 = bf4_tof(*(const ushort4*)(hin + (size_t)s4.z * DD + c4));
    float4 h3 = bf4_tof(*(const ushort4*)(hin + (size_t)s4.w * DD + c4));
    a0x += h0.x * w0; a0y += h0.y * w0; a0z += h0.z * w0; a0w += h0.w * w0;
    a1x += h1.x * w1; a1y += h1.y * w1; a1z += h1.z * w1; a1w += h1.w * w1;
    a2x += h2.x * w2; a2y += h2.y * w2; a2z += h2.z * w2; a2w += h2.w * w2;
    a3x += h3.x * w3; a3y += h3.y * w3; a3z += h3.z * w3; a3w += h3.w * w3;
  }
  for (; i < num; ++i) {
    int sI = lrow[i];
    float ww = dinv[sI] * di;
    float4 hs = bf4_tof(*(const ushort4*)(hin + (size_t)sI * DD + c4));
    a0x += hs.x * ww; a0y += hs.y * ww; a0z += hs.z * ww; a0w += hs.w * ww;
  }
  float4 bv = *(const float4*)(bias + c4);
  float4 acc = make_float4((a0x + a1x) + (a2x + a3x) + bv.x,
                           (a0y + a1y) + (a2y + a3y) + bv.y,
                           (a0z + a1z) + (a2z + a3z) + bv.z,
                           (a0w + a1w) + (a2w + a3w) + bv.w);
  if (relu) {
    acc.x = fmaxf(acc.x, 0.f); acc.y = fmaxf(acc.y, 0.f);
    acc.z = fmaxf(acc.z, 0.f); acc.w = fmaxf(acc.w, 0.f);
  }
  if (outF) *(float4*)(outF + (size_t)g * DD + c4) = acc;
  if (oh) {
    ushort h0 = bf16_rne(acc.x), h1 = bf16_rne(acc.y);
    ushort h2 = bf16_rne(acc.z), h3 = bf16_rne(acc.w);
    size_t oo = (size_t)g * DD + c4;
    *(ushort4*)(oh + oo) = make_ushort4(h0, h1, h2, h3);
    *(ushort4*)(ol + oo) = make_ushort4(
        bf16_rne(acc.x - bf16_tof(h0)), bf16_rne(acc.y - bf16_tof(h1)),
        bf16_rne(acc.z - bf16_tof(h2)), bf16_rne(acc.w - bf16_tof(h3)));
  }
}

// ---------------- launch ---------------------------------------------------
extern "C" void kernel_launch(void* const* d_in, const int* in_sizes, int n_in,
                              void* d_out, int out_size, void* d_ws, size_t ws_size,
                              hipStream_t stream) {
  const float* x   = (const float*)d_in[0];
  const int*   ei  = (const int*)d_in[1];
  const float* ipw = (const float*)d_in[2];
  const float* ipb = (const float*)d_in[3];
  const float* opw = (const float*)d_in[4];
  const float* opb = (const float*)d_in[5];
  const float* W1  = (const float*)d_in[6];
  const float* b1  = (const float*)d_in[7];
  const float* W2  = (const float*)d_in[8];
  const float* b2  = (const float*)d_in[9];
  const int* srcI = ei;
  const int* dstI = ei + NE;

  char* w = (char*)d_ws;
  ushort* qhg   = (ushort*)w; w += (size_t)NN * DD * 2;
  ushort* qlg   = (ushort*)w; w += (size_t)NN * DD * 2;
  ushort* khg   = (ushort*)w; w += (size_t)NN * DD * 2;
  ushort* vhg   = (ushort*)w; w += (size_t)NH * NN * 64 * 2;
  ushort* xh    = (ushort*)w; w += (size_t)NN * DD * 2;   // reused as attnh
  ushort* xl    = (ushort*)w; w += (size_t)NN * DD * 2;   // reused as attnl
  ushort* iph   = (ushort*)w; w += (size_t)NHD * DD * 2;
  ushort* ipl   = (ushort*)w; w += (size_t)NHD * DD * 2;
  ushort* w1h   = (ushort*)w; w += (size_t)DD * DD * 2;
  ushort* w1l   = (ushort*)w; w += (size_t)DD * DD * 2;
  ushort* w2h   = (ushort*)w; w += (size_t)DD * DD * 2;
  ushort* w2l   = (ushort*)w; w += (size_t)DD * DD * 2;
  ushort* opth  = (ushort*)w; w += (size_t)DD * DD * 2;
  ushort* optl  = (ushort*)w; w += (size_t)DD * DD * 2;
  ushort* wfh   = (ushort*)w; w += (size_t)DD * DD * 2;
  ushort* wfl   = (ushort*)w; w += (size_t)DD * DD * 2;
  float*  bfv   = (float*)w;  w += (size_t)DD * 4;
  ushort* hlin1 = (ushort*)w; w += (size_t)NN * DD * 2;
  ushort* hlin2 = (ushort*)w; w += (size_t)NN * DD * 2;
  ushort* g1h   = (ushort*)w; w += (size_t)NN * DD * 2;
  ushort* g1l   = (ushort*)w; w += (size_t)NN * DD * 2;
  float*  opT   = (float*)w;  w += (size_t)KVSPLIT * NH * NN * 64 * 4;
  float*  ml    = (float*)w;  w += (size_t)KVSPLIT * NH * NN * 2 * 4;
  int*    cnt    = (int*)w;   w += NN * 4;
  int*    cursor = (int*)w;   w += NN * 4;
  float*  dinv   = (float*)w; w += NN * 4;
  int*    lst    = (int*)w;   w += (size_t)NN * PAD * 4;
  ushort* attnh = xh;
  ushort* attnl = xl;

  // zero cnt+cursor (adjacent), then conversions + opw^T + bfv + histogram
  hipMemsetAsync(cnt, 0, 2 * NN * 4, stream);
  hipLaunchKernelGGL(k_cvt5, dim3(689 + NE / 256), dim3(256), 0, stream,
                     x, ipw, opw, W1, W2, opb, dstI,
                     xh, xl, iph, ipl, w1h, w1l, w2h, w2l, opth, optl, bfv, cnt);
  hipLaunchKernelGGL(k_fill, dim3(NE / 256), dim3(256), 0, stream, srcI, dstI, cnt,
                     cursor, lst, dinv);

  // Wf = W1 * Wop  (via gemmm with W = opw^T)
  hipLaunchKernelGGL(gemmm, dim3(4, 4), dim3(256), 0, stream,
                     w1h, w1l, opth, optl, (const float*)nullptr, (float*)nullptr,
                     wfh, wfl, DD, DD, DD, 1.f, 0, 0, (ushort*)nullptr, (ushort*)nullptr);

  // QKV projection: Q hi/lo (pre-scaled), K hi, V hi transposed — fused epilogue
  hipLaunchKernelGGL(gemmm, dim3(64, 12), dim3(256), 0, stream,
                     xh, xl, iph, ipl, ipb, (float*)nullptr, qhg, qlg,
                     NN, NHD, DD, QSCALE, DD, 1, khg, vhg);
  hipLaunchKernelGGL(flashm, dim3((NN / 128) * 16), dim3(256), 0, stream,
                     qhg, qlg, khg, vhg, opT, ml);
  hipLaunchKernelGGL(k_comb, dim3(NN / 32, NH), dim3(256), 0, stream, opT, ml, attnh, attnl);

  // fused out-proj + GCN1 linear: hlin1 = attn * Wf^T + W1*bop  (bf16-hi out)
  hipLaunchKernelGGL(gemmm, dim3(64, 4), dim3(256), 0, stream,
                     attnh, attnl, wfh, wfl, bfv, (float*)nullptr,
                     hlin1, (ushort*)nullptr, NN, DD, DD, 1.f, 0, 0,
                     (ushort*)nullptr, (ushort*)nullptr);
  hipLaunchKernelGGL(k_gather, dim3(NN / 4), dim3(256), 0, stream, hlin1, cnt, lst,
                     dinv, b1, (float*)nullptr, g1h, g1l, 1);
  // GCN2
  hipLaunchKernelGGL(gemmm, dim3(64, 4), dim3(256), 0, stream,
                     g1h, g1l, w2h, w2l, (const float*)nullptr, (float*)nullptr,
                     hlin2, (ushort*)nullptr, NN, DD, DD, 1.f, 0, 0,
                     (ushort*)nullptr, (ushort*)nullptr);
  hipLaunchKernelGGL(k_gather, dim3(NN / 4), dim3(256), 0, stream, hlin2, cnt, lst,
                     dinv, b2, (float*)d_out, (ushort*)nullptr, (ushort*)nullptr, 0);
}

// Round 9
// 116.789 us; speedup vs baseline: 2.1967x; 1.1745x over previous
//
#include <hip/hip_runtime.h>
#include <math.h>

#define NN   4096
#define DD   256
#define NHD  768
#define NH   4
#define NE   131072
#define KVSPLIT 4
#define PAD  128
#define QSCALE 0.18033688011112042f   // 0.125 * log2(e)

using bfx8   = __attribute__((ext_vector_type(8))) short;
using f32x4  = __attribute__((ext_vector_type(4))) float;
using f32x16 = __attribute__((ext_vector_type(16))) float;
#define MFMA16(a,b,c) __builtin_amdgcn_mfma_f32_16x16x32_bf16(a, b, c, 0, 0, 0)
#define MFMA32(a,b,c) __builtin_amdgcn_mfma_f32_32x32x16_bf16(a, b, c, 0, 0, 0)

__device__ __forceinline__ ushort bf16_rne(float f) {
  uint u = __float_as_uint(f);
  u += 0x7fffu + ((u >> 16) & 1u);
  return (ushort)(u >> 16);
}
__device__ __forceinline__ float bf16_tof(ushort h) {
  return __uint_as_float(((uint)h) << 16);
}
__device__ __forceinline__ float fexp2(float x) { return __builtin_amdgcn_exp2f(x); }
__device__ __forceinline__ int swzf(int row) {   // u32-index XOR mask, bits 2..4
  return ((row & 7) << 2) ^ ((row & 8) << 1);
}
__device__ __forceinline__ uint4 cvt8(const float* f) {
  ushort hs[8];
#pragma unroll
  for (int j = 0; j < 8; ++j) hs[j] = bf16_rne(f[j]);
  return make_uint4((uint)hs[0] | ((uint)hs[1] << 16), (uint)hs[2] | ((uint)hs[3] << 16),
                    (uint)hs[4] | ((uint)hs[5] << 16), (uint)hs[6] | ((uint)hs[7] << 16));
}

// ---------------- plain-bf16 MFMA GEMM, async-staged ------------------------
// mode 0: Cf fp32 and/or Cb bf16 (stride Nc). mode 1 (QKV): col<256 -> Q bf16
// compact [row*256] (Cb, pre-scaled); 256..511 -> K bf16 (kout); >=512 -> V
// bf16 transposed [h*64+d][n] (vout).
__global__ __launch_bounds__(256, 4) void gemmm(
    const ushort* __restrict__ Ah, const ushort* __restrict__ Wh,
    const float* __restrict__ bias, float* __restrict__ Cf,
    ushort* __restrict__ Cb,
    int M, int Nc, int K, float preScale, int preScaleCols,
    int mode, ushort* __restrict__ kout, ushort* __restrict__ vout) {
  __shared__ uint sAh[2048], sBh[2048];   // 16 KB
  const int tid = threadIdx.x;
  const int wid = tid >> 6, lane = tid & 63;
  const int m15 = lane & 15, g2 = lane >> 4;
  const int wr = wid >> 1, wc = wid & 1;
  const int mb = blockIdx.x << 6, nb = blockIdx.y << 6;
  const int sw = swzf(m15);
  const int pr0 = tid >> 3, pc0 = (tid & 7) << 2;
  const int pr1 = (tid + 256) >> 3;
  const int wi0 = (pr0 << 5) + (pc0 ^ swzf(pr0));
  const int wi1 = (pr1 << 5) + (pc0 ^ swzf(pr1));
  uint4 ra0, ra1, rb0, rb1;
  auto issue = [&](int k0) {
    ra0 = *(const uint4*)(Ah + (size_t)(mb + pr0) * K + k0 + (pc0 << 1));
    ra1 = *(const uint4*)(Ah + (size_t)(mb + pr1) * K + k0 + (pc0 << 1));
    rb0 = *(const uint4*)(Wh + (size_t)(nb + pr0) * K + k0 + (pc0 << 1));
    rb1 = *(const uint4*)(Wh + (size_t)(nb + pr1) * K + k0 + (pc0 << 1));
  };
  f32x4 acc[2][2];
#pragma unroll
  for (int r = 0; r < 2; ++r)
#pragma unroll
    for (int c = 0; c < 2; ++c) acc[r][c] = (f32x4){0.f, 0.f, 0.f, 0.f};

  issue(0);
  for (int k0 = 0; k0 < K; k0 += 64) {
    __syncthreads();
    *(uint4*)&sAh[wi0] = ra0; *(uint4*)&sBh[wi0] = rb0;
    *(uint4*)&sAh[wi1] = ra1; *(uint4*)&sBh[wi1] = rb1;
    __syncthreads();
    if (k0 + 64 < K) issue(k0 + 64);
#pragma unroll
    for (int c = 0; c < 2; ++c) {
      bfx8 ah[2], bh[2];
#pragma unroll
      for (int r = 0; r < 2; ++r) {
        int rowA = (wr << 5) + (r << 4) + m15;
        ah[r] = __builtin_bit_cast(bfx8, *(const uint4*)&sAh[(rowA << 5) + (((c << 4) + (g2 << 2)) ^ sw)]);
        int rowB = (wc << 5) + (r << 4) + m15;
        bh[r] = __builtin_bit_cast(bfx8, *(const uint4*)&sBh[(rowB << 5) + (((c << 4) + (g2 << 2)) ^ sw)]);
      }
#pragma unroll
      for (int r = 0; r < 2; ++r)
#pragma unroll
        for (int cc = 0; cc < 2; ++cc)
          acc[r][cc] = MFMA16(ah[r], bh[cc], acc[r][cc]);
    }
  }
#pragma unroll
  for (int r = 0; r < 2; ++r)
#pragma unroll
    for (int cc = 0; cc < 2; ++cc) {
      int col = nb + (wc << 5) + (cc << 4) + m15;
      float bv = bias ? bias[col] : 0.f;
      float sc = (col < preScaleCols) ? preScale : 1.f;
      int row0 = mb + (wr << 5) + (r << 4) + (g2 << 2);
      float v4[4];
#pragma unroll
      for (int j = 0; j < 4; ++j) v4[j] = (acc[r][cc][j] + bv) * sc;
      if (mode == 1) {
        if (col < 256) {
#pragma unroll
          for (int j = 0; j < 4; ++j)
            Cb[(size_t)(row0 + j) * 256 + col] = bf16_rne(v4[j]);
        } else if (col < 512) {
#pragma unroll
          for (int j = 0; j < 4; ++j)
            kout[(size_t)(row0 + j) * 256 + (col - 256)] = bf16_rne(v4[j]);
        } else {
          ushort4 vs = make_ushort4(bf16_rne(v4[0]), bf16_rne(v4[1]),
                                    bf16_rne(v4[2]), bf16_rne(v4[3]));
          *(ushort4*)(vout + ((size_t)(col - 512) << 12) + row0) = vs;
        }
      } else {
#pragma unroll
        for (int j = 0; j < 4; ++j) {
          int row = row0 + j;
          if (Cf) Cf[(size_t)row * Nc + col] = v4[j];
          if (Cb) Cb[(size_t)row * Nc + col] = bf16_rne(v4[j]);
        }
      }
    }
}

// ------- convert x/ipw/W1/W2 to bf16; opw^T; bfv; edge histogram ------------
__global__ __launch_bounds__(256) void k_cvt(
    const float* __restrict__ x, const float* __restrict__ ipw,
    const float* __restrict__ opw, const float* __restrict__ W1,
    const float* __restrict__ W2, const float* __restrict__ opb,
    const int* __restrict__ dst,
    ushort* xh, ushort* iph, ushort* w1h, ushort* w2h,
    ushort* opth, float* bfv, int* cnt) {
  __shared__ float sT[64 * 65];
  int b = blockIdx.x;
  if (b >= 672) {
    if (b < 688) {                       // transpose-convert opw -> opth
      int tx = b - 672, by = tx >> 2, bx = tx & 3;
      int r = threadIdx.x >> 2, cb = (threadIdx.x & 3) << 4;
      const float* src = opw + (size_t)(by * 64 + r) * 256 + bx * 64 + cb;
#pragma unroll
      for (int i = 0; i < 4; ++i) {
        float4 v = *(const float4*)(src + i * 4);
        sT[r * 65 + cb + i * 4 + 0] = v.x; sT[r * 65 + cb + i * 4 + 1] = v.y;
        sT[r * 65 + cb + i * 4 + 2] = v.z; sT[r * 65 + cb + i * 4 + 3] = v.w;
      }
      __syncthreads();
      int d = threadIdx.x >> 2, nb2 = (threadIdx.x & 3) << 4;
      float f[16];
#pragma unroll
      for (int i = 0; i < 16; ++i) f[i] = sT[(nb2 + i) * 65 + d];
      size_t o = (size_t)(bx * 64 + d) * 256 + by * 64 + nb2;
      *(uint4*)(opth + o)     = cvt8(&f[0]);
      *(uint4*)(opth + o + 8) = cvt8(&f[8]);
    } else if (b == 688) {               // bfv = W1 * opb
      int t = threadIdx.x;
      sT[t] = opb[t];
      __syncthreads();
      float acc = 0.f;
      const float* wr = W1 + (size_t)t * 256;
      for (int k = 0; k < 256; ++k) acc += wr[k] * sT[k];
      bfv[t] = acc;
    } else {                             // edge histogram (cnt pre-zeroed)
      int e = (b - 689) * 256 + threadIdx.x;
      if (e < NE) atomicAdd(&cnt[dst[e]], 1);
    }
    return;
  }
  const float* src; ushort* hi; int base;
  if (b < 512)      { src = x;   hi = xh;  base = b; }
  else if (b < 608) { src = ipw; hi = iph; base = b - 512; }
  else if (b < 640) { src = W1;  hi = w1h; base = b - 608; }
  else              { src = W2;  hi = w2h; base = b - 640; }
  size_t i = (size_t)base * 256 + threadIdx.x;
  float f[8];
  *(float4*)&f[0] = *(const float4*)(src + i * 8);
  *(float4*)&f[4] = *(const float4*)(src + i * 8 + 4);
  *(uint4*)(hi + i * 8) = cvt8(f);
}

// ------- MFMA 32x32 swapped-operand flash, plain bf16 QK and PV -------------
// 256 threads, 128 q rows, grid 512 (L2-friendly id co-location). 16 KB LDS.
__global__ __launch_bounds__(256, 2) void flashm(
    const ushort* __restrict__ qhg, const ushort* __restrict__ khg,
    const ushort* __restrict__ vhg,
    float* __restrict__ opT, float* __restrict__ ml) {
  __shared__ uint sKh[2048], sVh[2048];   // 16 KB

  const int b = blockIdx.x;
  const int id = b & 15;                 // (h,split): co-located per XCD
  const int h = id >> 2, split = id & 3;
  const int qb = (b >> 4) << 7;          // 128 q rows per block
  const int kv0 = split << 10;           // 1024 keys per split
  const int NT = 16;

  const int tid = threadIdx.x;
  const int wid = tid >> 6, lane = tid & 63;
  const int m31 = lane & 31, g = lane >> 5;

  bfx8 qh[4];
  {
    const size_t qoff = (size_t)(qb + (wid << 5) + m31) * 256 + h * 64 + (g << 3);
#pragma unroll
    for (int c = 0; c < 4; ++c)
      qh[c] = __builtin_bit_cast(bfx8, *(const uint4*)(qhg + qoff + (c << 4)));
  }

  f32x16 o[2];
#pragma unroll
  for (int dt = 0; dt < 2; ++dt)
#pragma unroll
    for (int j = 0; j < 16; ++j) o[dt][j] = 0.f;
  float mreg = -1e30f;
  float lacc[16];
#pragma unroll
  for (int j = 0; j < 16; ++j) lacc[j] = 0.f;

  // staging: 2 chunks of 256 threads x 16B (K tile 8 KB + V tile 8 KB)
  const int pr0 = tid >> 3, pc0 = (tid & 7) << 2;
  const int pr1 = (tid + 256) >> 3;
  const int wi0 = (pr0 << 5) + (pc0 ^ swzf(pr0));
  const int wi1 = (pr1 << 5) + (pc0 ^ swzf(pr1));
  uint4 rk0, rk1, rv0, rv1;
  auto issue = [&](int kv) {
    rk0 = *(const uint4*)(khg + (size_t)(kv + pr0) * 256 + h * 64 + (pc0 << 1));
    rk1 = *(const uint4*)(khg + (size_t)(kv + pr1) * 256 + h * 64 + (pc0 << 1));
    rv0 = *(const uint4*)(vhg + ((size_t)(h * 64 + pr0) << 12) + kv + (pc0 << 1));
    rv1 = *(const uint4*)(vhg + ((size_t)(h * 64 + pr1) << 12) + kv + (pc0 << 1));
  };

  issue(kv0);
  for (int it = 0; it < NT; ++it) {
    __syncthreads();
    *(uint4*)&sKh[wi0] = rk0; *(uint4*)&sVh[wi0] = rv0;
    *(uint4*)&sKh[wi1] = rk1; *(uint4*)&sVh[wi1] = rv1;
    __syncthreads();
    if (it + 1 < NT) issue(kv0 + ((it + 1) << 6));

    // ---- S^T = K_bf16 * Q_bf16, log2-domain ----
    f32x16 s[2];
#pragma unroll
    for (int kt = 0; kt < 2; ++kt) {
#pragma unroll
      for (int j = 0; j < 16; ++j) s[kt][j] = 0.f;
      const int row = (kt << 5) + m31;
      const int rb = row << 5;
      const int sw2 = swzf(row);
      __builtin_amdgcn_s_setprio(1);
#pragma unroll
      for (int c = 0; c < 4; ++c) {
        int col = ((c << 3) + (g << 2)) ^ sw2;
        bfx8 kh = __builtin_bit_cast(bfx8, *(const uint4*)&sKh[rb + col]);
        s[kt] = MFMA32(kh, qh[c], s[kt]);
      }
      __builtin_amdgcn_s_setprio(0);
    }

    // ---- online softmax, lane-local for q = m31; deferred l ----
    float v16[16];
#pragma unroll
    for (int j = 0; j < 16; ++j) v16[j] = fmaxf(s[0][j], s[1][j]);
#pragma unroll
    for (int st = 8; st; st >>= 1)
#pragma unroll
      for (int j = 0; j < 8; ++j)
        if (j < st) v16[j] = fmaxf(v16[j], v16[j + st]);
    float mt = fmaxf(v16[0], __shfl_xor(v16[0], 32));
    int need = (mt > mreg + 8.f) ? 1 : 0;
    if (__any(need)) {
      float mn = fmaxf(mreg, mt);
      float al = fexp2(mreg - mn);
      mreg = mn;
#pragma unroll
      for (int j = 0; j < 16; ++j) lacc[j] *= al;
#pragma unroll
      for (int dt = 0; dt < 2; ++dt)
#pragma unroll
        for (int j = 0; j < 16; ++j) o[dt][j] *= al;
    }
    float p0[16], p1[16];
#pragma unroll
    for (int j = 0; j < 16; ++j) {
      p0[j] = fexp2(s[0][j] - mreg);
      p1[j] = fexp2(s[1][j] - mreg);
      lacc[j] += p0[j] + p1[j];
    }

    // ---- pack P to bf16 (trunc) in-register ----
    uint puh[2][8];
#pragma unroll
    for (int kt = 0; kt < 2; ++kt)
#pragma unroll
      for (int jj = 0; jj < 8; ++jj) {
        float a = kt ? p1[2 * jj] : p0[2 * jj];
        float bq = kt ? p1[2 * jj + 1] : p0[2 * jj + 1];
        puh[kt][jj] = (__float_as_uint(a) >> 16) | (__float_as_uint(bq) & 0xffff0000u);
      }

    // ---- O^T += V^T_bf16 * P_bf16, permuted K-order ----
#pragma unroll
    for (int dt = 0; dt < 2; ++dt) {
      const int row = (dt << 5) + m31;
      const int rb = row << 5;
      const int sw2 = swzf(row);
      __builtin_amdgcn_s_setprio(1);
#pragma unroll
      for (int kt = 0; kt < 2; ++kt)
#pragma unroll
        for (int cc = 0; cc < 2; ++cc) {
          int cA = ((kt << 4) + (cc << 3) + (g << 1)) ^ sw2;
          int cB = ((kt << 4) + (cc << 3) + (g << 1) + 4) ^ sw2;
          uint2 vh0 = *(const uint2*)&sVh[rb + cA];
          uint2 vh1 = *(const uint2*)&sVh[rb + cB];
          bfx8 ah = __builtin_bit_cast(bfx8, make_uint4(vh0.x, vh0.y, vh1.x, vh1.y));
          bfx8 bh = __builtin_bit_cast(bfx8, make_uint4(puh[kt][4 * cc], puh[kt][4 * cc + 1],
                                                        puh[kt][4 * cc + 2], puh[kt][4 * cc + 3]));
          o[dt] = MFMA32(ah, bh, o[dt]);
        }
      __builtin_amdgcn_s_setprio(0);
    }
  }

  // final l reduction (deferred)
  float lreg;
  {
#pragma unroll
    for (int st = 8; st; st >>= 1)
#pragma unroll
      for (int j = 0; j < 8; ++j)
        if (j < st) lacc[j] += lacc[j + st];
    lreg = lacc[0] + __shfl_xor(lacc[0], 32);
  }

  const int region = (split * NH + h) * (NN >> 5) + (qb >> 5) + wid;
  float* ob = opT + (size_t)region * 2048;
#pragma unroll
  for (int dt = 0; dt < 2; ++dt)
#pragma unroll
    for (int r = 0; r < 16; ++r) {
      int d = (dt << 5) + (r & 3) + ((r >> 2) << 3) + (g << 2);
      ob[(d << 5) + m31] = o[dt][r];
    }
  if (!g) {
    size_t qi = (size_t)(split * NH + h) * NN + qb + (wid << 5) + m31;
    ml[qi * 2]     = mreg;
    ml[qi * 2 + 1] = lreg;
  }
}

// ---------------- combine KV-split partials -> attn bf16 --------------------
__global__ __launch_bounds__(256) void k_comb(const float* __restrict__ opT,
    const float* __restrict__ ml, ushort* __restrict__ attnh) {
  int qt = blockIdx.x, h = blockIdx.y, t = threadIdx.x;
  int qq = t & 31, dg = t >> 5;
  int q = (qt << 5) + qq;
  float ms[KVSPLIT], ls[KVSPLIT];
#pragma unroll
  for (int s = 0; s < KVSPLIT; ++s) {
    const float* e = ml + ((size_t)(s * NH + h) * NN + q) * 2;
    ms[s] = e[0]; ls[s] = e[1];
  }
  float Mx = ms[0];
#pragma unroll
  for (int s = 1; s < KVSPLIT; ++s) Mx = fmaxf(Mx, ms[s]);
  float cs[KVSPLIT], L = 0.f;
#pragma unroll
  for (int s = 0; s < KVSPLIT; ++s) { cs[s] = fexp2(ms[s] - Mx); L += ls[s] * cs[s]; }
  float invL = 1.f / L;
  float vals[8];
#pragma unroll
  for (int j = 0; j < 8; ++j) {
    int d = (dg << 3) + j;
    float acc = 0.f;
#pragma unroll
    for (int s = 0; s < KVSPLIT; ++s)
      acc += opT[((size_t)((s * NH + h) * (NN >> 5) + qt)) * 2048 + (d << 5) + qq] * cs[s];
    vals[j] = acc * invL;
  }
  size_t oo = (size_t)q * DD + h * 64 + (dg << 3);
  *(uint4*)(attnh + oo) = cvt8(vals);
}

// ---------------- CSR (fixed-stride) + gather (bf16 input) ------------------
__global__ void k_fill(const int* __restrict__ src, const int* __restrict__ dst,
    const int* __restrict__ cnt, int* cursor, int* __restrict__ lst,
    float* __restrict__ dinv) {
  int e = blockIdx.x * 256 + threadIdx.x;
  if (e < NN) dinv[e] = (float)(1.0 / sqrt((double)(cnt[e] + 1)));
  if (e < NE) {
    int d = dst[e];
    int pos = atomicAdd(&cursor[d], 1);
    if (pos < PAD) lst[(d << 7) + pos] = src[e];
  }
}
__device__ __forceinline__ float4 bf4_tof(ushort4 u) {
  return make_float4(bf16_tof(u.x), bf16_tof(u.y), bf16_tof(u.z), bf16_tof(u.w));
}
__global__ __launch_bounds__(256) void k_gather(const ushort* __restrict__ hin,
    const int* __restrict__ cnt, const int* __restrict__ lst,
    const float* __restrict__ dinv, const float* __restrict__ bias,
    float* __restrict__ outF, ushort* __restrict__ oh, int relu) {
  int g = (blockIdx.x << 2) + (threadIdx.x >> 6);
  int lane = threadIdx.x & 63;
  float di = dinv[g];
  int c4 = lane << 2;
  float4 hv = bf4_tof(*(const ushort4*)(hin + (size_t)g * DD + c4));
  float w = di * di;
  float a0x = hv.x * w, a0y = hv.y * w, a0z = hv.z * w, a0w = hv.w * w;
  float a1x = 0, a1y = 0, a1z = 0, a1w = 0;
  float a2x = 0, a2y = 0, a2z = 0, a2w = 0;
  float a3x = 0, a3y = 0, a3z = 0, a3w = 0;
  int num = min(cnt[g], PAD);
  const int* lrow = lst + (g << 7);
  int i = 0;
  for (; i + 4 <= num; i += 4) {
    int4 s4 = *(const int4*)(lrow + i);
    float w0 = dinv[s4.x] * di, w1 = dinv[s4.y] * di;
    float w2 = dinv[s4.z] * di, w3 = dinv[s4.w] * di;
    float4 h0 = bf4_tof(*(const ushort4*)(hin + (size_t)s4.x * DD + c4));
    float4 h1 = bf4_tof(*(const ushort4*)(hin + (size_t)s4.y * DD + c4));
    float4 h2 = bf4_tof(*(const ushort4*)(hin + (size_t)s4.z * DD + c4));
    float4 h3 = bf4_tof(*(const ushort4*)(hin + (size_t)s4.w * DD + c4));
    a0x += h0.x * w0; a0y += h0.y * w0; a0z += h0.z * w0; a0w += h0.w * w0;
    a1x += h1.x * w1; a1y += h1.y * w1; a1z += h1.z * w1; a1w += h1.w * w1;
    a2x += h2.x * w2; a2y += h2.y * w2; a2z += h2.z * w2; a2w += h2.w * w2;
    a3x += h3.x * w3; a3y += h3.y * w3; a3z += h3.z * w3; a3w += h3.w * w3;
  }
  for (; i < num; ++i) {
    int sI = lrow[i];
    float ww = dinv[sI] * di;
    float4 hs = bf4_tof(*(const ushort4*)(hin + (size_t)sI * DD + c4));
    a0x += hs.x * ww; a0y += hs.y * ww; a0z += hs.z * ww; a0w += hs.w * ww;
  }
  float4 bv = *(const float4*)(bias + c4);
  float4 acc = make_float4((a0x + a1x) + (a2x + a3x) + bv.x,
                           (a0y + a1y) + (a2y + a3y) + bv.y,
                           (a0z + a1z) + (a2z + a3z) + bv.z,
                           (a0w + a1w) + (a2w + a3w) + bv.w);
  if (relu) {
    acc.x = fmaxf(acc.x, 0.f); acc.y = fmaxf(acc.y, 0.f);
    acc.z = fmaxf(acc.z, 0.f); acc.w = fmaxf(acc.w, 0.f);
  }
  if (outF) *(float4*)(outF + (size_t)g * DD + c4) = acc;
  if (oh) {
    size_t oo = (size_t)g * DD + c4;
    *(ushort4*)(oh + oo) = make_ushort4(bf16_rne(acc.x), bf16_rne(acc.y),
                                        bf16_rne(acc.z), bf16_rne(acc.w));
  }
}

// ---------------- launch ---------------------------------------------------
extern "C" void kernel_launch(void* const* d_in, const int* in_sizes, int n_in,
                              void* d_out, int out_size, void* d_ws, size_t ws_size,
                              hipStream_t stream) {
  const float* x   = (const float*)d_in[0];
  const int*   ei  = (const int*)d_in[1];
  const float* ipw = (const float*)d_in[2];
  const float* ipb = (const float*)d_in[3];
  const float* opw = (const float*)d_in[4];
  const float* opb = (const float*)d_in[5];
  const float* W1  = (const float*)d_in[6];
  const float* b1  = (const float*)d_in[7];
  const float* W2  = (const float*)d_in[8];
  const float* b2  = (const float*)d_in[9];
  const int* srcI = ei;
  const int* dstI = ei + NE;

  char* w = (char*)d_ws;
  ushort* qhg   = (ushort*)w; w += (size_t)NN * DD * 2;
  ushort* khg   = (ushort*)w; w += (size_t)NN * DD * 2;
  ushort* vhg   = (ushort*)w; w += (size_t)NH * NN * 64 * 2;
  ushort* xh    = (ushort*)w; w += (size_t)NN * DD * 2;   // reused as attnh
  ushort* iph   = (ushort*)w; w += (size_t)NHD * DD * 2;
  ushort* w1h   = (ushort*)w; w += (size_t)DD * DD * 2;
  ushort* w2h   = (ushort*)w; w += (size_t)DD * DD * 2;
  ushort* opth  = (ushort*)w; w += (size_t)DD * DD * 2;
  ushort* wfh   = (ushort*)w; w += (size_t)DD * DD * 2;
  float*  bfv   = (float*)w;  w += (size_t)DD * 4;
  ushort* hlin1 = (ushort*)w; w += (size_t)NN * DD * 2;
  ushort* hlin2 = (ushort*)w; w += (size_t)NN * DD * 2;
  ushort* g1h   = (ushort*)w; w += (size_t)NN * DD * 2;
  float*  opT   = (float*)w;  w += (size_t)KVSPLIT * NH * NN * 64 * 4;
  float*  ml    = (float*)w;  w += (size_t)KVSPLIT * NH * NN * 2 * 4;
  int*    cnt    = (int*)w;   w += NN * 4;
  int*    cursor = (int*)w;   w += NN * 4;
  float*  dinv   = (float*)w; w += NN * 4;
  int*    lst    = (int*)w;   w += (size_t)NN * PAD * 4;
  ushort* attnh = xh;

  // zero cnt+cursor (adjacent), then conversions + opw^T + bfv + histogram
  hipMemsetAsync(cnt, 0, 2 * NN * 4, stream);
  hipLaunchKernelGGL(k_cvt, dim3(689 + NE / 256), dim3(256), 0, stream,
                     x, ipw, opw, W1, W2, opb, dstI,
                     xh, iph, w1h, w2h, opth, bfv, cnt);
  hipLaunchKernelGGL(k_fill, dim3(NE / 256), dim3(256), 0, stream, srcI, dstI, cnt,
                     cursor, lst, dinv);

  // Wf = W1 * Wop  (bf16)
  hipLaunchKernelGGL(gemmm, dim3(4, 4), dim3(256), 0, stream,
                     w1h, opth, (const float*)nullptr, (float*)nullptr, wfh,
                     DD, DD, DD, 1.f, 0, 0, (ushort*)nullptr, (ushort*)nullptr);

  // QKV projection: Q bf16 (pre-scaled), K bf16, V bf16 transposed
  hipLaunchKernelGGL(gemmm, dim3(64, 12), dim3(256), 0, stream,
                     xh, iph, ipb, (float*)nullptr, qhg,
                     NN, NHD, DD, QSCALE, DD, 1, khg, vhg);
  hipLaunchKernelGGL(flashm, dim3((NN / 128) * 16), dim3(256), 0, stream,
                     qhg, khg, vhg, opT, ml);
  hipLaunchKernelGGL(k_comb, dim3(NN / 32, NH), dim3(256), 0, stream, opT, ml, attnh);

  // fused out-proj + GCN1 linear: hlin1 = attn * Wf^T + W1*bop  (bf16 out)
  hipLaunchKernelGGL(gemmm, dim3(64, 4), dim3(256), 0, stream,
                     attnh, wfh, bfv, (float*)nullptr, hlin1,
                     NN, DD, DD, 1.f, 0, 0, (ushort*)nullptr, (ushort*)nullptr);
  hipLaunchKernelGGL(k_gather, dim3(NN / 4), dim3(256), 0, stream, hlin1, cnt, lst,
                     dinv, b1, (float*)nullptr, g1h, 1);
  // GCN2
  hipLaunchKernelGGL(gemmm, dim3(64, 4), dim3(256), 0, stream,
                     g1h, w2h, (const float*)nullptr, (float*)nullptr, hlin2,
                     NN, DD, DD, 1.f, 0, 0, (ushort*)nullptr, (ushort*)nullptr);
  hipLaunchKernelGGL(k_gather, dim3(NN / 4), dim3(256), 0, stream, hlin2, cnt, lst,
                     dinv, b2, (float*)d_out, (ushort*)nullptr, 0);
}

// Round 10
// 113.464 us; speedup vs baseline: 2.2611x; 1.0293x over previous
//
#include <hip/hip_runtime.h>
#include <math.h>

#define NN   4096
#define DD   256
#define NHD  768
#define NH   4
#define NE   131072
#define KVSPLIT 4
#define PAD  128
#define QSCALE 0.18033688011112042f   // 0.125 * log2(e)

using bfx8   = __attribute__((ext_vector_type(8))) short;
using f32x4  = __attribute__((ext_vector_type(4))) float;
using f32x16 = __attribute__((ext_vector_type(16))) float;
#define MFMA16(a,b,c) __builtin_amdgcn_mfma_f32_16x16x32_bf16(a, b, c, 0, 0, 0)
#define MFMA32(a,b,c) __builtin_amdgcn_mfma_f32_32x32x16_bf16(a, b, c, 0, 0, 0)

__device__ __forceinline__ ushort bf16_rne(float f) {
  uint u = __float_as_uint(f);
  u += 0x7fffu + ((u >> 16) & 1u);
  return (ushort)(u >> 16);
}
__device__ __forceinline__ float bf16_tof(ushort h) {
  return __uint_as_float(((uint)h) << 16);
}
__device__ __forceinline__ float fexp2(float x) { return __builtin_amdgcn_exp2f(x); }
__device__ __forceinline__ int swzf(int row) {   // u32-index XOR mask, bits 2..4
  return ((row & 7) << 2) ^ ((row & 8) << 1);
}
__device__ __forceinline__ uint4 cvt8(const float* f) {
  ushort hs[8];
#pragma unroll
  for (int j = 0; j < 8; ++j) hs[j] = bf16_rne(f[j]);
  return make_uint4((uint)hs[0] | ((uint)hs[1] << 16), (uint)hs[2] | ((uint)hs[3] << 16),
                    (uint)hs[4] | ((uint)hs[5] << 16), (uint)hs[6] | ((uint)hs[7] << 16));
}

// ---------------- plain-bf16 MFMA GEMM, async-staged ------------------------
// mode 0: Cf fp32 and/or Cb bf16 (stride Nc). mode 1 (QKV): col<256 -> Q bf16
// compact [row*256] (Cb, pre-scaled); 256..511 -> K bf16 (kout); >=512 -> V
// bf16 transposed [h*64+d][n] (vout).
__global__ __launch_bounds__(256, 4) void gemmm(
    const ushort* __restrict__ Ah, const ushort* __restrict__ Wh,
    const float* __restrict__ bias, float* __restrict__ Cf,
    ushort* __restrict__ Cb,
    int M, int Nc, int K, float preScale, int preScaleCols,
    int mode, ushort* __restrict__ kout, ushort* __restrict__ vout) {
  __shared__ uint sAh[2048], sBh[2048];   // 16 KB
  const int tid = threadIdx.x;
  const int wid = tid >> 6, lane = tid & 63;
  const int m15 = lane & 15, g2 = lane >> 4;
  const int wr = wid >> 1, wc = wid & 1;
  const int mb = blockIdx.x << 6, nb = blockIdx.y << 6;
  const int sw = swzf(m15);
  const int pr0 = tid >> 3, pc0 = (tid & 7) << 2;
  const int pr1 = (tid + 256) >> 3;
  const int wi0 = (pr0 << 5) + (pc0 ^ swzf(pr0));
  const int wi1 = (pr1 << 5) + (pc0 ^ swzf(pr1));
  uint4 ra0, ra1, rb0, rb1;
  auto issue = [&](int k0) {
    ra0 = *(const uint4*)(Ah + (size_t)(mb + pr0) * K + k0 + (pc0 << 1));
    ra1 = *(const uint4*)(Ah + (size_t)(mb + pr1) * K + k0 + (pc0 << 1));
    rb0 = *(const uint4*)(Wh + (size_t)(nb + pr0) * K + k0 + (pc0 << 1));
    rb1 = *(const uint4*)(Wh + (size_t)(nb + pr1) * K + k0 + (pc0 << 1));
  };
  f32x4 acc[2][2];
#pragma unroll
  for (int r = 0; r < 2; ++r)
#pragma unroll
    for (int c = 0; c < 2; ++c) acc[r][c] = (f32x4){0.f, 0.f, 0.f, 0.f};

  issue(0);
  for (int k0 = 0; k0 < K; k0 += 64) {
    __syncthreads();
    *(uint4*)&sAh[wi0] = ra0; *(uint4*)&sBh[wi0] = rb0;
    *(uint4*)&sAh[wi1] = ra1; *(uint4*)&sBh[wi1] = rb1;
    __syncthreads();
    if (k0 + 64 < K) issue(k0 + 64);
#pragma unroll
    for (int c = 0; c < 2; ++c) {
      bfx8 ah[2], bh[2];
#pragma unroll
      for (int r = 0; r < 2; ++r) {
        int rowA = (wr << 5) + (r << 4) + m15;
        ah[r] = __builtin_bit_cast(bfx8, *(const uint4*)&sAh[(rowA << 5) + (((c << 4) + (g2 << 2)) ^ sw)]);
        int rowB = (wc << 5) + (r << 4) + m15;
        bh[r] = __builtin_bit_cast(bfx8, *(const uint4*)&sBh[(rowB << 5) + (((c << 4) + (g2 << 2)) ^ sw)]);
      }
#pragma unroll
      for (int r = 0; r < 2; ++r)
#pragma unroll
        for (int cc = 0; cc < 2; ++cc)
          acc[r][cc] = MFMA16(ah[r], bh[cc], acc[r][cc]);
    }
  }
#pragma unroll
  for (int r = 0; r < 2; ++r)
#pragma unroll
    for (int cc = 0; cc < 2; ++cc) {
      int col = nb + (wc << 5) + (cc << 4) + m15;
      float bv = bias ? bias[col] : 0.f;
      float sc = (col < preScaleCols) ? preScale : 1.f;
      int row0 = mb + (wr << 5) + (r << 4) + (g2 << 2);
      float v4[4];
#pragma unroll
      for (int j = 0; j < 4; ++j) v4[j] = (acc[r][cc][j] + bv) * sc;
      if (mode == 1) {
        if (col < 256) {
#pragma unroll
          for (int j = 0; j < 4; ++j)
            Cb[(size_t)(row0 + j) * 256 + col] = bf16_rne(v4[j]);
        } else if (col < 512) {
#pragma unroll
          for (int j = 0; j < 4; ++j)
            kout[(size_t)(row0 + j) * 256 + (col - 256)] = bf16_rne(v4[j]);
        } else {
          ushort4 vs = make_ushort4(bf16_rne(v4[0]), bf16_rne(v4[1]),
                                    bf16_rne(v4[2]), bf16_rne(v4[3]));
          *(ushort4*)(vout + ((size_t)(col - 512) << 12) + row0) = vs;
        }
      } else {
#pragma unroll
        for (int j = 0; j < 4; ++j) {
          int row = row0 + j;
          if (Cf) Cf[(size_t)row * Nc + col] = v4[j];
          if (Cb) Cb[(size_t)row * Nc + col] = bf16_rne(v4[j]);
        }
      }
    }
}

// ------- convert x/ipw/W1/W2 to bf16; opw^T; bfv; zero cnt/cursor -----------
__global__ __launch_bounds__(256) void k_cvt(
    const float* __restrict__ x, const float* __restrict__ ipw,
    const float* __restrict__ opw, const float* __restrict__ W1,
    const float* __restrict__ W2, const float* __restrict__ opb,
    ushort* xh, ushort* iph, ushort* w1h, ushort* w2h,
    ushort* opth, float* bfv, int* cnt, int* cursor) {
  __shared__ float sT[64 * 65];
  int b = blockIdx.x;
  if (b >= 672) {
    if (b < 688) {                       // transpose-convert opw -> opth
      int tx = b - 672, by = tx >> 2, bx = tx & 3;
      int r = threadIdx.x >> 2, cb = (threadIdx.x & 3) << 4;
      const float* src = opw + (size_t)(by * 64 + r) * 256 + bx * 64 + cb;
#pragma unroll
      for (int i = 0; i < 4; ++i) {
        float4 v = *(const float4*)(src + i * 4);
        sT[r * 65 + cb + i * 4 + 0] = v.x; sT[r * 65 + cb + i * 4 + 1] = v.y;
        sT[r * 65 + cb + i * 4 + 2] = v.z; sT[r * 65 + cb + i * 4 + 3] = v.w;
      }
      __syncthreads();
      int d = threadIdx.x >> 2, nb2 = (threadIdx.x & 3) << 4;
      float f[16];
#pragma unroll
      for (int i = 0; i < 16; ++i) f[i] = sT[(nb2 + i) * 65 + d];
      size_t o = (size_t)(bx * 64 + d) * 256 + by * 64 + nb2;
      *(uint4*)(opth + o)     = cvt8(&f[0]);
      *(uint4*)(opth + o + 8) = cvt8(&f[8]);
    } else if (b == 688) {               // bfv = W1 * opb
      int t = threadIdx.x;
      sT[t] = opb[t];
      __syncthreads();
      float acc = 0.f;
      const float* wr = W1 + (size_t)t * 256;
      for (int k = 0; k < 256; ++k) acc += wr[k] * sT[k];
      bfv[t] = acc;
    } else {                             // 4 blocks: zero cnt + cursor
      int i = ((b - 689) * 256 + threadIdx.x) * 4;
      *(int4*)(cnt + i) = make_int4(0, 0, 0, 0);
      *(int4*)(cursor + i) = make_int4(0, 0, 0, 0);
    }
    return;
  }
  const float* src; ushort* hi; int base;
  if (b < 512)      { src = x;   hi = xh;  base = b; }
  else if (b < 608) { src = ipw; hi = iph; base = b - 512; }
  else if (b < 640) { src = W1;  hi = w1h; base = b - 608; }
  else              { src = W2;  hi = w2h; base = b - 640; }
  size_t i = (size_t)base * 256 + threadIdx.x;
  float f[8];
  *(float4*)&f[0] = *(const float4*)(src + i * 8);
  *(float4*)&f[4] = *(const float4*)(src + i * 8 + 4);
  *(uint4*)(hi + i * 8) = cvt8(f);
}

// ---------------- edge histogram (cnt zeroed by k_cvt) ----------------------
__global__ void k_hist(const int* __restrict__ dst, int* __restrict__ cnt) {
  int e = blockIdx.x * 256 + threadIdx.x;
  if (e < NE) atomicAdd(&cnt[dst[e]], 1);
}

// ------- MFMA 32x32 swapped-operand flash, plain bf16 QK and PV -------------
// 256 threads, 128 q rows, grid 512 (L2-friendly id co-location). 16 KB LDS.
__global__ __launch_bounds__(256, 2) void flashm(
    const ushort* __restrict__ qhg, const ushort* __restrict__ khg,
    const ushort* __restrict__ vhg,
    float* __restrict__ opT, float* __restrict__ ml) {
  __shared__ uint sKh[2048], sVh[2048];   // 16 KB

  const int b = blockIdx.x;
  const int id = b & 15;                 // (h,split): co-located per XCD
  const int h = id >> 2, split = id & 3;
  const int qb = (b >> 4) << 7;          // 128 q rows per block
  const int kv0 = split << 10;           // 1024 keys per split
  const int NT = 16;

  const int tid = threadIdx.x;
  const int wid = tid >> 6, lane = tid & 63;
  const int m31 = lane & 31, g = lane >> 5;

  bfx8 qh[4];
  {
    const size_t qoff = (size_t)(qb + (wid << 5) + m31) * 256 + h * 64 + (g << 3);
#pragma unroll
    for (int c = 0; c < 4; ++c)
      qh[c] = __builtin_bit_cast(bfx8, *(const uint4*)(qhg + qoff + (c << 4)));
  }

  f32x16 o[2];
#pragma unroll
  for (int dt = 0; dt < 2; ++dt)
#pragma unroll
    for (int j = 0; j < 16; ++j) o[dt][j] = 0.f;
  float mreg = -1e30f;
  float lacc[16];
#pragma unroll
  for (int j = 0; j < 16; ++j) lacc[j] = 0.f;

  // staging: 2 chunks of 256 threads x 16B (K tile 8 KB + V tile 8 KB)
  const int pr0 = tid >> 3, pc0 = (tid & 7) << 2;
  const int pr1 = (tid + 256) >> 3;
  const int wi0 = (pr0 << 5) + (pc0 ^ swzf(pr0));
  const int wi1 = (pr1 << 5) + (pc0 ^ swzf(pr1));
  uint4 rk0, rk1, rv0, rv1;
  auto issue = [&](int kv) {
    rk0 = *(const uint4*)(khg + (size_t)(kv + pr0) * 256 + h * 64 + (pc0 << 1));
    rk1 = *(const uint4*)(khg + (size_t)(kv + pr1) * 256 + h * 64 + (pc0 << 1));
    rv0 = *(const uint4*)(vhg + ((size_t)(h * 64 + pr0) << 12) + kv + (pc0 << 1));
    rv1 = *(const uint4*)(vhg + ((size_t)(h * 64 + pr1) << 12) + kv + (pc0 << 1));
  };

  issue(kv0);
  for (int it = 0; it < NT; ++it) {
    __syncthreads();
    *(uint4*)&sKh[wi0] = rk0; *(uint4*)&sVh[wi0] = rv0;
    *(uint4*)&sKh[wi1] = rk1; *(uint4*)&sVh[wi1] = rv1;
    __syncthreads();
    if (it + 1 < NT) issue(kv0 + ((it + 1) << 6));

    // ---- S^T = K_bf16 * Q_bf16, log2-domain ----
    f32x16 s[2];
#pragma unroll
    for (int kt = 0; kt < 2; ++kt) {
#pragma unroll
      for (int j = 0; j < 16; ++j) s[kt][j] = 0.f;
      const int row = (kt << 5) + m31;
      const int rb = row << 5;
      const int sw2 = swzf(row);
      __builtin_amdgcn_s_setprio(1);
#pragma unroll
      for (int c = 0; c < 4; ++c) {
        int col = ((c << 3) + (g << 2)) ^ sw2;
        bfx8 kh = __builtin_bit_cast(bfx8, *(const uint4*)&sKh[rb + col]);
        s[kt] = MFMA32(kh, qh[c], s[kt]);
      }
      __builtin_amdgcn_s_setprio(0);
    }

    // ---- online softmax, lane-local for q = m31; deferred l ----
    float v16[16];
#pragma unroll
    for (int j = 0; j < 16; ++j) v16[j] = fmaxf(s[0][j], s[1][j]);
#pragma unroll
    for (int st = 8; st; st >>= 1)
#pragma unroll
      for (int j = 0; j < 8; ++j)
        if (j < st) v16[j] = fmaxf(v16[j], v16[j + st]);
    float mt = fmaxf(v16[0], __shfl_xor(v16[0], 32));
    int need = (mt > mreg + 8.f) ? 1 : 0;
    if (__any(need)) {
      float mn = fmaxf(mreg, mt);
      float al = fexp2(mreg - mn);
      mreg = mn;
#pragma unroll
      for (int j = 0; j < 16; ++j) lacc[j] *= al;
#pragma unroll
      for (int dt = 0; dt < 2; ++dt)
#pragma unroll
        for (int j = 0; j < 16; ++j) o[dt][j] *= al;
    }
    float p0[16], p1[16];
#pragma unroll
    for (int j = 0; j < 16; ++j) {
      p0[j] = fexp2(s[0][j] - mreg);
      p1[j] = fexp2(s[1][j] - mreg);
      lacc[j] += p0[j] + p1[j];
    }

    // ---- pack P to bf16 (trunc) in-register ----
    uint puh[2][8];
#pragma unroll
    for (int kt = 0; kt < 2; ++kt)
#pragma unroll
      for (int jj = 0; jj < 8; ++jj) {
        float a = kt ? p1[2 * jj] : p0[2 * jj];
        float bq = kt ? p1[2 * jj + 1] : p0[2 * jj + 1];
        puh[kt][jj] = (__float_as_uint(a) >> 16) | (__float_as_uint(bq) & 0xffff0000u);
      }

    // ---- O^T += V^T_bf16 * P_bf16, permuted K-order ----
#pragma unroll
    for (int dt = 0; dt < 2; ++dt) {
      const int row = (dt << 5) + m31;
      const int rb = row << 5;
      const int sw2 = swzf(row);
      __builtin_amdgcn_s_setprio(1);
#pragma unroll
      for (int kt = 0; kt < 2; ++kt)
#pragma unroll
        for (int cc = 0; cc < 2; ++cc) {
          int cA = ((kt << 4) + (cc << 3) + (g << 1)) ^ sw2;
          int cB = ((kt << 4) + (cc << 3) + (g << 1) + 4) ^ sw2;
          uint2 vh0 = *(const uint2*)&sVh[rb + cA];
          uint2 vh1 = *(const uint2*)&sVh[rb + cB];
          bfx8 ah = __builtin_bit_cast(bfx8, make_uint4(vh0.x, vh0.y, vh1.x, vh1.y));
          bfx8 bh = __builtin_bit_cast(bfx8, make_uint4(puh[kt][4 * cc], puh[kt][4 * cc + 1],
                                                        puh[kt][4 * cc + 2], puh[kt][4 * cc + 3]));
          o[dt] = MFMA32(ah, bh, o[dt]);
        }
      __builtin_amdgcn_s_setprio(0);
    }
  }

  // final l reduction (deferred)
  float lreg;
  {
#pragma unroll
    for (int st = 8; st; st >>= 1)
#pragma unroll
      for (int j = 0; j < 8; ++j)
        if (j < st) lacc[j] += lacc[j + st];
    lreg = lacc[0] + __shfl_xor(lacc[0], 32);
  }

  const int region = (split * NH + h) * (NN >> 5) + (qb >> 5) + wid;
  float* ob = opT + (size_t)region * 2048;
#pragma unroll
  for (int dt = 0; dt < 2; ++dt)
#pragma unroll
    for (int r = 0; r < 16; ++r) {
      int d = (dt << 5) + (r & 3) + ((r >> 2) << 3) + (g << 2);
      ob[(d << 5) + m31] = o[dt][r];
    }
  if (!g) {
    size_t qi = (size_t)(split * NH + h) * NN + qb + (wid << 5) + m31;
    ml[qi * 2]     = mreg;
    ml[qi * 2 + 1] = lreg;
  }
}

// ---------------- combine KV-split partials -> attn bf16 --------------------
__global__ __launch_bounds__(256) void k_comb(const float* __restrict__ opT,
    const float* __restrict__ ml, ushort* __restrict__ attnh) {
  int qt = blockIdx.x, h = blockIdx.y, t = threadIdx.x;
  int qq = t & 31, dg = t >> 5;
  int q = (qt << 5) + qq;
  float ms[KVSPLIT], ls[KVSPLIT];
#pragma unroll
  for (int s = 0; s < KVSPLIT; ++s) {
    const float* e = ml + ((size_t)(s * NH + h) * NN + q) * 2;
    ms[s] = e[0]; ls[s] = e[1];
  }
  float Mx = ms[0];
#pragma unroll
  for (int s = 1; s < KVSPLIT; ++s) Mx = fmaxf(Mx, ms[s]);
  float cs[KVSPLIT], L = 0.f;
#pragma unroll
  for (int s = 0; s < KVSPLIT; ++s) { cs[s] = fexp2(ms[s] - Mx); L += ls[s] * cs[s]; }
  float invL = 1.f / L;
  float vals[8];
#pragma unroll
  for (int j = 0; j < 8; ++j) {
    int d = (dg << 3) + j;
    float acc = 0.f;
#pragma unroll
    for (int s = 0; s < KVSPLIT; ++s)
      acc += opT[((size_t)((s * NH + h) * (NN >> 5) + qt)) * 2048 + (d << 5) + qq] * cs[s];
    vals[j] = acc * invL;
  }
  size_t oo = (size_t)q * DD + h * 64 + (dg << 3);
  *(uint4*)(attnh + oo) = cvt8(vals);
}

// ---------------- CSR (fixed-stride) + gather (bf16 input) ------------------
__global__ void k_fill(const int* __restrict__ src, const int* __restrict__ dst,
    const int* __restrict__ cnt, int* cursor, int* __restrict__ lst,
    float* __restrict__ dinv) {
  int e = blockIdx.x * 256 + threadIdx.x;
  if (e < NN) dinv[e] = (float)(1.0 / sqrt((double)(cnt[e] + 1)));
  if (e < NE) {
    int d = dst[e];
    int pos = atomicAdd(&cursor[d], 1);
    if (pos < PAD) lst[(d << 7) + pos] = src[e];
  }
}
__device__ __forceinline__ float4 bf4_tof(ushort4 u) {
  return make_float4(bf16_tof(u.x), bf16_tof(u.y), bf16_tof(u.z), bf16_tof(u.w));
}
__global__ __launch_bounds__(256) void k_gather(const ushort* __restrict__ hin,
    const int* __restrict__ cnt, const int* __restrict__ lst,
    const float* __restrict__ dinv, const float* __restrict__ bias,
    float* __restrict__ outF, ushort* __restrict__ oh, int relu) {
  int g = (blockIdx.x << 2) + (threadIdx.x >> 6);
  int lane = threadIdx.x & 63;
  float di = dinv[g];
  int c4 = lane << 2;
  float4 hv = bf4_tof(*(const ushort4*)(hin + (size_t)g * DD + c4));
  float w = di * di;
  float a0x = hv.x * w, a0y = hv.y * w, a0z = hv.z * w, a0w = hv.w * w;
  float a1x = 0, a1y = 0, a1z = 0, a1w = 0;
  float a2x = 0, a2y = 0, a2z = 0, a2w = 0;
  float a3x = 0, a3y = 0, a3z = 0, a3w = 0;
  int num = min(cnt[g], PAD);
  const int* lrow = lst + (g << 7);
  int i = 0;
  for (; i + 4 <= num; i += 4) {
    int4 s4 = *(const int4*)(lrow + i);
    float w0 = dinv[s4.x] * di, w1 = dinv[s4.y] * di;
    float w2 = dinv[s4.z] * di, w3 = dinv[s4.w] * di;
    float4 h0 = bf4_tof(*(const ushort4*)(hin + (size_t)s4.x * DD + c4));
    float4 h1 = bf4_tof(*(const ushort4*)(hin + (size_t)s4.y * DD + c4));
    float4 h2 = bf4_tof(*(const ushort4*)(hin + (size_t)s4.z * DD + c4));
    float4 h3 = bf4_tof(*(const ushort4*)(hin + (size_t)s4.w * DD + c4));
    a0x += h0.x * w0; a0y += h0.y * w0; a0z += h0.z * w0; a0w += h0.w * w0;
    a1x += h1.x * w1; a1y += h1.y * w1; a1z += h1.z * w1; a1w += h1.w * w1;
    a2x += h2.x * w2; a2y += h2.y * w2; a2z += h2.z * w2; a2w += h2.w * w2;
    a3x += h3.x * w3; a3y += h3.y * w3; a3z += h3.z * w3; a3w += h3.w * w3;
  }
  for (; i < num; ++i) {
    int sI = lrow[i];
    float ww = dinv[sI] * di;
    float4 hs = bf4_tof(*(const ushort4*)(hin + (size_t)sI * DD + c4));
    a0x += hs.x * ww; a0y += hs.y * ww; a0z += hs.z * ww; a0w += hs.w * ww;
  }
  float4 bv = *(const float4*)(bias + c4);
  float4 acc = make_float4((a0x + a1x) + (a2x + a3x) + bv.x,
                           (a0y + a1y) + (a2y + a3y) + bv.y,
                           (a0z + a1z) + (a2z + a3z) + bv.z,
                           (a0w + a1w) + (a2w + a3w) + bv.w);
  if (relu) {
    acc.x = fmaxf(acc.x, 0.f); acc.y = fmaxf(acc.y, 0.f);
    acc.z = fmaxf(acc.z, 0.f); acc.w = fmaxf(acc.w, 0.f);
  }
  if (outF) *(float4*)(outF + (size_t)g * DD + c4) = acc;
  if (oh) {
    size_t oo = (size_t)g * DD + c4;
    *(ushort4*)(oh + oo) = make_ushort4(bf16_rne(acc.x), bf16_rne(acc.y),
                                        bf16_rne(acc.z), bf16_rne(acc.w));
  }
}

// ---------------- launch ---------------------------------------------------
extern "C" void kernel_launch(void* const* d_in, const int* in_sizes, int n_in,
                              void* d_out, int out_size, void* d_ws, size_t ws_size,
                              hipStream_t stream) {
  const float* x   = (const float*)d_in[0];
  const int*   ei  = (const int*)d_in[1];
  const float* ipw = (const float*)d_in[2];
  const float* ipb = (const float*)d_in[3];
  const float* opw = (const float*)d_in[4];
  const float* opb = (const float*)d_in[5];
  const float* W1  = (const float*)d_in[6];
  const float* b1  = (const float*)d_in[7];
  const float* W2  = (const float*)d_in[8];
  const float* b2  = (const float*)d_in[9];
  const int* srcI = ei;
  const int* dstI = ei + NE;

  char* w = (char*)d_ws;
  ushort* qhg   = (ushort*)w; w += (size_t)NN * DD * 2;
  ushort* khg   = (ushort*)w; w += (size_t)NN * DD * 2;
  ushort* vhg   = (ushort*)w; w += (size_t)NH * NN * 64 * 2;
  ushort* xh    = (ushort*)w; w += (size_t)NN * DD * 2;   // reused as attnh
  ushort* iph   = (ushort*)w; w += (size_t)NHD * DD * 2;
  ushort* w1h   = (ushort*)w; w += (size_t)DD * DD * 2;
  ushort* w2h   = (ushort*)w; w += (size_t)DD * DD * 2;
  ushort* opth  = (ushort*)w; w += (size_t)DD * DD * 2;
  ushort* wfh   = (ushort*)w; w += (size_t)DD * DD * 2;
  float*  bfv   = (float*)w;  w += (size_t)DD * 4;
  ushort* hlin1 = (ushort*)w; w += (size_t)NN * DD * 2;
  ushort* hlin2 = (ushort*)w; w += (size_t)NN * DD * 2;
  ushort* g1h   = (ushort*)w; w += (size_t)NN * DD * 2;
  float*  opT   = (float*)w;  w += (size_t)KVSPLIT * NH * NN * 64 * 4;
  float*  ml    = (float*)w;  w += (size_t)KVSPLIT * NH * NN * 2 * 4;
  int*    cnt    = (int*)w;   w += NN * 4;
  int*    cursor = (int*)w;   w += NN * 4;
  float*  dinv   = (float*)w; w += NN * 4;
  int*    lst    = (int*)w;   w += (size_t)NN * PAD * 4;
  ushort* attnh = xh;

  // conversions + opw^T + bfv + zero cnt/cursor (no memset — fill kernel is ~40us)
  hipLaunchKernelGGL(k_cvt, dim3(693), dim3(256), 0, stream,
                     x, ipw, opw, W1, W2, opb,
                     xh, iph, w1h, w2h, opth, bfv, cnt, cursor);
  hipLaunchKernelGGL(k_hist, dim3(NE / 256), dim3(256), 0, stream, dstI, cnt);
  hipLaunchKernelGGL(k_fill, dim3(NE / 256), dim3(256), 0, stream, srcI, dstI, cnt,
                     cursor, lst, dinv);

  // Wf = W1 * Wop  (bf16)
  hipLaunchKernelGGL(gemmm, dim3(4, 4), dim3(256), 0, stream,
                     w1h, opth, (const float*)nullptr, (float*)nullptr, wfh,
                     DD, DD, DD, 1.f, 0, 0, (ushort*)nullptr, (ushort*)nullptr);

  // QKV projection: Q bf16 (pre-scaled), K bf16, V bf16 transposed
  hipLaunchKernelGGL(gemmm, dim3(64, 12), dim3(256), 0, stream,
                     xh, iph, ipb, (float*)nullptr, qhg,
                     NN, NHD, DD, QSCALE, DD, 1, khg, vhg);
  hipLaunchKernelGGL(flashm, dim3((NN / 128) * 16), dim3(256), 0, stream,
                     qhg, khg, vhg, opT, ml);
  hipLaunchKernelGGL(k_comb, dim3(NN / 32, NH), dim3(256), 0, stream, opT, ml, attnh);

  // fused out-proj + GCN1 linear: hlin1 = attn * Wf^T + W1*bop  (bf16 out)
  hipLaunchKernelGGL(gemmm, dim3(64, 4), dim3(256), 0, stream,
                     attnh, wfh, bfv, (float*)nullptr, hlin1,
                     NN, DD, DD, 1.f, 0, 0, (ushort*)nullptr, (ushort*)nullptr);
  hipLaunchKernelGGL(k_gather, dim3(NN / 4), dim3(256), 0, stream, hlin1, cnt, lst,
                     dinv, b1, (float*)nullptr, g1h, 1);
  // GCN2
  hipLaunchKernelGGL(gemmm, dim3(64, 4), dim3(256), 0, stream,
                     g1h, w2h, (const float*)nullptr, (float*)nullptr, hlin2,
                     NN, DD, DD, 1.f, 0, 0, (ushort*)nullptr, (ushort*)nullptr);
  hipLaunchKernelGGL(k_gather, dim3(NN / 4), dim3(256), 0, stream, hlin2, cnt, lst,
                     dinv, b2, (float*)d_out, (ushort*)nullptr, 0);
}

// Round 11
// 104.537 us; speedup vs baseline: 2.4542x; 1.0854x over previous
//
#include <hip/hip_runtime.h>
#include <math.h>

#define NN   4096
#define DD   256
#define NHD  768
#define NH   4
#define NE   131072
#define KVSPLIT 4
#define PAD  128
#define QSCALE 0.18033688011112042f   // 0.125 * log2(e)

using bfx8   = __attribute__((ext_vector_type(8))) short;
using f32x4  = __attribute__((ext_vector_type(4))) float;
using f32x16 = __attribute__((ext_vector_type(16))) float;
#define MFMA16(a,b,c) __builtin_amdgcn_mfma_f32_16x16x32_bf16(a, b, c, 0, 0, 0)
#define MFMA32(a,b,c) __builtin_amdgcn_mfma_f32_32x32x16_bf16(a, b, c, 0, 0, 0)

__device__ __forceinline__ ushort bf16_rne(float f) {
  uint u = __float_as_uint(f);
  u += 0x7fffu + ((u >> 16) & 1u);
  return (ushort)(u >> 16);
}
__device__ __forceinline__ float bf16_tof(ushort h) {
  return __uint_as_float(((uint)h) << 16);
}
__device__ __forceinline__ float fexp2(float x) { return __builtin_amdgcn_exp2f(x); }
__device__ __forceinline__ int swzf(int row) {   // u32-index XOR mask, bits 2..4
  return ((row & 7) << 2) ^ ((row & 8) << 1);
}
__device__ __forceinline__ uint4 cvt8(const float* f) {
  ushort hs[8];
#pragma unroll
  for (int j = 0; j < 8; ++j) hs[j] = bf16_rne(f[j]);
  return make_uint4((uint)hs[0] | ((uint)hs[1] << 16), (uint)hs[2] | ((uint)hs[3] << 16),
                    (uint)hs[4] | ((uint)hs[5] << 16), (uint)hs[6] | ((uint)hs[7] << 16));
}

// ---------------- plain-bf16 MFMA GEMM, async-staged ------------------------
// mode 0: Cf fp32 and/or Cb bf16 (stride Nc). mode 1 (QKV): col<256 -> Q bf16
// compact [row*256] (Cb, pre-scaled); 256..511 -> K bf16 (kout); >=512 -> V
// bf16 transposed [h*64+d][n] (vout).
__global__ __launch_bounds__(256, 4) void gemmm(
    const ushort* __restrict__ Ah, const ushort* __restrict__ Wh,
    const float* __restrict__ bias, float* __restrict__ Cf,
    ushort* __restrict__ Cb,
    int M, int Nc, int K, float preScale, int preScaleCols,
    int mode, ushort* __restrict__ kout, ushort* __restrict__ vout) {
  __shared__ uint sAh[2048], sBh[2048];   // 16 KB
  const int tid = threadIdx.x;
  const int wid = tid >> 6, lane = tid & 63;
  const int m15 = lane & 15, g2 = lane >> 4;
  const int wr = wid >> 1, wc = wid & 1;
  const int mb = blockIdx.x << 6, nb = blockIdx.y << 6;
  const int sw = swzf(m15);
  const int pr0 = tid >> 3, pc0 = (tid & 7) << 2;
  const int pr1 = (tid + 256) >> 3;
  const int wi0 = (pr0 << 5) + (pc0 ^ swzf(pr0));
  const int wi1 = (pr1 << 5) + (pc0 ^ swzf(pr1));
  uint4 ra0, ra1, rb0, rb1;
  auto issue = [&](int k0) {
    ra0 = *(const uint4*)(Ah + (size_t)(mb + pr0) * K + k0 + (pc0 << 1));
    ra1 = *(const uint4*)(Ah + (size_t)(mb + pr1) * K + k0 + (pc0 << 1));
    rb0 = *(const uint4*)(Wh + (size_t)(nb + pr0) * K + k0 + (pc0 << 1));
    rb1 = *(const uint4*)(Wh + (size_t)(nb + pr1) * K + k0 + (pc0 << 1));
  };
  f32x4 acc[2][2];
#pragma unroll
  for (int r = 0; r < 2; ++r)
#pragma unroll
    for (int c = 0; c < 2; ++c) acc[r][c] = (f32x4){0.f, 0.f, 0.f, 0.f};

  issue(0);
  for (int k0 = 0; k0 < K; k0 += 64) {
    __syncthreads();
    *(uint4*)&sAh[wi0] = ra0; *(uint4*)&sBh[wi0] = rb0;
    *(uint4*)&sAh[wi1] = ra1; *(uint4*)&sBh[wi1] = rb1;
    __syncthreads();
    if (k0 + 64 < K) issue(k0 + 64);
#pragma unroll
    for (int c = 0; c < 2; ++c) {
      bfx8 ah[2], bh[2];
#pragma unroll
      for (int r = 0; r < 2; ++r) {
        int rowA = (wr << 5) + (r << 4) + m15;
        ah[r] = __builtin_bit_cast(bfx8, *(const uint4*)&sAh[(rowA << 5) + (((c << 4) + (g2 << 2)) ^ sw)]);
        int rowB = (wc << 5) + (r << 4) + m15;
        bh[r] = __builtin_bit_cast(bfx8, *(const uint4*)&sBh[(rowB << 5) + (((c << 4) + (g2 << 2)) ^ sw)]);
      }
#pragma unroll
      for (int r = 0; r < 2; ++r)
#pragma unroll
        for (int cc = 0; cc < 2; ++cc)
          acc[r][cc] = MFMA16(ah[r], bh[cc], acc[r][cc]);
    }
  }
#pragma unroll
  for (int r = 0; r < 2; ++r)
#pragma unroll
    for (int cc = 0; cc < 2; ++cc) {
      int col = nb + (wc << 5) + (cc << 4) + m15;
      float bv = bias ? bias[col] : 0.f;
      float sc = (col < preScaleCols) ? preScale : 1.f;
      int row0 = mb + (wr << 5) + (r << 4) + (g2 << 2);
      float v4[4];
#pragma unroll
      for (int j = 0; j < 4; ++j) v4[j] = (acc[r][cc][j] + bv) * sc;
      if (mode == 1) {
        if (col < 256) {
#pragma unroll
          for (int j = 0; j < 4; ++j)
            Cb[(size_t)(row0 + j) * 256 + col] = bf16_rne(v4[j]);
        } else if (col < 512) {
#pragma unroll
          for (int j = 0; j < 4; ++j)
            kout[(size_t)(row0 + j) * 256 + (col - 256)] = bf16_rne(v4[j]);
        } else {
          ushort4 vs = make_ushort4(bf16_rne(v4[0]), bf16_rne(v4[1]),
                                    bf16_rne(v4[2]), bf16_rne(v4[3]));
          *(ushort4*)(vout + ((size_t)(col - 512) << 12) + row0) = vs;
        }
      } else {
#pragma unroll
        for (int j = 0; j < 4; ++j) {
          int row = row0 + j;
          if (Cf) Cf[(size_t)row * Nc + col] = v4[j];
          if (Cb) Cb[(size_t)row * Nc + col] = bf16_rne(v4[j]);
        }
      }
    }
}

// ------- convert x/ipw/W1/W2 to bf16; opw^T; bfv; zero cursor ---------------
__global__ __launch_bounds__(256) void k_cvt(
    const float* __restrict__ x, const float* __restrict__ ipw,
    const float* __restrict__ opw, const float* __restrict__ W1,
    const float* __restrict__ W2, const float* __restrict__ opb,
    ushort* xh, ushort* iph, ushort* w1h, ushort* w2h,
    ushort* opth, float* bfv, int* cursor) {
  __shared__ float sT[64 * 65];
  int b = blockIdx.x;
  if (b >= 672) {
    if (b < 688) {                       // transpose-convert opw -> opth
      int tx = b - 672, by = tx >> 2, bx = tx & 3;
      int r = threadIdx.x >> 2, cb = (threadIdx.x & 3) << 4;
      const float* src = opw + (size_t)(by * 64 + r) * 256 + bx * 64 + cb;
#pragma unroll
      for (int i = 0; i < 4; ++i) {
        float4 v = *(const float4*)(src + i * 4);
        sT[r * 65 + cb + i * 4 + 0] = v.x; sT[r * 65 + cb + i * 4 + 1] = v.y;
        sT[r * 65 + cb + i * 4 + 2] = v.z; sT[r * 65 + cb + i * 4 + 3] = v.w;
      }
      __syncthreads();
      int d = threadIdx.x >> 2, nb2 = (threadIdx.x & 3) << 4;
      float f[16];
#pragma unroll
      for (int i = 0; i < 16; ++i) f[i] = sT[(nb2 + i) * 65 + d];
      size_t o = (size_t)(bx * 64 + d) * 256 + by * 64 + nb2;
      *(uint4*)(opth + o)     = cvt8(&f[0]);
      *(uint4*)(opth + o + 8) = cvt8(&f[8]);
    } else if (b == 688) {               // bfv = W1 * opb
      int t = threadIdx.x;
      sT[t] = opb[t];
      __syncthreads();
      float acc = 0.f;
      const float* wr = W1 + (size_t)t * 256;
      for (int k = 0; k < 256; ++k) acc += wr[k] * sT[k];
      bfv[t] = acc;
    } else {                             // 4 blocks: zero cursor
      int i = ((b - 689) * 256 + threadIdx.x) * 4;
      *(int4*)(cursor + i) = make_int4(0, 0, 0, 0);
    }
    return;
  }
  const float* src; ushort* hi; int base;
  if (b < 512)      { src = x;   hi = xh;  base = b; }
  else if (b < 608) { src = ipw; hi = iph; base = b - 512; }
  else if (b < 640) { src = W1;  hi = w1h; base = b - 608; }
  else              { src = W2;  hi = w2h; base = b - 640; }
  size_t i = (size_t)base * 256 + threadIdx.x;
  float f[8];
  *(float4*)&f[0] = *(const float4*)(src + i * 8);
  *(float4*)&f[4] = *(const float4*)(src + i * 8 + 4);
  *(uint4*)(hi + i * 8) = cvt8(f);
}

// ---------------- CSR fill; cursor ends as in-degree ------------------------
__global__ void k_fill(const int* __restrict__ src, const int* __restrict__ dst,
    int* cursor, int* __restrict__ lst) {
  int e = blockIdx.x * 256 + threadIdx.x;
  if (e < NE) {
    int d = dst[e];
    int pos = atomicAdd(&cursor[d], 1);
    if (pos < PAD) lst[(d << 7) + pos] = src[e];
  }
}

// ------- MFMA 32x32 swapped-operand flash, plain bf16, 1-barrier dbuf -------
// 256 threads, 128 q rows, grid 512 (L2-friendly id co-location). 32 KB LDS.
__global__ __launch_bounds__(256, 2) void flashm(
    const ushort* __restrict__ qhg, const ushort* __restrict__ khg,
    const ushort* __restrict__ vhg,
    float* __restrict__ opT, float* __restrict__ ml) {
  __shared__ uint sKh[4096], sVh[4096];   // double-buffered, 32 KB

  const int b = blockIdx.x;
  const int id = b & 15;                 // (h,split): co-located per XCD
  const int h = id >> 2, split = id & 3;
  const int qb = (b >> 4) << 7;          // 128 q rows per block
  const int kv0 = split << 10;           // 1024 keys per split
  const int NT = 16;

  const int tid = threadIdx.x;
  const int wid = tid >> 6, lane = tid & 63;
  const int m31 = lane & 31, g = lane >> 5;

  bfx8 qh[4];
  {
    const size_t qoff = (size_t)(qb + (wid << 5) + m31) * 256 + h * 64 + (g << 3);
#pragma unroll
    for (int c = 0; c < 4; ++c)
      qh[c] = __builtin_bit_cast(bfx8, *(const uint4*)(qhg + qoff + (c << 4)));
  }

  f32x16 o[2];
#pragma unroll
  for (int dt = 0; dt < 2; ++dt)
#pragma unroll
    for (int j = 0; j < 16; ++j) o[dt][j] = 0.f;
  float mreg = -1e30f;
  float lacc[16];
#pragma unroll
  for (int j = 0; j < 16; ++j) lacc[j] = 0.f;

  // staging: 2 chunks of 256 threads x 16B (K tile 8 KB + V tile 8 KB)
  const int pr0 = tid >> 3, pc0 = (tid & 7) << 2;
  const int pr1 = (tid + 256) >> 3;
  const int wi0 = (pr0 << 5) + (pc0 ^ swzf(pr0));
  const int wi1 = (pr1 << 5) + (pc0 ^ swzf(pr1));
  uint4 rk0, rk1, rv0, rv1;
  auto issue = [&](int kv) {
    rk0 = *(const uint4*)(khg + (size_t)(kv + pr0) * 256 + h * 64 + (pc0 << 1));
    rk1 = *(const uint4*)(khg + (size_t)(kv + pr1) * 256 + h * 64 + (pc0 << 1));
    rv0 = *(const uint4*)(vhg + ((size_t)(h * 64 + pr0) << 12) + kv + (pc0 << 1));
    rv1 = *(const uint4*)(vhg + ((size_t)(h * 64 + pr1) << 12) + kv + (pc0 << 1));
  };
  auto writebuf = [&](int buf) {
    uint* K = sKh + (buf << 11);
    uint* V = sVh + (buf << 11);
    *(uint4*)&K[wi0] = rk0; *(uint4*)&V[wi0] = rv0;
    *(uint4*)&K[wi1] = rk1; *(uint4*)&V[wi1] = rv1;
  };

  // prologue: tile0 -> buf0, tile1 in regs
  issue(kv0);
  writebuf(0);
  issue(kv0 + 64);
  __syncthreads();

  for (int it = 0; it < NT; ++it) {
    const int cur = it & 1;
    if (it + 1 < NT) writebuf(cur ^ 1);           // overlaps with compute below
    if (it + 2 < NT) issue(kv0 + ((it + 2) << 6));
    const uint* Kb = sKh + (cur << 11);
    const uint* Vb = sVh + (cur << 11);

    // ---- S^T = K_bf16 * Q_bf16, log2-domain ----
    f32x16 s[2];
#pragma unroll
    for (int kt = 0; kt < 2; ++kt) {
#pragma unroll
      for (int j = 0; j < 16; ++j) s[kt][j] = 0.f;
      const int row = (kt << 5) + m31;
      const int rb = row << 5;
      const int sw2 = swzf(row);
      __builtin_amdgcn_s_setprio(1);
#pragma unroll
      for (int c = 0; c < 4; ++c) {
        int col = ((c << 3) + (g << 2)) ^ sw2;
        bfx8 kh = __builtin_bit_cast(bfx8, *(const uint4*)&Kb[rb + col]);
        s[kt] = MFMA32(kh, qh[c], s[kt]);
      }
      __builtin_amdgcn_s_setprio(0);
    }

    // ---- online softmax, lane-local for q = m31; deferred l ----
    float v16[16];
#pragma unroll
    for (int j = 0; j < 16; ++j) v16[j] = fmaxf(s[0][j], s[1][j]);
#pragma unroll
    for (int st = 8; st; st >>= 1)
#pragma unroll
      for (int j = 0; j < 8; ++j)
        if (j < st) v16[j] = fmaxf(v16[j], v16[j + st]);
    float mt = fmaxf(v16[0], __shfl_xor(v16[0], 32));
    int need = (mt > mreg + 8.f) ? 1 : 0;
    if (__any(need)) {
      float mn = fmaxf(mreg, mt);
      float al = fexp2(mreg - mn);
      mreg = mn;
#pragma unroll
      for (int j = 0; j < 16; ++j) lacc[j] *= al;
#pragma unroll
      for (int dt = 0; dt < 2; ++dt)
#pragma unroll
        for (int j = 0; j < 16; ++j) o[dt][j] *= al;
    }
    float p0[16], p1[16];
#pragma unroll
    for (int j = 0; j < 16; ++j) {
      p0[j] = fexp2(s[0][j] - mreg);
      p1[j] = fexp2(s[1][j] - mreg);
      lacc[j] += p0[j] + p1[j];
    }

    // ---- pack P to bf16 (trunc) in-register ----
    uint puh[2][8];
#pragma unroll
    for (int kt = 0; kt < 2; ++kt)
#pragma unroll
      for (int jj = 0; jj < 8; ++jj) {
        float a = kt ? p1[2 * jj] : p0[2 * jj];
        float bq = kt ? p1[2 * jj + 1] : p0[2 * jj + 1];
        puh[kt][jj] = (__float_as_uint(a) >> 16) | (__float_as_uint(bq) & 0xffff0000u);
      }

    // ---- O^T += V^T_bf16 * P_bf16, permuted K-order ----
#pragma unroll
    for (int dt = 0; dt < 2; ++dt) {
      const int row = (dt << 5) + m31;
      const int rb = row << 5;
      const int sw2 = swzf(row);
      __builtin_amdgcn_s_setprio(1);
#pragma unroll
      for (int kt = 0; kt < 2; ++kt)
#pragma unroll
        for (int cc = 0; cc < 2; ++cc) {
          int cA = ((kt << 4) + (cc << 3) + (g << 1)) ^ sw2;
          int cB = ((kt << 4) + (cc << 3) + (g << 1) + 4) ^ sw2;
          uint2 vh0 = *(const uint2*)&Vb[rb + cA];
          uint2 vh1 = *(const uint2*)&Vb[rb + cB];
          bfx8 ah = __builtin_bit_cast(bfx8, make_uint4(vh0.x, vh0.y, vh1.x, vh1.y));
          bfx8 bh = __builtin_bit_cast(bfx8, make_uint4(puh[kt][4 * cc], puh[kt][4 * cc + 1],
                                                        puh[kt][4 * cc + 2], puh[kt][4 * cc + 3]));
          o[dt] = MFMA32(ah, bh, o[dt]);
        }
      __builtin_amdgcn_s_setprio(0);
    }
    __syncthreads();   // seals my reads of buf[cur] and writes of buf[cur^1]
  }

  // final l reduction (deferred)
  float lreg;
  {
#pragma unroll
    for (int st = 8; st; st >>= 1)
#pragma unroll
      for (int j = 0; j < 8; ++j)
        if (j < st) lacc[j] += lacc[j + st];
    lreg = lacc[0] + __shfl_xor(lacc[0], 32);
  }

  const int region = (split * NH + h) * (NN >> 5) + (qb >> 5) + wid;
  float* ob = opT + (size_t)region * 2048;
#pragma unroll
  for (int dt = 0; dt < 2; ++dt)
#pragma unroll
    for (int r = 0; r < 16; ++r) {
      int d = (dt << 5) + (r & 3) + ((r >> 2) << 3) + (g << 2);
      ob[(d << 5) + m31] = o[dt][r];
    }
  if (!g) {
    size_t qi = (size_t)(split * NH + h) * NN + qb + (wid << 5) + m31;
    ml[qi * 2]     = mreg;
    ml[qi * 2 + 1] = lreg;
  }
}

// ---------------- combine KV-split partials -> attn bf16 --------------------
__global__ __launch_bounds__(256) void k_comb(const float* __restrict__ opT,
    const float* __restrict__ ml, ushort* __restrict__ attnh) {
  int qt = blockIdx.x, h = blockIdx.y, t = threadIdx.x;
  int qq = t & 31, dg = t >> 5;
  int q = (qt << 5) + qq;
  float ms[KVSPLIT], ls[KVSPLIT];
#pragma unroll
  for (int s = 0; s < KVSPLIT; ++s) {
    const float* e = ml + ((size_t)(s * NH + h) * NN + q) * 2;
    ms[s] = e[0]; ls[s] = e[1];
  }
  float Mx = ms[0];
#pragma unroll
  for (int s = 1; s < KVSPLIT; ++s) Mx = fmaxf(Mx, ms[s]);
  float cs[KVSPLIT], L = 0.f;
#pragma unroll
  for (int s = 0; s < KVSPLIT; ++s) { cs[s] = fexp2(ms[s] - Mx); L += ls[s] * cs[s]; }
  float invL = 1.f / L;
  float vals[8];
#pragma unroll
  for (int j = 0; j < 8; ++j) {
    int d = (dg << 3) + j;
    float acc = 0.f;
#pragma unroll
    for (int s = 0; s < KVSPLIT; ++s)
      acc += opT[((size_t)((s * NH + h) * (NN >> 5) + qt)) * 2048 + (d << 5) + qq] * cs[s];
    vals[j] = acc * invL;
  }
  size_t oo = (size_t)q * DD + h * 64 + (dg << 3);
  *(uint4*)(attnh + oo) = cvt8(vals);
}

// ---------------- gather (bf16 input; deg -> dinv inline) -------------------
__device__ __forceinline__ float4 bf4_tof(ushort4 u) {
  return make_float4(bf16_tof(u.x), bf16_tof(u.y), bf16_tof(u.z), bf16_tof(u.w));
}
__device__ __forceinline__ float drs(int d) { return rsqrtf((float)(d + 1)); }
__global__ __launch_bounds__(256) void k_gather(const ushort* __restrict__ hin,
    const int* __restrict__ deg, const int* __restrict__ lst,
    const float* __restrict__ bias,
    float* __restrict__ outF, ushort* __restrict__ oh, int relu) {
  int g = (blockIdx.x << 2) + (threadIdx.x >> 6);
  int lane = threadIdx.x & 63;
  int dg = deg[g];
  float di = drs(dg);
  int c4 = lane << 2;
  float4 hv = bf4_tof(*(const ushort4*)(hin + (size_t)g * DD + c4));
  float w = di * di;
  float a0x = hv.x * w, a0y = hv.y * w, a0z = hv.z * w, a0w = hv.w * w;
  float a1x = 0, a1y = 0, a1z = 0, a1w = 0;
  float a2x = 0, a2y = 0, a2z = 0, a2w = 0;
  float a3x = 0, a3y = 0, a3z = 0, a3w = 0;
  int num = min(dg, PAD);
  const int* lrow = lst + (g << 7);
  int i = 0;
  for (; i + 4 <= num; i += 4) {
    int4 s4 = *(const int4*)(lrow + i);
    float w0 = drs(deg[s4.x]) * di, w1 = drs(deg[s4.y]) * di;
    float w2 = drs(deg[s4.z]) * di, w3 = drs(deg[s4.w]) * di;
    float4 h0 = bf4_tof(*(const ushort4*)(hin + (size_t)s4.x * DD + c4));
    float4 h1 = bf4_tof(*(const ushort4*)(hin + (size_t)s4.y * DD + c4));
    float4 h2 = bf4_tof(*(const ushort4*)(hin + (size_t)s4.z * DD + c4));
    float4 h3 = bf4_tof(*(const ushort4*)(hin + (size_t)s4.w * DD + c4));
    a0x += h0.x * w0; a0y += h0.y * w0; a0z += h0.z * w0; a0w += h0.w * w0;
    a1x += h1.x * w1; a1y += h1.y * w1; a1z += h1.z * w1; a1w += h1.w * w1;
    a2x += h2.x * w2; a2y += h2.y * w2; a2z += h2.z * w2; a2w += h2.w * w2;
    a3x += h3.x * w3; a3y += h3.y * w3; a3z += h3.z * w3; a3w += h3.w * w3;
  }
  for (; i < num; ++i) {
    int sI = lrow[i];
    float ww = drs(deg[sI]) * di;
    float4 hs = bf4_tof(*(const ushort4*)(hin + (size_t)sI * DD + c4));
    a0x += hs.x * ww; a0y += hs.y * ww; a0z += hs.z * ww; a0w += hs.w * ww;
  }
  float4 bv = *(const float4*)(bias + c4);
  float4 acc = make_float4((a0x + a1x) + (a2x + a3x) + bv.x,
                           (a0y + a1y) + (a2y + a3y) + bv.y,
                           (a0z + a1z) + (a2z + a3z) + bv.z,
                           (a0w + a1w) + (a2w + a3w) + bv.w);
  if (relu) {
    acc.x = fmaxf(acc.x, 0.f); acc.y = fmaxf(acc.y, 0.f);
    acc.z = fmaxf(acc.z, 0.f); acc.w = fmaxf(acc.w, 0.f);
  }
  if (outF) *(float4*)(outF + (size_t)g * DD + c4) = acc;
  if (oh) {
    size_t oo = (size_t)g * DD + c4;
    *(ushort4*)(oh + oo) = make_ushort4(bf16_rne(acc.x), bf16_rne(acc.y),
                                        bf16_rne(acc.z), bf16_rne(acc.w));
  }
}

// ---------------- launch ---------------------------------------------------
extern "C" void kernel_launch(void* const* d_in, const int* in_sizes, int n_in,
                              void* d_out, int out_size, void* d_ws, size_t ws_size,
                              hipStream_t stream) {
  const float* x   = (const float*)d_in[0];
  const int*   ei  = (const int*)d_in[1];
  const float* ipw = (const float*)d_in[2];
  const float* ipb = (const float*)d_in[3];
  const float* opw = (const float*)d_in[4];
  const float* opb = (const float*)d_in[5];
  const float* W1  = (const float*)d_in[6];
  const float* b1  = (const float*)d_in[7];
  const float* W2  = (const float*)d_in[8];
  const float* b2  = (const float*)d_in[9];
  const int* srcI = ei;
  const int* dstI = ei + NE;

  char* w = (char*)d_ws;
  ushort* qhg   = (ushort*)w; w += (size_t)NN * DD * 2;
  ushort* khg   = (ushort*)w; w += (size_t)NN * DD * 2;
  ushort* vhg   = (ushort*)w; w += (size_t)NH * NN * 64 * 2;
  ushort* xh    = (ushort*)w; w += (size_t)NN * DD * 2;   // reused as attnh
  ushort* iph   = (ushort*)w; w += (size_t)NHD * DD * 2;
  ushort* w1h   = (ushort*)w; w += (size_t)DD * DD * 2;
  ushort* w2h   = (ushort*)w; w += (size_t)DD * DD * 2;
  ushort* opth  = (ushort*)w; w += (size_t)DD * DD * 2;
  ushort* wfh   = (ushort*)w; w += (size_t)DD * DD * 2;
  float*  bfv   = (float*)w;  w += (size_t)DD * 4;
  ushort* hlin1 = (ushort*)w; w += (size_t)NN * DD * 2;
  ushort* hlin2 = (ushort*)w; w += (size_t)NN * DD * 2;
  ushort* g1h   = (ushort*)w; w += (size_t)NN * DD * 2;
  float*  opT   = (float*)w;  w += (size_t)KVSPLIT * NH * NN * 64 * 4;
  float*  ml    = (float*)w;  w += (size_t)KVSPLIT * NH * NN * 2 * 4;
  int*    cursor = (int*)w;   w += NN * 4;
  int*    lst    = (int*)w;   w += (size_t)NN * PAD * 4;
  ushort* attnh = xh;

  // conversions + opw^T + bfv + zero cursor
  hipLaunchKernelGGL(k_cvt, dim3(693), dim3(256), 0, stream,
                     x, ipw, opw, W1, W2, opb,
                     xh, iph, w1h, w2h, opth, bfv, cursor);
  // CSR fill; cursor ends as in-degree (used directly by gathers)
  hipLaunchKernelGGL(k_fill, dim3(NE / 256), dim3(256), 0, stream, srcI, dstI,
                     cursor, lst);

  // Wf = W1 * Wop  (bf16)
  hipLaunchKernelGGL(gemmm, dim3(4, 4), dim3(256), 0, stream,
                     w1h, opth, (const float*)nullptr, (float*)nullptr, wfh,
                     DD, DD, DD, 1.f, 0, 0, (ushort*)nullptr, (ushort*)nullptr);

  // QKV projection: Q bf16 (pre-scaled), K bf16, V bf16 transposed
  hipLaunchKernelGGL(gemmm, dim3(64, 12), dim3(256), 0, stream,
                     xh, iph, ipb, (float*)nullptr, qhg,
                     NN, NHD, DD, QSCALE, DD, 1, khg, vhg);
  hipLaunchKernelGGL(flashm, dim3((NN / 128) * 16), dim3(256), 0, stream,
                     qhg, khg, vhg, opT, ml);
  hipLaunchKernelGGL(k_comb, dim3(NN / 32, NH), dim3(256), 0, stream, opT, ml, attnh);

  // fused out-proj + GCN1 linear: hlin1 = attn * Wf^T + W1*bop  (bf16 out)
  hipLaunchKernelGGL(gemmm, dim3(64, 4), dim3(256), 0, stream,
                     attnh, wfh, bfv, (float*)nullptr, hlin1,
                     NN, DD, DD, 1.f, 0, 0, (ushort*)nullptr, (ushort*)nullptr);
  hipLaunchKernelGGL(k_gather, dim3(NN / 4), dim3(256), 0, stream, hlin1, cursor, lst,
                     b1, (float*)nullptr, g1h, 1);
  // GCN2
  hipLaunchKernelGGL(gemmm, dim3(64, 4), dim3(256), 0, stream,
                     g1h, w2h, (const float*)nullptr, (float*)nullptr, hlin2,
                     NN, DD, DD, 1.f, 0, 0, (ushort*)nullptr, (ushort*)nullptr);
  hipLaunchKernelGGL(k_gather, dim3(NN / 4), dim3(256), 0, stream, hlin2, cursor, lst,
                     b2, (float*)d_out, (ushort*)nullptr, 0);
}

// Round 12
// 95.729 us; speedup vs baseline: 2.6800x; 1.0920x over previous
//
#include <hip/hip_runtime.h>
#include <math.h>

#define NN   4096
#define DD   256
#define NHD  768
#define NH   4
#define NE   131072
#define KVSPLIT 4
#define PAD  128
#define QSCALE 0.18033688011112042f   // 0.125 * log2(e)

using bfx8   = __attribute__((ext_vector_type(8))) short;
using f32x4  = __attribute__((ext_vector_type(4))) float;
using f32x16 = __attribute__((ext_vector_type(16))) float;
#define MFMA16(a,b,c) __builtin_amdgcn_mfma_f32_16x16x32_bf16(a, b, c, 0, 0, 0)
#define MFMA32(a,b,c) __builtin_amdgcn_mfma_f32_32x32x16_bf16(a, b, c, 0, 0, 0)

__device__ __forceinline__ ushort bf16_rne(float f) {
  uint u = __float_as_uint(f);
  u += 0x7fffu + ((u >> 16) & 1u);
  return (ushort)(u >> 16);
}
__device__ __forceinline__ float bf16_tof(ushort h) {
  return __uint_as_float(((uint)h) << 16);
}
__device__ __forceinline__ float fexp2(float x) { return __builtin_amdgcn_exp2f(x); }
__device__ __forceinline__ int swzf(int row) {   // u32-index XOR mask, bits 2..4
  return ((row & 7) << 2) ^ ((row & 8) << 1);
}
__device__ __forceinline__ uint4 cvt8(const float* f) {
  ushort hs[8];
#pragma unroll
  for (int j = 0; j < 8; ++j) hs[j] = bf16_rne(f[j]);
  return make_uint4((uint)hs[0] | ((uint)hs[1] << 16), (uint)hs[2] | ((uint)hs[3] << 16),
                    (uint)hs[4] | ((uint)hs[5] << 16), (uint)hs[6] | ((uint)hs[7] << 16));
}

// ---------------- plain-bf16 MFMA GEMM body (device fn) ---------------------
// mode 0: Cf fp32 and/or Cb bf16 (stride Nc). mode 1 (QKV): col<256 -> Q bf16
// compact [row*256] (Cb, pre-scaled); 256..511 -> K bf16 (kout); >=512 -> V
// bf16 transposed [h*64+d][n] (vout).
__device__ __forceinline__ void gemm_body(
    uint* sAh, uint* sBh,
    const ushort* __restrict__ Ah, const ushort* __restrict__ Wh,
    const float* __restrict__ bias, float* __restrict__ Cf,
    ushort* __restrict__ Cb,
    int Nc, int K, float preScale, int preScaleCols,
    int mode, ushort* __restrict__ kout, ushort* __restrict__ vout,
    int mb, int nb) {
  const int tid = threadIdx.x;
  const int wid = tid >> 6, lane = tid & 63;
  const int m15 = lane & 15, g2 = lane >> 4;
  const int wr = wid >> 1, wc = wid & 1;
  const int sw = swzf(m15);
  const int pr0 = tid >> 3, pc0 = (tid & 7) << 2;
  const int pr1 = (tid + 256) >> 3;
  const int wi0 = (pr0 << 5) + (pc0 ^ swzf(pr0));
  const int wi1 = (pr1 << 5) + (pc0 ^ swzf(pr1));
  uint4 ra0, ra1, rb0, rb1;
  auto issue = [&](int k0) {
    ra0 = *(const uint4*)(Ah + (size_t)(mb + pr0) * K + k0 + (pc0 << 1));
    ra1 = *(const uint4*)(Ah + (size_t)(mb + pr1) * K + k0 + (pc0 << 1));
    rb0 = *(const uint4*)(Wh + (size_t)(nb + pr0) * K + k0 + (pc0 << 1));
    rb1 = *(const uint4*)(Wh + (size_t)(nb + pr1) * K + k0 + (pc0 << 1));
  };
  f32x4 acc[2][2];
#pragma unroll
  for (int r = 0; r < 2; ++r)
#pragma unroll
    for (int c = 0; c < 2; ++c) acc[r][c] = (f32x4){0.f, 0.f, 0.f, 0.f};

  issue(0);
  for (int k0 = 0; k0 < K; k0 += 64) {
    __syncthreads();
    *(uint4*)&sAh[wi0] = ra0; *(uint4*)&sBh[wi0] = rb0;
    *(uint4*)&sAh[wi1] = ra1; *(uint4*)&sBh[wi1] = rb1;
    __syncthreads();
    if (k0 + 64 < K) issue(k0 + 64);
#pragma unroll
    for (int c = 0; c < 2; ++c) {
      bfx8 ah[2], bh[2];
#pragma unroll
      for (int r = 0; r < 2; ++r) {
        int rowA = (wr << 5) + (r << 4) + m15;
        ah[r] = __builtin_bit_cast(bfx8, *(const uint4*)&sAh[(rowA << 5) + (((c << 4) + (g2 << 2)) ^ sw)]);
        int rowB = (wc << 5) + (r << 4) + m15;
        bh[r] = __builtin_bit_cast(bfx8, *(const uint4*)&sBh[(rowB << 5) + (((c << 4) + (g2 << 2)) ^ sw)]);
      }
#pragma unroll
      for (int r = 0; r < 2; ++r)
#pragma unroll
        for (int cc = 0; cc < 2; ++cc)
          acc[r][cc] = MFMA16(ah[r], bh[cc], acc[r][cc]);
    }
  }
#pragma unroll
  for (int r = 0; r < 2; ++r)
#pragma unroll
    for (int cc = 0; cc < 2; ++cc) {
      int col = nb + (wc << 5) + (cc << 4) + m15;
      float bv = bias ? bias[col] : 0.f;
      float sc = (col < preScaleCols) ? preScale : 1.f;
      int row0 = mb + (wr << 5) + (r << 4) + (g2 << 2);
      float v4[4];
#pragma unroll
      for (int j = 0; j < 4; ++j) v4[j] = (acc[r][cc][j] + bv) * sc;
      if (mode == 1) {
        if (col < 256) {
#pragma unroll
          for (int j = 0; j < 4; ++j)
            Cb[(size_t)(row0 + j) * 256 + col] = bf16_rne(v4[j]);
        } else if (col < 512) {
#pragma unroll
          for (int j = 0; j < 4; ++j)
            kout[(size_t)(row0 + j) * 256 + (col - 256)] = bf16_rne(v4[j]);
        } else {
          ushort4 vs = make_ushort4(bf16_rne(v4[0]), bf16_rne(v4[1]),
                                    bf16_rne(v4[2]), bf16_rne(v4[3]));
          *(ushort4*)(vout + ((size_t)(col - 512) << 12) + row0) = vs;
        }
      } else {
#pragma unroll
        for (int j = 0; j < 4; ++j) {
          int row = row0 + j;
          if (Cf) Cf[(size_t)row * Nc + col] = v4[j];
          if (Cb) Cb[(size_t)row * Nc + col] = bf16_rne(v4[j]);
        }
      }
    }
}

// ---------------- standalone GEMM (tail layers) -----------------------------
__global__ __launch_bounds__(256, 4) void gemmm(
    const ushort* __restrict__ Ah, const ushort* __restrict__ Wh,
    const float* __restrict__ bias, float* __restrict__ Cf,
    ushort* __restrict__ Cb, int Nc, int K) {
  __shared__ uint smem[4096];
  gemm_body(smem, smem + 2048, Ah, Wh, bias, Cf, Cb, Nc, K, 1.f, 0, 0,
            (ushort*)nullptr, (ushort*)nullptr, blockIdx.x << 6, blockIdx.y << 6);
}

// ----- merged middle: QKV gemm (768) + Wf gemm (16) + edge fill (512) -------
__global__ __launch_bounds__(256, 4) void k_mid(
    const ushort* __restrict__ xh, const ushort* __restrict__ iph,
    const float* __restrict__ ipb,
    ushort* __restrict__ qhg, ushort* __restrict__ khg, ushort* __restrict__ vhg,
    const ushort* __restrict__ w1h, const ushort* __restrict__ opth,
    ushort* __restrict__ wfh,
    const int* __restrict__ src, const int* __restrict__ dst,
    int* cursor, int* __restrict__ lst) {
  __shared__ uint smem[4096];
  int b = blockIdx.x;
  if (b < 768) {          // QKV projection, mode 1
    gemm_body(smem, smem + 2048, xh, iph, ipb, (float*)nullptr, qhg,
              NHD, DD, QSCALE, DD, 1, khg, vhg,
              (b & 63) << 6, (b >> 6) << 6);
  } else if (b < 784) {   // Wf = W1 * Wop
    int idx = b - 768;
    gemm_body(smem, smem + 2048, w1h, opth, (const float*)nullptr,
              (float*)nullptr, wfh, DD, DD, 1.f, 0, 0,
              (ushort*)nullptr, (ushort*)nullptr,
              (idx & 3) << 6, (idx >> 2) << 6);
  } else {                // CSR fill; cursor ends as in-degree
    int e = (b - 784) * 256 + threadIdx.x;
    int d = dst[e];
    int pos = atomicAdd(&cursor[d], 1);
    if (pos < PAD) lst[(d << 7) + pos] = src[e];
  }
}

// ------- convert x/ipw/W1/W2 to bf16; opw^T; bfv; zero cursor ---------------
__global__ __launch_bounds__(256) void k_cvt(
    const float* __restrict__ x, const float* __restrict__ ipw,
    const float* __restrict__ opw, const float* __restrict__ W1,
    const float* __restrict__ W2, const float* __restrict__ opb,
    ushort* xh, ushort* iph, ushort* w1h, ushort* w2h,
    ushort* opth, float* bfv, int* cursor) {
  __shared__ float sT[64 * 65];
  int b = blockIdx.x;
  if (b >= 672) {
    if (b < 688) {                       // transpose-convert opw -> opth
      int tx = b - 672, by = tx >> 2, bx = tx & 3;
      int r = threadIdx.x >> 2, cb = (threadIdx.x & 3) << 4;
      const float* src = opw + (size_t)(by * 64 + r) * 256 + bx * 64 + cb;
#pragma unroll
      for (int i = 0; i < 4; ++i) {
        float4 v = *(const float4*)(src + i * 4);
        sT[r * 65 + cb + i * 4 + 0] = v.x; sT[r * 65 + cb + i * 4 + 1] = v.y;
        sT[r * 65 + cb + i * 4 + 2] = v.z; sT[r * 65 + cb + i * 4 + 3] = v.w;
      }
      __syncthreads();
      int d = threadIdx.x >> 2, nb2 = (threadIdx.x & 3) << 4;
      float f[16];
#pragma unroll
      for (int i = 0; i < 16; ++i) f[i] = sT[(nb2 + i) * 65 + d];
      size_t o = (size_t)(bx * 64 + d) * 256 + by * 64 + nb2;
      *(uint4*)(opth + o)     = cvt8(&f[0]);
      *(uint4*)(opth + o + 8) = cvt8(&f[8]);
    } else if (b == 688) {               // bfv = W1 * opb
      int t = threadIdx.x;
      sT[t] = opb[t];
      __syncthreads();
      float acc = 0.f;
      const float* wr = W1 + (size_t)t * 256;
      for (int k = 0; k < 256; ++k) acc += wr[k] * sT[k];
      bfv[t] = acc;
    } else {                             // 4 blocks: zero cursor
      int i = ((b - 689) * 256 + threadIdx.x) * 4;
      *(int4*)(cursor + i) = make_int4(0, 0, 0, 0);
    }
    return;
  }
  const float* src; ushort* hi; int base;
  if (b < 512)      { src = x;   hi = xh;  base = b; }
  else if (b < 608) { src = ipw; hi = iph; base = b - 512; }
  else if (b < 640) { src = W1;  hi = w1h; base = b - 608; }
  else              { src = W2;  hi = w2h; base = b - 640; }
  size_t i = (size_t)base * 256 + threadIdx.x;
  float f[8];
  *(float4*)&f[0] = *(const float4*)(src + i * 8);
  *(float4*)&f[4] = *(const float4*)(src + i * 8 + 4);
  *(uint4*)(hi + i * 8) = cvt8(f);
}

// ------- MFMA 32x32 swapped-operand flash, plain bf16, 1-barrier dbuf -------
// 256 threads, 128 q rows, grid 512 (L2-friendly id co-location). 32 KB LDS.
__global__ __launch_bounds__(256, 2) void flashm(
    const ushort* __restrict__ qhg, const ushort* __restrict__ khg,
    const ushort* __restrict__ vhg,
    float* __restrict__ opT, float* __restrict__ ml) {
  __shared__ uint sKh[4096], sVh[4096];   // double-buffered, 32 KB

  const int b = blockIdx.x;
  const int id = b & 15;                 // (h,split): co-located per XCD
  const int h = id >> 2, split = id & 3;
  const int qb = (b >> 4) << 7;          // 128 q rows per block
  const int kv0 = split << 10;           // 1024 keys per split
  const int NT = 16;

  const int tid = threadIdx.x;
  const int wid = tid >> 6, lane = tid & 63;
  const int m31 = lane & 31, g = lane >> 5;

  bfx8 qh[4];
  {
    const size_t qoff = (size_t)(qb + (wid << 5) + m31) * 256 + h * 64 + (g << 3);
#pragma unroll
    for (int c = 0; c < 4; ++c)
      qh[c] = __builtin_bit_cast(bfx8, *(const uint4*)(qhg + qoff + (c << 4)));
  }

  f32x16 o[2];
#pragma unroll
  for (int dt = 0; dt < 2; ++dt)
#pragma unroll
    for (int j = 0; j < 16; ++j) o[dt][j] = 0.f;
  float mreg = -1e30f;
  float lacc[16];
#pragma unroll
  for (int j = 0; j < 16; ++j) lacc[j] = 0.f;

  // staging: 2 chunks of 256 threads x 16B (K tile 8 KB + V tile 8 KB)
  const int pr0 = tid >> 3, pc0 = (tid & 7) << 2;
  const int pr1 = (tid + 256) >> 3;
  const int wi0 = (pr0 << 5) + (pc0 ^ swzf(pr0));
  const int wi1 = (pr1 << 5) + (pc0 ^ swzf(pr1));
  uint4 rk0, rk1, rv0, rv1;
  auto issue = [&](int kv) {
    rk0 = *(const uint4*)(khg + (size_t)(kv + pr0) * 256 + h * 64 + (pc0 << 1));
    rk1 = *(const uint4*)(khg + (size_t)(kv + pr1) * 256 + h * 64 + (pc0 << 1));
    rv0 = *(const uint4*)(vhg + ((size_t)(h * 64 + pr0) << 12) + kv + (pc0 << 1));
    rv1 = *(const uint4*)(vhg + ((size_t)(h * 64 + pr1) << 12) + kv + (pc0 << 1));
  };
  auto writebuf = [&](int buf) {
    uint* K = sKh + (buf << 11);
    uint* V = sVh + (buf << 11);
    *(uint4*)&K[wi0] = rk0; *(uint4*)&V[wi0] = rv0;
    *(uint4*)&K[wi1] = rk1; *(uint4*)&V[wi1] = rv1;
  };

  issue(kv0);
  writebuf(0);
  issue(kv0 + 64);
  __syncthreads();

  for (int it = 0; it < NT; ++it) {
    const int cur = it & 1;
    if (it + 1 < NT) writebuf(cur ^ 1);
    if (it + 2 < NT) issue(kv0 + ((it + 2) << 6));
    const uint* Kb = sKh + (cur << 11);
    const uint* Vb = sVh + (cur << 11);

    // ---- S^T = K_bf16 * Q_bf16, log2-domain ----
    f32x16 s[2];
#pragma unroll
    for (int kt = 0; kt < 2; ++kt) {
#pragma unroll
      for (int j = 0; j < 16; ++j) s[kt][j] = 0.f;
      const int row = (kt << 5) + m31;
      const int rb = row << 5;
      const int sw2 = swzf(row);
      __builtin_amdgcn_s_setprio(1);
#pragma unroll
      for (int c = 0; c < 4; ++c) {
        int col = ((c << 3) + (g << 2)) ^ sw2;
        bfx8 kh = __builtin_bit_cast(bfx8, *(const uint4*)&Kb[rb + col]);
        s[kt] = MFMA32(kh, qh[c], s[kt]);
      }
      __builtin_amdgcn_s_setprio(0);
    }

    // ---- online softmax, lane-local for q = m31; deferred l ----
    float v16[16];
#pragma unroll
    for (int j = 0; j < 16; ++j) v16[j] = fmaxf(s[0][j], s[1][j]);
#pragma unroll
    for (int st = 8; st; st >>= 1)
#pragma unroll
      for (int j = 0; j < 8; ++j)
        if (j < st) v16[j] = fmaxf(v16[j], v16[j + st]);
    float mt = fmaxf(v16[0], __shfl_xor(v16[0], 32));
    int need = (mt > mreg + 8.f) ? 1 : 0;
    if (__any(need)) {
      float mn = fmaxf(mreg, mt);
      float al = fexp2(mreg - mn);
      mreg = mn;
#pragma unroll
      for (int j = 0; j < 16; ++j) lacc[j] *= al;
#pragma unroll
      for (int dt = 0; dt < 2; ++dt)
#pragma unroll
        for (int j = 0; j < 16; ++j) o[dt][j] *= al;
    }
    float p0[16], p1[16];
#pragma unroll
    for (int j = 0; j < 16; ++j) {
      p0[j] = fexp2(s[0][j] - mreg);
      p1[j] = fexp2(s[1][j] - mreg);
      lacc[j] += p0[j] + p1[j];
    }

    // ---- pack P to bf16 (trunc) in-register ----
    uint puh[2][8];
#pragma unroll
    for (int kt = 0; kt < 2; ++kt)
#pragma unroll
      for (int jj = 0; jj < 8; ++jj) {
        float a = kt ? p1[2 * jj] : p0[2 * jj];
        float bq = kt ? p1[2 * jj + 1] : p0[2 * jj + 1];
        puh[kt][jj] = (__float_as_uint(a) >> 16) | (__float_as_uint(bq) & 0xffff0000u);
      }

    // ---- O^T += V^T_bf16 * P_bf16, permuted K-order ----
#pragma unroll
    for (int dt = 0; dt < 2; ++dt) {
      const int row = (dt << 5) + m31;
      const int rb = row << 5;
      const int sw2 = swzf(row);
      __builtin_amdgcn_s_setprio(1);
#pragma unroll
      for (int kt = 0; kt < 2; ++kt)
#pragma unroll
        for (int cc = 0; cc < 2; ++cc) {
          int cA = ((kt << 4) + (cc << 3) + (g << 1)) ^ sw2;
          int cB = ((kt << 4) + (cc << 3) + (g << 1) + 4) ^ sw2;
          uint2 vh0 = *(const uint2*)&Vb[rb + cA];
          uint2 vh1 = *(const uint2*)&Vb[rb + cB];
          bfx8 ah = __builtin_bit_cast(bfx8, make_uint4(vh0.x, vh0.y, vh1.x, vh1.y));
          bfx8 bh = __builtin_bit_cast(bfx8, make_uint4(puh[kt][4 * cc], puh[kt][4 * cc + 1],
                                                        puh[kt][4 * cc + 2], puh[kt][4 * cc + 3]));
          o[dt] = MFMA32(ah, bh, o[dt]);
        }
      __builtin_amdgcn_s_setprio(0);
    }
    __syncthreads();
  }

  float lreg;
  {
#pragma unroll
    for (int st = 8; st; st >>= 1)
#pragma unroll
      for (int j = 0; j < 8; ++j)
        if (j < st) lacc[j] += lacc[j + st];
    lreg = lacc[0] + __shfl_xor(lacc[0], 32);
  }

  const int region = (split * NH + h) * (NN >> 5) + (qb >> 5) + wid;
  float* ob = opT + (size_t)region * 2048;
#pragma unroll
  for (int dt = 0; dt < 2; ++dt)
#pragma unroll
    for (int r = 0; r < 16; ++r) {
      int d = (dt << 5) + (r & 3) + ((r >> 2) << 3) + (g << 2);
      ob[(d << 5) + m31] = o[dt][r];
    }
  if (!g) {
    size_t qi = (size_t)(split * NH + h) * NN + qb + (wid << 5) + m31;
    ml[qi * 2]     = mreg;
    ml[qi * 2 + 1] = lreg;
  }
}

// ---------------- combine KV-split partials -> attn bf16 --------------------
__global__ __launch_bounds__(256) void k_comb(const float* __restrict__ opT,
    const float* __restrict__ ml, ushort* __restrict__ attnh) {
  int qt = blockIdx.x, h = blockIdx.y, t = threadIdx.x;
  int qq = t & 31, dg = t >> 5;
  int q = (qt << 5) + qq;
  float ms[KVSPLIT], ls[KVSPLIT];
#pragma unroll
  for (int s = 0; s < KVSPLIT; ++s) {
    const float* e = ml + ((size_t)(s * NH + h) * NN + q) * 2;
    ms[s] = e[0]; ls[s] = e[1];
  }
  float Mx = ms[0];
#pragma unroll
  for (int s = 1; s < KVSPLIT; ++s) Mx = fmaxf(Mx, ms[s]);
  float cs[KVSPLIT], L = 0.f;
#pragma unroll
  for (int s = 0; s < KVSPLIT; ++s) { cs[s] = fexp2(ms[s] - Mx); L += ls[s] * cs[s]; }
  float invL = 1.f / L;
  float vals[8];
#pragma unroll
  for (int j = 0; j < 8; ++j) {
    int d = (dg << 3) + j;
    float acc = 0.f;
#pragma unroll
    for (int s = 0; s < KVSPLIT; ++s)
      acc += opT[((size_t)((s * NH + h) * (NN >> 5) + qt)) * 2048 + (d << 5) + qq] * cs[s];
    vals[j] = acc * invL;
  }
  size_t oo = (size_t)q * DD + h * 64 + (dg << 3);
  *(uint4*)(attnh + oo) = cvt8(vals);
}

// ---------------- gather (bf16 input; deg -> dinv inline) -------------------
__device__ __forceinline__ float4 bf4_tof(ushort4 u) {
  return make_float4(bf16_tof(u.x), bf16_tof(u.y), bf16_tof(u.z), bf16_tof(u.w));
}
__device__ __forceinline__ float drs(int d) { return rsqrtf((float)(d + 1)); }
__global__ __launch_bounds__(256) void k_gather(const ushort* __restrict__ hin,
    const int* __restrict__ deg, const int* __restrict__ lst,
    const float* __restrict__ bias,
    float* __restrict__ outF, ushort* __restrict__ oh, int relu) {
  int g = (blockIdx.x << 2) + (threadIdx.x >> 6);
  int lane = threadIdx.x & 63;
  int dg = deg[g];
  float di = drs(dg);
  int c4 = lane << 2;
  float4 hv = bf4_tof(*(const ushort4*)(hin + (size_t)g * DD + c4));
  float w = di * di;
  float a0x = hv.x * w, a0y = hv.y * w, a0z = hv.z * w, a0w = hv.w * w;
  float a1x = 0, a1y = 0, a1z = 0, a1w = 0;
  float a2x = 0, a2y = 0, a2z = 0, a2w = 0;
  float a3x = 0, a3y = 0, a3z = 0, a3w = 0;
  int num = min(dg, PAD);
  const int* lrow = lst + (g << 7);
  int i = 0;
  for (; i + 4 <= num; i += 4) {
    int4 s4 = *(const int4*)(lrow + i);
    float w0 = drs(deg[s4.x]) * di, w1 = drs(deg[s4.y]) * di;
    float w2 = drs(deg[s4.z]) * di, w3 = drs(deg[s4.w]) * di;
    float4 h0 = bf4_tof(*(const ushort4*)(hin + (size_t)s4.x * DD + c4));
    float4 h1 = bf4_tof(*(const ushort4*)(hin + (size_t)s4.y * DD + c4));
    float4 h2 = bf4_tof(*(const ushort4*)(hin + (size_t)s4.z * DD + c4));
    float4 h3 = bf4_tof(*(const ushort4*)(hin + (size_t)s4.w * DD + c4));
    a0x += h0.x * w0; a0y += h0.y * w0; a0z += h0.z * w0; a0w += h0.w * w0;
    a1x += h1.x * w1; a1y += h1.y * w1; a1z += h1.z * w1; a1w += h1.w * w1;
    a2x += h2.x * w2; a2y += h2.y * w2; a2z += h2.z * w2; a2w += h2.w * w2;
    a3x += h3.x * w3; a3y += h3.y * w3; a3z += h3.z * w3; a3w += h3.w * w3;
  }
  for (; i < num; ++i) {
    int sI = lrow[i];
    float ww = drs(deg[sI]) * di;
    float4 hs = bf4_tof(*(const ushort4*)(hin + (size_t)sI * DD + c4));
    a0x += hs.x * ww; a0y += hs.y * ww; a0z += hs.z * ww; a0w += hs.w * ww;
  }
  float4 bv = *(const float4*)(bias + c4);
  float4 acc = make_float4((a0x + a1x) + (a2x + a3x) + bv.x,
                           (a0y + a1y) + (a2y + a3y) + bv.y,
                           (a0z + a1z) + (a2z + a3z) + bv.z,
                           (a0w + a1w) + (a2w + a3w) + bv.w);
  if (relu) {
    acc.x = fmaxf(acc.x, 0.f); acc.y = fmaxf(acc.y, 0.f);
    acc.z = fmaxf(acc.z, 0.f); acc.w = fmaxf(acc.w, 0.f);
  }
  if (outF) *(float4*)(outF + (size_t)g * DD + c4) = acc;
  if (oh) {
    size_t oo = (size_t)g * DD + c4;
    *(ushort4*)(oh + oo) = make_ushort4(bf16_rne(acc.x), bf16_rne(acc.y),
                                        bf16_rne(acc.z), bf16_rne(acc.w));
  }
}

// ---------------- launch ---------------------------------------------------
extern "C" void kernel_launch(void* const* d_in, const int* in_sizes, int n_in,
                              void* d_out, int out_size, void* d_ws, size_t ws_size,
                              hipStream_t stream) {
  const float* x   = (const float*)d_in[0];
  const int*   ei  = (const int*)d_in[1];
  const float* ipw = (const float*)d_in[2];
  const float* ipb = (const float*)d_in[3];
  const float* opw = (const float*)d_in[4];
  const float* opb = (const float*)d_in[5];
  const float* W1  = (const float*)d_in[6];
  const float* b1  = (const float*)d_in[7];
  const float* W2  = (const float*)d_in[8];
  const float* b2  = (const float*)d_in[9];
  const int* srcI = ei;
  const int* dstI = ei + NE;

  char* w = (char*)d_ws;
  ushort* qhg   = (ushort*)w; w += (size_t)NN * DD * 2;
  ushort* khg   = (ushort*)w; w += (size_t)NN * DD * 2;
  ushort* vhg   = (ushort*)w; w += (size_t)NH * NN * 64 * 2;
  ushort* xh    = (ushort*)w; w += (size_t)NN * DD * 2;   // reused as attnh
  ushort* iph   = (ushort*)w; w += (size_t)NHD * DD * 2;
  ushort* w1h   = (ushort*)w; w += (size_t)DD * DD * 2;
  ushort* w2h   = (ushort*)w; w += (size_t)DD * DD * 2;
  ushort* opth  = (ushort*)w; w += (size_t)DD * DD * 2;
  ushort* wfh   = (ushort*)w; w += (size_t)DD * DD * 2;
  float*  bfv   = (float*)w;  w += (size_t)DD * 4;
  ushort* hlin1 = (ushort*)w; w += (size_t)NN * DD * 2;
  ushort* hlin2 = (ushort*)w; w += (size_t)NN * DD * 2;
  ushort* g1h   = (ushort*)w; w += (size_t)NN * DD * 2;
  float*  opT   = (float*)w;  w += (size_t)KVSPLIT * NH * NN * 64 * 4;
  float*  ml    = (float*)w;  w += (size_t)KVSPLIT * NH * NN * 2 * 4;
  int*    cursor = (int*)w;   w += NN * 4;
  int*    lst    = (int*)w;   w += (size_t)NN * PAD * 4;
  ushort* attnh = xh;

  // conversions + opw^T + bfv + zero cursor
  hipLaunchKernelGGL(k_cvt, dim3(693), dim3(256), 0, stream,
                     x, ipw, opw, W1, W2, opb,
                     xh, iph, w1h, w2h, opth, bfv, cursor);
  // merged: QKV gemm + Wf gemm + CSR fill (mutually independent)
  hipLaunchKernelGGL(k_mid, dim3(1296), dim3(256), 0, stream,
                     xh, iph, ipb, qhg, khg, vhg, w1h, opth, wfh,
                     srcI, dstI, cursor, lst);

  hipLaunchKernelGGL(flashm, dim3((NN / 128) * 16), dim3(256), 0, stream,
                     qhg, khg, vhg, opT, ml);
  hipLaunchKernelGGL(k_comb, dim3(NN / 32, NH), dim3(256), 0, stream, opT, ml, attnh);

  // fused out-proj + GCN1 linear: hlin1 = attn * Wf^T + W1*bop  (bf16 out)
  hipLaunchKernelGGL(gemmm, dim3(64, 4), dim3(256), 0, stream,
                     attnh, wfh, bfv, (float*)nullptr, hlin1, DD, DD);
  hipLaunchKernelGGL(k_gather, dim3(NN / 4), dim3(256), 0, stream, hlin1, cursor, lst,
                     b1, (float*)nullptr, g1h, 1);
  // GCN2
  hipLaunchKernelGGL(gemmm, dim3(64, 4), dim3(256), 0, stream,
                     g1h, w2h, (const float*)nullptr, (float*)nullptr, hlin2, DD, DD);
  hipLaunchKernelGGL(k_gather, dim3(NN / 4), dim3(256), 0, stream, hlin2, cursor, lst,
                     b2, (float*)d_out, (ushort*)nullptr, 0);
}